// Round 1
// baseline (1261.953 us; speedup 1.0000x reference)
//
#include <hip/hip_runtime.h>

typedef unsigned short u16;
typedef __attribute__((ext_vector_type(8))) short s16x8;
typedef __attribute__((ext_vector_type(4))) float f32x4;
typedef __attribute__((ext_vector_type(4))) int   i32x4;
typedef __attribute__((ext_vector_type(4))) unsigned short u16x4;

// ---------------- workspace layout (bytes) ----------------
constexpr size_t OFF_XB   = 0;                     // bf16 x          [2048][1024]
constexpr size_t OFF_WQB  = OFF_XB   + 4194304;    // bf16 Wq         [1024][1024]
constexpr size_t OFF_WKB  = OFF_WQB  + 2097152;    // bf16 Wk         [512][1024]
constexpr size_t OFF_WVB  = OFF_WKB  + 1048576;    // bf16 Wv         [512][1024]
constexpr size_t OFF_WOB  = OFF_WVB  + 1048576;    // bf16 Wo         [1024][1024]
constexpr size_t OFF_W1T  = OFF_WOB  + 2097152;    // bf16 W1T        [384][1024] (rows 320..383 zero)
constexpr size_t OFF_W2T  = OFF_W1T  + 786432;     // bf16 w2T        [1024][64]
constexpr size_t OFF_A2T  = OFF_W2T  + 131072;     // bf16 a2T        [1024][64]
constexpr size_t OFF_V2T  = OFF_A2T  + 131072;     // bf16 v2T        [1024][32]
constexpr size_t OFF_G2T  = OFF_V2T  + 65536;      // bf16 g2T        [1024][160]
constexpr size_t OFF_KQF  = OFF_G2T  + 327680;     // f32 k-proj      [2048][512]
constexpr size_t OFF_VQF  = OFF_KQF  + 4194304;    // f32 v-proj      [2048][512]
constexpr size_t OFF_URAW = OFF_VQF  + 4194304;    // f32 stage1 raw  [2048][320]
constexpr size_t OFF_UB   = OFF_URAW + 2621440;    // bf16 stage1 act [2048][384]
constexpr size_t OFF_S2A  = OFF_UB   + 1572864;    // f32 iclr        [2048][1024]
constexpr size_t OFF_S2V  = OFF_S2A  + 8388608;    // f32 vmix        [2048][1024]
constexpr size_t OFF_GBUF = OFF_S2V  + 8388608;    // f32 gate        [2048][1024]
constexpr size_t OFF_SEQ  = OFF_GBUF + 8388608;    // f32 SEQ [2][16][1024][6][64] (r,decay,k,v,a,b)
constexpr size_t OFF_YBUF = OFF_SEQ  + 50331648;   // f32 y   [2][16][1024][64]
constexpr size_t OFF_XGB  = OFF_YBUF + 8388608;    // bf16 xn*g       [2048][1024]

__device__ __forceinline__ u16 f2bf(float f){
  unsigned int u = __builtin_bit_cast(unsigned int, f);
  u = u + 0x7fffu + ((u >> 16) & 1u);
  return (u16)(u >> 16);
}

// ---------------- prep: convert/transpose + v_first passthrough ----------------
constexpr size_t N_XB=2097152, N_WQ=1048576, N_WK=524288, N_WV=524288, N_WO=1048576,
  N_W1T=393216, N_W2T=65536, N_A2T=65536, N_V2T=32768, N_G2T=163840, N_VF=2097152;
constexpr size_t PREP_TOT = N_XB+N_WQ+N_WK+N_WV+N_WO+N_W1T+N_W2T+N_A2T+N_V2T+N_G2T+N_VF;

__global__ __launch_bounds__(256) void prep_kernel(char* ws, const float* x, const float* vfirst,
  const float* w1, const float* w2, const float* a1, const float* a2,
  const float* v1, const float* v2, const float* g1, const float* g2,
  const float* Wq, const float* Wk, const float* Wv, const float* Wo, float* dout)
{
  u16* XB=(u16*)(ws+OFF_XB); u16* WQB=(u16*)(ws+OFF_WQB); u16* WKB=(u16*)(ws+OFF_WKB);
  u16* WVB=(u16*)(ws+OFF_WVB); u16* WOB=(u16*)(ws+OFF_WOB); u16* W1T=(u16*)(ws+OFF_W1T);
  u16* W2T=(u16*)(ws+OFF_W2T); u16* A2T=(u16*)(ws+OFF_A2T); u16* V2T=(u16*)(ws+OFF_V2T);
  u16* G2T=(u16*)(ws+OFF_G2T);
  for (size_t idx=(size_t)blockIdx.x*256+threadIdx.x; idx<PREP_TOT; idx+=(size_t)gridDim.x*256){
    size_t r = idx;
    if (r < N_XB){ XB[r]=f2bf(x[r]); continue; } r-=N_XB;
    if (r < N_WQ){ WQB[r]=f2bf(Wq[r]); continue; } r-=N_WQ;
    if (r < N_WK){ WKB[r]=f2bf(Wk[r]); continue; } r-=N_WK;
    if (r < N_WV){ WVB[r]=f2bf(Wv[r]); continue; } r-=N_WV;
    if (r < N_WO){ WOB[r]=f2bf(Wo[r]); continue; } r-=N_WO;
    if (r < N_W1T){
      int n=(int)(r>>10), k=(int)(r&1023); float v=0.f;
      if (n<64) v=w1[(size_t)k*64+n];
      else if (n<128) v=a1[(size_t)k*64+(n-64)];
      else if (n<160) v=v1[(size_t)k*32+(n-128)];
      else if (n<320) v=g1[(size_t)k*160+(n-160)];
      W1T[r]=f2bf(v); continue; } r-=N_W1T;
    if (r < N_W2T){ int c=(int)(r>>6), d=(int)(r&63); W2T[r]=f2bf(w2[(size_t)d*1024+c]); continue; } r-=N_W2T;
    if (r < N_A2T){ int c=(int)(r>>6), d=(int)(r&63); A2T[r]=f2bf(a2[(size_t)d*1024+c]); continue; } r-=N_A2T;
    if (r < N_V2T){ int c=(int)(r>>5), d=(int)(r&31); V2T[r]=f2bf(v2[(size_t)d*1024+c]); continue; } r-=N_V2T;
    if (r < N_G2T){ int c=(int)(r/160), d=(int)(r%160); G2T[r]=f2bf(g2[(size_t)d*1024+c]); continue; } r-=N_G2T;
    dout[2228224 + r] = vfirst[r];   // v_first passthrough (offset 2097152+131072)
  }
}

// ---------------- activation for stage-1 ----------------
__global__ __launch_bounds__(256) void act_kernel(char* ws){
  const float* URAW=(const float*)(ws+OFF_URAW);
  u16* UB=(u16*)(ws+OFF_UB);
  size_t idx=(size_t)blockIdx.x*256+threadIdx.x;   // grid covers 2048*384 exactly
  int m=(int)(idx/384), n=(int)(idx%384);
  float v=0.f;
  if (n<64)       v = tanhf(URAW[(size_t)m*320+n]);
  else if (n<160) v = URAW[(size_t)m*320+n];
  else if (n<320) v = 1.0f/(1.0f+__expf(-URAW[(size_t)m*320+n]));
  UB[idx]=f2bf(v);
}

// ---------------- unified NT bf16 MFMA GEMM: C[m][n] = sum_k A[m][k]*B[n][k] ----------------
__global__ __launch_bounds__(256) void gemm_kernel(int phase, char* ws,
  const float* w0b, const float* a0b, const float* v0b, float* dout)
{
  const u16* A; const u16* Bw;
  float* outF=nullptr; const float* bias=nullptr;
  float* SEQf=(float*)(ws+OFF_SEQ);
  int lda=0, ldb=0, K=0, ldc=0, Nlim=1024, col0=0, outMode=0;
  int y = blockIdx.y;
  if (phase==0){
    A=(const u16*)(ws+OFF_XB); lda=1024; K=1024;
    if (y<8)      { Bw=(const u16*)(ws+OFF_WQB); ldb=1024; col0=y*128;       outMode=1; }
    else if (y<12){ Bw=(const u16*)(ws+OFF_WKB); ldb=1024; col0=(y-8)*128;   outF=(float*)(ws+OFF_KQF); ldc=512; Nlim=512; }
    else if (y<16){ Bw=(const u16*)(ws+OFF_WVB); ldb=1024; col0=(y-12)*128;  outF=(float*)(ws+OFF_VQF); ldc=512; Nlim=512; }
    else          { Bw=(const u16*)(ws+OFF_W1T); ldb=1024; col0=(y-16)*128;  outF=(float*)(ws+OFF_URAW); ldc=320; Nlim=320; }
  } else if (phase==1){
    int seg=y>>3; col0=(y&7)*128;
    const int Ks[4]={64,64,32,160};
    const int Ao[4]={0,64,128,160};
    K=Ks[seg]; lda=384; ldb=K;
    A=(const u16*)(ws+OFF_UB) + Ao[seg];
    if (seg==0)     { Bw=(const u16*)(ws+OFF_W2T); outMode=2; bias=w0b; }
    else if (seg==1){ Bw=(const u16*)(ws+OFF_A2T); outMode=3; bias=a0b; outF=(float*)(ws+OFF_S2A); ldc=1024; }
    else if (seg==2){ Bw=(const u16*)(ws+OFF_V2T); outMode=3; bias=v0b; outF=(float*)(ws+OFF_S2V); ldc=1024; }
    else            { Bw=(const u16*)(ws+OFF_G2T); outF=(float*)(ws+OFF_GBUF); ldc=1024; }
  } else {
    A=(const u16*)(ws+OFF_XGB); lda=1024; K=1024;
    Bw=(const u16*)(ws+OFF_WOB); ldb=1024; col0=y*128; outF=dout; ldc=1024;
  }
  int m0 = blockIdx.x*128;
  __shared__ __align__(16) u16 As[128][40];
  __shared__ __align__(16) u16 Bs[128][40];
  int tid=threadIdx.x, l=tid&63, wv=tid>>6, wm=wv>>1, wn=wv&1;
  f32x4 acc[4][4];
  #pragma unroll
  for (int i=0;i<4;i++)
    #pragma unroll
    for (int j=0;j<4;j++) acc[i][j]=(f32x4){0.f,0.f,0.f,0.f};

  for (int k0=0;k0<K;k0+=32){
    #pragma unroll
    for (int c=tid;c<512;c+=256){
      int row=c>>2, seg=c&3;
      *(i32x4*)(&As[row][seg*8]) = *(const i32x4*)(A  + (size_t)(m0+row)*lda  + k0 + seg*8);
      *(i32x4*)(&Bs[row][seg*8]) = *(const i32x4*)(Bw + (size_t)(col0+row)*ldb + k0 + seg*8);
    }
    __syncthreads();
    int kseg=(l>>4)*8, rrow=l&15;
    s16x8 af[4], bf[4];
    #pragma unroll
    for (int mt=0;mt<4;mt++) af[mt]=*(const s16x8*)(&As[wm*64+mt*16+rrow][kseg]);
    #pragma unroll
    for (int nt=0;nt<4;nt++) bf[nt]=*(const s16x8*)(&Bs[wn*64+nt*16+rrow][kseg]);
    #pragma unroll
    for (int mt=0;mt<4;mt++)
      #pragma unroll
      for (int nt=0;nt<4;nt++)
        acc[mt][nt]=__builtin_amdgcn_mfma_f32_16x16x32_bf16(af[mt],bf[nt],acc[mt][nt],0,0,0);
    __syncthreads();
  }
  // epilogue
  #pragma unroll
  for (int mt=0;mt<4;mt++){
    #pragma unroll
    for (int nt=0;nt<4;nt++){
      int nglob = col0 + wn*64 + nt*16 + (l&15);
      if (nglob >= Nlim) continue;
      #pragma unroll
      for (int rg=0;rg<4;rg++){
        int mrow = m0 + wm*64 + mt*16 + ((l>>4)<<2) + rg;
        float val = acc[mt][nt][rg];
        if (outMode==0){
          outF[(size_t)mrow*ldc + nglob] = val;
        } else if (outMode==1){          // r -> SEQ slot 0
          int b=mrow>>10, t=mrow&1023, h=nglob>>6, i=nglob&63;
          SEQf[(((size_t)(b*16+h)*1024+t)*384) + i] = val;
        } else if (outMode==2){          // decay -> SEQ slot 1
          float w = bias[nglob] + val;
          float d = expf(-expf(w));
          int b=mrow>>10, t=mrow&1023, h=nglob>>6, i=nglob&63;
          SEQf[(((size_t)(b*16+h)*1024+t)*384) + 64 + i] = d;
        } else {                          // sigmoid(bias+acc)
          float s = 1.0f/(1.0f+__expf(-(bias[nglob]+val)));
          outF[(size_t)mrow*ldc + nglob] = s;
        }
      }
    }
  }
}

// ---------------- prep2: build SEQ slots k,v,a,b ----------------
__global__ __launch_bounds__(256) void prep2_kernel(char* ws, const float* vfirst,
  const float* kk_s, const float* ka_s)
{
  const float* KQF=(const float*)(ws+OFF_KQF);
  const float* VQF=(const float*)(ws+OFF_VQF);
  const float* ICLR=(const float*)(ws+OFF_S2A);
  const float* VMIX=(const float*)(ws+OFF_S2V);
  float* SEQf=(float*)(ws+OFF_SEQ);
  int m=blockIdx.x, b=m>>10, t=m&1023;
  int tid=threadIdx.x, c0=tid*4, h=c0>>6, i0=c0&63, hk=h>>1;
  f32x4 kq=*(const f32x4*)(KQF+(size_t)m*512+hk*64+i0);
  f32x4 vq=*(const f32x4*)(VQF+(size_t)m*512+hk*64+i0);
  f32x4 ic=*(const f32x4*)(ICLR+(size_t)m*1024+c0);
  f32x4 vm=*(const f32x4*)(VMIX+(size_t)m*1024+c0);
  f32x4 vf=*(const f32x4*)(vfirst+(size_t)m*1024+c0);
  f32x4 kkc=*(const f32x4*)(kk_s+c0);
  f32x4 kac=*(const f32x4*)(ka_s+c0);
  f32x4 kk=kq*kkc;
  float ssq=kk[0]*kk[0]+kk[1]*kk[1]+kk[2]*kk[2]+kk[3]*kk[3];
  #pragma unroll
  for (int mk=1;mk<16;mk<<=1) ssq += __shfl_xor(ssq,mk);
  float scale = 1.0f / fmaxf(sqrtf(ssq), 1e-12f);
  f32x4 kf,vv,av,bv;
  #pragma unroll
  for (int j=0;j<4;j++){
    float icc = 1.0f + (ic[j]-1.0f)*kac[j];
    float kkn = kk[j]*scale;
    kf[j]=kq[j]*icc;
    vv[j]=vq[j] + (vf[j]-vq[j])*vm[j];
    av[j]=-kkn;
    bv[j]=kkn*icc;
  }
  size_t sb = (((size_t)(b*16+h)*1024)+t)*384 + i0;
  *(f32x4*)(SEQf+sb+128)=kf;
  *(f32x4*)(SEQf+sb+192)=vv;
  *(f32x4*)(SEQf+sb+256)=av;
  *(f32x4*)(SEQf+sb+320)=bv;
}

// ---------------- the sequential wkv scan ----------------
__global__ __launch_bounds__(256) void scan_kernel(char* ws, const float* S0, float* dout){
  const float* SEQ=(const float*)(ws+OFF_SEQ);
  float* YB=(float*)(ws+OFF_YBUF);
  int bh=blockIdx.x;
  int tid=threadIdx.x, l=tid&63, wq=tid>>6;
  const float* seqb = SEQ + (size_t)bh*(1024*384);
  float S[16];
  {
    const float* s0 = S0 + (size_t)bh*4096 + (size_t)l*64 + wq*16;
    #pragma unroll
    for (int j=0;j<16;j++) S[j]=s0[j];
  }
  __shared__ float vec[2][384];
  __shared__ float redsa[4][64];
  __shared__ float redy[4][64];
  for (int i=tid;i<384;i+=256) vec[0][i]=seqb[i];
  __syncthreads();
  for (int t=0;t<1024;++t){
    const float* vcur = vec[t&1];
    if (t+1<1024){
      const float* g = seqb + (size_t)(t+1)*384;
      float* dst = vec[(t+1)&1];
      for (int i=tid;i<384;i+=256) dst[i]=g[i];
    }
    const float* aslice = vcur + 256 + wq*16;
    float p=0.f;
    #pragma unroll
    for (int j=0;j<16;j++) p += S[j]*aslice[j];
    redsa[wq][l]=p;
    __syncthreads();
    float sa = redsa[0][l]+redsa[1][l]+redsa[2][l]+redsa[3][l];
    float vl = vcur[192+l];
    const float* rs  = vcur + wq*16;
    const float* wsl = vcur + 64 + wq*16;
    const float* ks  = vcur + 128 + wq*16;
    const float* bs  = vcur + 320 + wq*16;
    float yp=0.f;
    #pragma unroll
    for (int j=0;j<16;j++){
      float sj = S[j]*wsl[j] + sa*bs[j] + vl*ks[j];
      S[j]=sj;
      yp += sj*rs[j];
    }
    redy[wq][l]=yp;
    __syncthreads();
    if (wq==0)
      YB[(size_t)bh*65536 + (size_t)t*64 + l] = redy[0][l]+redy[1][l]+redy[2][l]+redy[3][l];
  }
  float* So = dout + 2097152 + (size_t)bh*4096 + (size_t)l*64 + wq*16;
  #pragma unroll
  for (int j=0;j<16;j++) So[j]=S[j];
}

// ---------------- epilogue: groupnorm + bonus + gate -> bf16 ----------------
__global__ __launch_bounds__(256) void epi_kernel(char* ws, const float* rk,
  const float* lnw, const float* lnb)
{
  const float* YB=(const float*)(ws+OFF_YBUF);
  const float* SEQf=(const float*)(ws+OFF_SEQ);
  const float* GB=(const float*)(ws+OFF_GBUF);
  u16* XGB=(u16*)(ws+OFF_XGB);
  int m=blockIdx.x, b=m>>10, t=m&1023;
  int tid=threadIdx.x, c0=tid*4, h=c0>>6, i0=c0&63;
  f32x4 y=*(const f32x4*)(YB + ((size_t)(b*16+h)*1024+t)*64 + i0);
  float s = y[0]+y[1]+y[2]+y[3];
  float ss= y[0]*y[0]+y[1]*y[1]+y[2]*y[2]+y[3]*y[3];
  #pragma unroll
  for (int mk=1;mk<16;mk<<=1){ s+=__shfl_xor(s,mk); ss+=__shfl_xor(ss,mk); }
  float mu=s*(1.0f/64.0f), var=ss*(1.0f/64.0f)-mu*mu;
  float inv=rsqrtf(var + 6.4e-4f);
  size_t sb=((size_t)(b*16+h)*1024+t)*384;
  f32x4 r=*(const f32x4*)(SEQf+sb+i0);
  f32x4 k=*(const f32x4*)(SEQf+sb+128+i0);
  f32x4 v=*(const f32x4*)(SEQf+sb+192+i0);
  f32x4 q=*(const f32x4*)(rk + h*64 + i0);
  float dp = r[0]*k[0]*q[0]+r[1]*k[1]*q[1]+r[2]*k[2]*q[2]+r[3]*k[3]*q[3];
  #pragma unroll
  for (int mk=1;mk<16;mk<<=1) dp+=__shfl_xor(dp,mk);
  f32x4 g=*(const f32x4*)(GB+(size_t)m*1024+c0);
  u16x4 outv;
  #pragma unroll
  for (int j=0;j<4;j++){
    float xn = (y[j]-mu)*inv*lnw[c0+j] + lnb[c0+j] + dp*v[j];
    outv[j]=f2bf(xn*g[j]);
  }
  *(u16x4*)(XGB+(size_t)m*1024+c0)=outv;
}

extern "C" void kernel_launch(void* const* d_in, const int* in_sizes, int n_in,
                              void* d_out, int out_size, void* d_ws, size_t ws_size,
                              hipStream_t stream) {
  const float* x      =(const float*)d_in[0];
  const float* S0     =(const float*)d_in[1];
  const float* vfirst =(const float*)d_in[2];
  const float* w0     =(const float*)d_in[3];
  const float* w1     =(const float*)d_in[4];
  const float* w2     =(const float*)d_in[5];
  const float* a0     =(const float*)d_in[6];
  const float* a1     =(const float*)d_in[7];
  const float* a2     =(const float*)d_in[8];
  const float* v0     =(const float*)d_in[9];
  const float* v1     =(const float*)d_in[10];
  const float* v2     =(const float*)d_in[11];
  const float* g1     =(const float*)d_in[12];
  const float* g2     =(const float*)d_in[13];
  const float* k_k    =(const float*)d_in[14];
  const float* k_a    =(const float*)d_in[15];
  const float* r_k    =(const float*)d_in[16];
  const float* Wq     =(const float*)d_in[17];
  const float* Wk     =(const float*)d_in[18];
  const float* Wv     =(const float*)d_in[19];
  const float* Wo     =(const float*)d_in[20];
  const float* ln_w   =(const float*)d_in[21];
  const float* ln_b   =(const float*)d_in[22];
  char* ws=(char*)d_ws;
  float* dout=(float*)d_out;

  prep_kernel<<<2048,256,0,stream>>>(ws,x,vfirst,w1,w2,a1,a2,v1,v2,g1,g2,Wq,Wk,Wv,Wo,dout);
  gemm_kernel<<<dim3(16,19),256,0,stream>>>(0,ws,w0,a0,v0,dout);
  act_kernel<<<3072,256,0,stream>>>(ws);
  gemm_kernel<<<dim3(16,32),256,0,stream>>>(1,ws,w0,a0,v0,dout);
  prep2_kernel<<<2048,256,0,stream>>>(ws,vfirst,k_k,k_a);
  scan_kernel<<<32,256,0,stream>>>(ws,S0,dout);
  epi_kernel<<<2048,256,0,stream>>>(ws,r_k,ln_w,ln_b);
  gemm_kernel<<<dim3(16,8),256,0,stream>>>(2,ws,w0,a0,v0,dout);
}

// Round 2
// 645.129 us; speedup vs baseline: 1.9561x; 1.9561x over previous
//
#include <hip/hip_runtime.h>

typedef unsigned short u16;
typedef __attribute__((ext_vector_type(8))) short s16x8;
typedef __attribute__((ext_vector_type(4))) float f32x4;
typedef __attribute__((ext_vector_type(4))) int   i32x4;
typedef __attribute__((ext_vector_type(4))) unsigned short u16x4;

// ---------------- workspace layout (bytes) ----------------
constexpr size_t OFF_XB   = 0;                     // bf16 x          [2048][1024]
constexpr size_t OFF_WQB  = OFF_XB   + 4194304;    // bf16 Wq         [1024][1024]
constexpr size_t OFF_WKB  = OFF_WQB  + 2097152;    // bf16 Wk         [512][1024]
constexpr size_t OFF_WVB  = OFF_WKB  + 1048576;    // bf16 Wv         [512][1024]
constexpr size_t OFF_WOB  = OFF_WVB  + 1048576;    // bf16 Wo         [1024][1024]
constexpr size_t OFF_W1T  = OFF_WOB  + 2097152;    // bf16 W1T        [384][1024] (rows 320..383 zero)
constexpr size_t OFF_W2T  = OFF_W1T  + 786432;     // bf16 w2T        [1024][64]
constexpr size_t OFF_A2T  = OFF_W2T  + 131072;     // bf16 a2T        [1024][64]
constexpr size_t OFF_V2T  = OFF_A2T  + 131072;     // bf16 v2T        [1024][32]
constexpr size_t OFF_G2T  = OFF_V2T  + 65536;      // bf16 g2T        [1024][160]
constexpr size_t OFF_KQF  = OFF_G2T  + 327680;     // f32 k-proj      [2048][512]
constexpr size_t OFF_VQF  = OFF_KQF  + 4194304;    // f32 v-proj      [2048][512]
constexpr size_t OFF_URAW = OFF_VQF  + 4194304;    // f32 stage1 raw  [2048][320]
constexpr size_t OFF_UB   = OFF_URAW + 2621440;    // bf16 stage1 act [2048][384]
constexpr size_t OFF_S2A  = OFF_UB   + 1572864;    // f32 iclr        [2048][1024]
constexpr size_t OFF_S2V  = OFF_S2A  + 8388608;    // f32 vmix        [2048][1024]
constexpr size_t OFF_GBUF = OFF_S2V  + 8388608;    // f32 gate        [2048][1024]
constexpr size_t OFF_SEQ  = OFF_GBUF + 8388608;    // f32 SEQ [2][16][1024][6][64] (r,decay,k,v,a,b)
constexpr size_t OFF_YBUF = OFF_SEQ  + 50331648;   // f32 y   [2][16][1024][64]
constexpr size_t OFF_XGB  = OFF_YBUF + 8388608;    // bf16 xn*g       [2048][1024]

__device__ __forceinline__ u16 f2bf(float f){
  unsigned int u = __builtin_bit_cast(unsigned int, f);
  u = u + 0x7fffu + ((u >> 16) & 1u);
  return (u16)(u >> 16);
}

__device__ __forceinline__ void gload_lds16(const float* g, float* l){
  __builtin_amdgcn_global_load_lds((const __attribute__((address_space(1))) void*)g,
                                   (__attribute__((address_space(3))) void*)l, 16, 0, 0);
}
__device__ __forceinline__ void gload_lds4(const float* g, float* l){
  __builtin_amdgcn_global_load_lds((const __attribute__((address_space(1))) void*)g,
                                   (__attribute__((address_space(3))) void*)l, 4, 0, 0);
}

// ---------------- prep: convert/transpose + v_first passthrough ----------------
constexpr size_t N_XB=2097152, N_WQ=1048576, N_WK=524288, N_WV=524288, N_WO=1048576,
  N_W1T=393216, N_W2T=65536, N_A2T=65536, N_V2T=32768, N_G2T=163840, N_VF=2097152;
constexpr size_t PREP_TOT = N_XB+N_WQ+N_WK+N_WV+N_WO+N_W1T+N_W2T+N_A2T+N_V2T+N_G2T+N_VF;

__global__ __launch_bounds__(256) void prep_kernel(char* ws, const float* x, const float* vfirst,
  const float* w1, const float* w2, const float* a1, const float* a2,
  const float* v1, const float* v2, const float* g1, const float* g2,
  const float* Wq, const float* Wk, const float* Wv, const float* Wo, float* dout)
{
  u16* XB=(u16*)(ws+OFF_XB); u16* WQB=(u16*)(ws+OFF_WQB); u16* WKB=(u16*)(ws+OFF_WKB);
  u16* WVB=(u16*)(ws+OFF_WVB); u16* WOB=(u16*)(ws+OFF_WOB); u16* W1T=(u16*)(ws+OFF_W1T);
  u16* W2T=(u16*)(ws+OFF_W2T); u16* A2T=(u16*)(ws+OFF_A2T); u16* V2T=(u16*)(ws+OFF_V2T);
  u16* G2T=(u16*)(ws+OFF_G2T);
  for (size_t idx=(size_t)blockIdx.x*256+threadIdx.x; idx<PREP_TOT; idx+=(size_t)gridDim.x*256){
    size_t r = idx;
    if (r < N_XB){ XB[r]=f2bf(x[r]); continue; } r-=N_XB;
    if (r < N_WQ){ WQB[r]=f2bf(Wq[r]); continue; } r-=N_WQ;
    if (r < N_WK){ WKB[r]=f2bf(Wk[r]); continue; } r-=N_WK;
    if (r < N_WV){ WVB[r]=f2bf(Wv[r]); continue; } r-=N_WV;
    if (r < N_WO){ WOB[r]=f2bf(Wo[r]); continue; } r-=N_WO;
    if (r < N_W1T){
      int n=(int)(r>>10), k=(int)(r&1023); float v=0.f;
      if (n<64) v=w1[(size_t)k*64+n];
      else if (n<128) v=a1[(size_t)k*64+(n-64)];
      else if (n<160) v=v1[(size_t)k*32+(n-128)];
      else if (n<320) v=g1[(size_t)k*160+(n-160)];
      W1T[r]=f2bf(v); continue; } r-=N_W1T;
    if (r < N_W2T){ int c=(int)(r>>6), d=(int)(r&63); W2T[r]=f2bf(w2[(size_t)d*1024+c]); continue; } r-=N_W2T;
    if (r < N_A2T){ int c=(int)(r>>6), d=(int)(r&63); A2T[r]=f2bf(a2[(size_t)d*1024+c]); continue; } r-=N_A2T;
    if (r < N_V2T){ int c=(int)(r>>5), d=(int)(r&31); V2T[r]=f2bf(v2[(size_t)d*1024+c]); continue; } r-=N_V2T;
    if (r < N_G2T){ int c=(int)(r/160), d=(int)(r%160); G2T[r]=f2bf(g2[(size_t)d*1024+c]); continue; } r-=N_G2T;
    dout[2228224 + r] = vfirst[r];   // v_first passthrough (offset 2097152+131072)
  }
}

// ---------------- activation for stage-1 ----------------
__global__ __launch_bounds__(256) void act_kernel(char* ws){
  const float* URAW=(const float*)(ws+OFF_URAW);
  u16* UB=(u16*)(ws+OFF_UB);
  size_t idx=(size_t)blockIdx.x*256+threadIdx.x;   // grid covers 2048*384 exactly
  int m=(int)(idx/384), n=(int)(idx%384);
  float v=0.f;
  if (n<64)       v = tanhf(URAW[(size_t)m*320+n]);
  else if (n<160) v = URAW[(size_t)m*320+n];
  else if (n<320) v = 1.0f/(1.0f+__expf(-URAW[(size_t)m*320+n]));
  UB[idx]=f2bf(v);
}

// ---------------- unified NT bf16 MFMA GEMM: C[m][n] = sum_k A[m][k]*B[n][k] ----------------
__global__ __launch_bounds__(256) void gemm_kernel(int phase, char* ws,
  const float* w0b, const float* a0b, const float* v0b, float* dout)
{
  const u16* A; const u16* Bw;
  float* outF=nullptr; const float* bias=nullptr;
  float* SEQf=(float*)(ws+OFF_SEQ);
  int lda=0, ldb=0, K=0, ldc=0, Nlim=1024, col0=0, outMode=0;
  int y = blockIdx.y;
  if (phase==0){
    A=(const u16*)(ws+OFF_XB); lda=1024; K=1024;
    if (y<8)      { Bw=(const u16*)(ws+OFF_WQB); ldb=1024; col0=y*128;       outMode=1; }
    else if (y<12){ Bw=(const u16*)(ws+OFF_WKB); ldb=1024; col0=(y-8)*128;   outF=(float*)(ws+OFF_KQF); ldc=512; Nlim=512; }
    else if (y<16){ Bw=(const u16*)(ws+OFF_WVB); ldb=1024; col0=(y-12)*128;  outF=(float*)(ws+OFF_VQF); ldc=512; Nlim=512; }
    else          { Bw=(const u16*)(ws+OFF_W1T); ldb=1024; col0=(y-16)*128;  outF=(float*)(ws+OFF_URAW); ldc=320; Nlim=320; }
  } else if (phase==1){
    int seg=y>>3; col0=(y&7)*128;
    const int Ks[4]={64,64,32,160};
    const int Ao[4]={0,64,128,160};
    K=Ks[seg]; lda=384; ldb=K;
    A=(const u16*)(ws+OFF_UB) + Ao[seg];
    if (seg==0)     { Bw=(const u16*)(ws+OFF_W2T); outMode=2; bias=w0b; }
    else if (seg==1){ Bw=(const u16*)(ws+OFF_A2T); outMode=3; bias=a0b; outF=(float*)(ws+OFF_S2A); ldc=1024; }
    else if (seg==2){ Bw=(const u16*)(ws+OFF_V2T); outMode=3; bias=v0b; outF=(float*)(ws+OFF_S2V); ldc=1024; }
    else            { Bw=(const u16*)(ws+OFF_G2T); outF=(float*)(ws+OFF_GBUF); ldc=1024; }
  } else {
    A=(const u16*)(ws+OFF_XGB); lda=1024; K=1024;
    Bw=(const u16*)(ws+OFF_WOB); ldb=1024; col0=y*128; outF=dout; ldc=1024;
  }
  int m0 = blockIdx.x*128;
  __shared__ __align__(16) u16 As[128][40];
  __shared__ __align__(16) u16 Bs[128][40];
  int tid=threadIdx.x, l=tid&63, wv=tid>>6, wm=wv>>1, wn=wv&1;
  f32x4 acc[4][4];
  #pragma unroll
  for (int i=0;i<4;i++)
    #pragma unroll
    for (int j=0;j<4;j++) acc[i][j]=(f32x4){0.f,0.f,0.f,0.f};

  for (int k0=0;k0<K;k0+=32){
    #pragma unroll
    for (int c=tid;c<512;c+=256){
      int row=c>>2, seg=c&3;
      *(i32x4*)(&As[row][seg*8]) = *(const i32x4*)(A  + (size_t)(m0+row)*lda  + k0 + seg*8);
      *(i32x4*)(&Bs[row][seg*8]) = *(const i32x4*)(Bw + (size_t)(col0+row)*ldb + k0 + seg*8);
    }
    __syncthreads();
    int kseg=(l>>4)*8, rrow=l&15;
    s16x8 af[4], bf[4];
    #pragma unroll
    for (int mt=0;mt<4;mt++) af[mt]=*(const s16x8*)(&As[wm*64+mt*16+rrow][kseg]);
    #pragma unroll
    for (int nt=0;nt<4;nt++) bf[nt]=*(const s16x8*)(&Bs[wn*64+nt*16+rrow][kseg]);
    #pragma unroll
    for (int mt=0;mt<4;mt++)
      #pragma unroll
      for (int nt=0;nt<4;nt++)
        acc[mt][nt]=__builtin_amdgcn_mfma_f32_16x16x32_bf16(af[mt],bf[nt],acc[mt][nt],0,0,0);
    __syncthreads();
  }
  // epilogue
  #pragma unroll
  for (int mt=0;mt<4;mt++){
    #pragma unroll
    for (int nt=0;nt<4;nt++){
      int nglob = col0 + wn*64 + nt*16 + (l&15);
      if (nglob >= Nlim) continue;
      #pragma unroll
      for (int rg=0;rg<4;rg++){
        int mrow = m0 + wm*64 + mt*16 + ((l>>4)<<2) + rg;
        float val = acc[mt][nt][rg];
        if (outMode==0){
          outF[(size_t)mrow*ldc + nglob] = val;
        } else if (outMode==1){          // r -> SEQ slot 0
          int b=mrow>>10, t=mrow&1023, h=nglob>>6, i=nglob&63;
          SEQf[(((size_t)(b*16+h)*1024+t)*384) + i] = val;
        } else if (outMode==2){          // decay -> SEQ slot 1
          float w = bias[nglob] + val;
          float d = expf(-expf(w));
          int b=mrow>>10, t=mrow&1023, h=nglob>>6, i=nglob&63;
          SEQf[(((size_t)(b*16+h)*1024+t)*384) + 64 + i] = d;
        } else {                          // sigmoid(bias+acc)
          float s = 1.0f/(1.0f+__expf(-(bias[nglob]+val)));
          outF[(size_t)mrow*ldc + nglob] = s;
        }
      }
    }
  }
}

// ---------------- prep2: build SEQ slots k,v,a,b ----------------
__global__ __launch_bounds__(256) void prep2_kernel(char* ws, const float* vfirst,
  const float* kk_s, const float* ka_s)
{
  const float* KQF=(const float*)(ws+OFF_KQF);
  const float* VQF=(const float*)(ws+OFF_VQF);
  const float* ICLR=(const float*)(ws+OFF_S2A);
  const float* VMIX=(const float*)(ws+OFF_S2V);
  float* SEQf=(float*)(ws+OFF_SEQ);
  int m=blockIdx.x, b=m>>10, t=m&1023;
  int tid=threadIdx.x, c0=tid*4, h=c0>>6, i0=c0&63, hk=h>>1;
  f32x4 kq=*(const f32x4*)(KQF+(size_t)m*512+hk*64+i0);
  f32x4 vq=*(const f32x4*)(VQF+(size_t)m*512+hk*64+i0);
  f32x4 ic=*(const f32x4*)(ICLR+(size_t)m*1024+c0);
  f32x4 vm=*(const f32x4*)(VMIX+(size_t)m*1024+c0);
  f32x4 vf=*(const f32x4*)(vfirst+(size_t)m*1024+c0);
  f32x4 kkc=*(const f32x4*)(kk_s+c0);
  f32x4 kac=*(const f32x4*)(ka_s+c0);
  f32x4 kk=kq*kkc;
  float ssq=kk[0]*kk[0]+kk[1]*kk[1]+kk[2]*kk[2]+kk[3]*kk[3];
  #pragma unroll
  for (int mk=1;mk<16;mk<<=1) ssq += __shfl_xor(ssq,mk);
  float scale = 1.0f / fmaxf(sqrtf(ssq), 1e-12f);
  f32x4 kf,vv,av,bv;
  #pragma unroll
  for (int j=0;j<4;j++){
    float icc = 1.0f + (ic[j]-1.0f)*kac[j];
    float kkn = kk[j]*scale;
    kf[j]=kq[j]*icc;
    vv[j]=vq[j] + (vf[j]-vq[j])*vm[j];
    av[j]=-kkn;
    bv[j]=kkn*icc;
  }
  size_t sb = (((size_t)(b*16+h)*1024)+t)*384 + i0;
  *(f32x4*)(SEQf+sb+128)=kf;
  *(f32x4*)(SEQf+sb+192)=vv;
  *(f32x4*)(SEQf+sb+256)=av;
  *(f32x4*)(SEQf+sb+320)=bv;
}

// ---------------- the sequential wkv scan (barrier-free, shfl reductions) ----------------
// block = 1 head = 4 waves. wave w owns rows i in [16w,16w+16).
// lane l: i = 16w + (l&15), j-slice = [16*(l>>4), 16*(l>>4)+16).
// Each wave stages its head's per-step 384-float vector into a private
// 8-slot LDS ring via global_load_lds; ordering via hand-counted vmcnt
// once per 4-step group. No __syncthreads anywhere.
__global__ __launch_bounds__(256) void scan_kernel(char* ws, const float* S0, float* dout){
  const float* SEQ=(const float*)(ws+OFF_SEQ);
  float* YB=(float*)(ws+OFF_YBUF);
  int bh=blockIdx.x;
  int tid=threadIdx.x;
  int wid=tid>>6, l=tid&63, jq=l>>4, il=l&15;
  const float* seqb = SEQ + (size_t)bh*(1024*384);
  __shared__ __align__(16) float ring[4][8][384];   // 48 KiB
  float* wring = &ring[wid][0][0];

  float S[16];
  {
    const float* s0 = S0 + (size_t)bh*4096 + (size_t)(16*wid+il)*64 + 16*jq;
    #pragma unroll
    for (int j=0;j<16;j++) S[j]=s0[j];
  }

  // prologue: stage steps 0..7 (3 loads per step: 16B x64 lanes + 2x 4B x64)
  #pragma unroll
  for (int t=0;t<8;t++){
    const float* src = seqb + (size_t)t*384;
    float* dst = wring + t*384;
    gload_lds16(src + l*4, dst);
    gload_lds4 (src + 256 + l, dst + 256);
    gload_lds4 (src + 320 + l, dst + 320);
  }
  asm volatile("s_waitcnt vmcnt(12)" ::: "memory");   // steps 0..3 resident

  float* ybase = YB + (size_t)bh*65536 + 16*wid + il;

  for (int g=0; g<256; ++g){
    // slots for steps 4g..4g+3 resident: 12 newer loads + 4 newer stores outstanding max
    asm volatile("s_waitcnt vmcnt(16)" ::: "memory");
    __builtin_amdgcn_sched_barrier(0);
    int tbase = g*4;
    #pragma unroll
    for (int s=0;s<4;s++){
      int t = tbase + s;
      const float* vb = wring + (t&7)*384;
      f32x4 rv[4], wv[4], kv[4], av[4], bv[4];
      #pragma unroll
      for (int q=0;q<4;q++){
        rv[q] = *(const f32x4*)(vb       + jq*16 + q*4);
        wv[q] = *(const f32x4*)(vb + 64  + jq*16 + q*4);
        kv[q] = *(const f32x4*)(vb + 128 + jq*16 + q*4);
        av[q] = *(const f32x4*)(vb + 256 + jq*16 + q*4);
        bv[q] = *(const f32x4*)(vb + 320 + jq*16 + q*4);
      }
      float vsc = vb[192 + 16*wid + il];
      float p[4]={0.f,0.f,0.f,0.f};
      #pragma unroll
      for (int q=0;q<4;q++)
        #pragma unroll
        for (int e=0;e<4;e++) p[e] += S[q*4+e]*av[q][e];
      float sa=(p[0]+p[1])+(p[2]+p[3]);
      sa += __shfl_xor(sa,16); sa += __shfl_xor(sa,32);
      float ya[4]={0.f,0.f,0.f,0.f};
      #pragma unroll
      for (int q=0;q<4;q++)
        #pragma unroll
        for (int e=0;e<4;e++){
          float sj = S[q*4+e]*wv[q][e] + sa*bv[q][e] + vsc*kv[q][e];
          S[q*4+e]=sj;
          ya[e] += sj*rv[q][e];
        }
      float yp=(ya[0]+ya[1])+(ya[2]+ya[3]);
      yp += __shfl_xor(yp,16); yp += __shfl_xor(yp,32);
      if (jq==0) ybase[(size_t)t*64] = yp;
    }
    // issue staging for group g+2 (steps 4g+8..4g+11); clamp src at tail so the
    // per-group vmcnt arithmetic stays exact (dest slots are dead at tail).
    #pragma unroll
    for (int s=0;s<4;s++){
      int t = tbase + 8 + s;
      int tsrc = t < 1024 ? t : 1023;
      const float* src = seqb + (size_t)tsrc*384;
      float* dst = wring + (t&7)*384;
      gload_lds16(src + l*4, dst);
      gload_lds4 (src + 256 + l, dst + 256);
      gload_lds4 (src + 320 + l, dst + 320);
    }
  }

  float* So = dout + 2097152 + (size_t)bh*4096 + (size_t)(16*wid+il)*64 + 16*jq;
  #pragma unroll
  for (int q=0;q<4;q++) *(f32x4*)(So + q*4) = (f32x4){S[q*4],S[q*4+1],S[q*4+2],S[q*4+3]};
}

// ---------------- epilogue: groupnorm + bonus + gate -> bf16 ----------------
__global__ __launch_bounds__(256) void epi_kernel(char* ws, const float* rk,
  const float* lnw, const float* lnb)
{
  const float* YB=(const float*)(ws+OFF_YBUF);
  const float* SEQf=(const float*)(ws+OFF_SEQ);
  const float* GB=(const float*)(ws+OFF_GBUF);
  u16* XGB=(u16*)(ws+OFF_XGB);
  int m=blockIdx.x, b=m>>10, t=m&1023;
  int tid=threadIdx.x, c0=tid*4, h=c0>>6, i0=c0&63;
  f32x4 y=*(const f32x4*)(YB + ((size_t)(b*16+h)*1024+t)*64 + i0);
  float s = y[0]+y[1]+y[2]+y[3];
  float ss= y[0]*y[0]+y[1]*y[1]+y[2]*y[2]+y[3]*y[3];
  #pragma unroll
  for (int mk=1;mk<16;mk<<=1){ s+=__shfl_xor(s,mk); ss+=__shfl_xor(ss,mk); }
  float mu=s*(1.0f/64.0f), var=ss*(1.0f/64.0f)-mu*mu;
  float inv=rsqrtf(var + 6.4e-4f);
  size_t sb=((size_t)(b*16+h)*1024+t)*384;
  f32x4 r=*(const f32x4*)(SEQf+sb+i0);
  f32x4 k=*(const f32x4*)(SEQf+sb+128+i0);
  f32x4 v=*(const f32x4*)(SEQf+sb+192+i0);
  f32x4 q=*(const f32x4*)(rk + h*64 + i0);
  float dp = r[0]*k[0]*q[0]+r[1]*k[1]*q[1]+r[2]*k[2]*q[2]+r[3]*k[3]*q[3];
  #pragma unroll
  for (int mk=1;mk<16;mk<<=1) dp+=__shfl_xor(dp,mk);
  f32x4 g=*(const f32x4*)(GB+(size_t)m*1024+c0);
  u16x4 outv;
  #pragma unroll
  for (int j=0;j<4;j++){
    float xn = (y[j]-mu)*inv*lnw[c0+j] + lnb[c0+j] + dp*v[j];
    outv[j]=f2bf(xn*g[j]);
  }
  *(u16x4*)(XGB+(size_t)m*1024+c0)=outv;
}

extern "C" void kernel_launch(void* const* d_in, const int* in_sizes, int n_in,
                              void* d_out, int out_size, void* d_ws, size_t ws_size,
                              hipStream_t stream) {
  const float* x      =(const float*)d_in[0];
  const float* S0     =(const float*)d_in[1];
  const float* vfirst =(const float*)d_in[2];
  const float* w0     =(const float*)d_in[3];
  const float* w1     =(const float*)d_in[4];
  const float* w2     =(const float*)d_in[5];
  const float* a0     =(const float*)d_in[6];
  const float* a1     =(const float*)d_in[7];
  const float* a2     =(const float*)d_in[8];
  const float* v0     =(const float*)d_in[9];
  const float* v1     =(const float*)d_in[10];
  const float* v2     =(const float*)d_in[11];
  const float* g1     =(const float*)d_in[12];
  const float* g2     =(const float*)d_in[13];
  const float* k_k    =(const float*)d_in[14];
  const float* k_a    =(const float*)d_in[15];
  const float* r_k    =(const float*)d_in[16];
  const float* Wq     =(const float*)d_in[17];
  const float* Wk     =(const float*)d_in[18];
  const float* Wv     =(const float*)d_in[19];
  const float* Wo     =(const float*)d_in[20];
  const float* ln_w   =(const float*)d_in[21];
  const float* ln_b   =(const float*)d_in[22];
  char* ws=(char*)d_ws;
  float* dout=(float*)d_out;

  prep_kernel<<<2048,256,0,stream>>>(ws,x,vfirst,w1,w2,a1,a2,v1,v2,g1,g2,Wq,Wk,Wv,Wo,dout);
  gemm_kernel<<<dim3(16,19),256,0,stream>>>(0,ws,w0,a0,v0,dout);
  act_kernel<<<3072,256,0,stream>>>(ws);
  gemm_kernel<<<dim3(16,32),256,0,stream>>>(1,ws,w0,a0,v0,dout);
  prep2_kernel<<<2048,256,0,stream>>>(ws,vfirst,k_k,k_a);
  scan_kernel<<<32,256,0,stream>>>(ws,S0,dout);
  epi_kernel<<<2048,256,0,stream>>>(ws,r_k,ln_w,ln_b);
  gemm_kernel<<<dim3(16,8),256,0,stream>>>(2,ws,w0,a0,v0,dout);
}

// Round 4
// 449.730 us; speedup vs baseline: 2.8060x; 1.4345x over previous
//
#include <hip/hip_runtime.h>

typedef unsigned short u16;
typedef __attribute__((ext_vector_type(8))) short s16x8;
typedef __attribute__((ext_vector_type(4))) float f32x4;
typedef __attribute__((ext_vector_type(4))) int   i32x4;
typedef __attribute__((ext_vector_type(2))) int   i32x2;
typedef __attribute__((ext_vector_type(4))) unsigned short u16x4;

// ---------------- workspace layout (bytes) ----------------
constexpr size_t OFF_XB   = 0;                     // bf16 x          [2048][1024]
constexpr size_t OFF_WQB  = OFF_XB   + 4194304;    // bf16 Wq         [1024][1024]
constexpr size_t OFF_WKB  = OFF_WQB  + 2097152;    // bf16 Wk         [512][1024]
constexpr size_t OFF_WVB  = OFF_WKB  + 1048576;    // bf16 Wv         [512][1024]
constexpr size_t OFF_WOB  = OFF_WVB  + 1048576;    // bf16 Wo         [1024][1024]
constexpr size_t OFF_W1T  = OFF_WOB  + 2097152;    // bf16 W1T        [384][1024] (rows 320..383 zero)
constexpr size_t OFF_W2T  = OFF_W1T  + 786432;     // bf16 w2T        [1024][64]
constexpr size_t OFF_A2T  = OFF_W2T  + 131072;     // bf16 a2T        [1024][64]
constexpr size_t OFF_V2T  = OFF_A2T  + 131072;     // bf16 v2T        [1024][32]
constexpr size_t OFF_G2T  = OFF_V2T  + 65536;      // bf16 g2T        [1024][160]
constexpr size_t OFF_KQF  = OFF_G2T  + 327680;     // f32 k-proj      [2048][512]
constexpr size_t OFF_VQF  = OFF_KQF  + 4194304;    // f32 v-proj      [2048][512]
constexpr size_t OFF_URAW = OFF_VQF  + 4194304;    // f32 stage1 raw  [2048][320]
constexpr size_t OFF_UB   = OFF_URAW + 2621440;    // bf16 stage1 act [2048][384]
constexpr size_t OFF_S2A  = OFF_UB   + 1572864;    // f32 iclr        [2048][1024]
constexpr size_t OFF_S2V  = OFF_S2A  + 8388608;    // f32 vmix        [2048][1024]
constexpr size_t OFF_GBUF = OFF_S2V  + 8388608;    // f32 gate        [2048][1024]
constexpr size_t OFF_SEQ  = OFF_GBUF + 8388608;    // f32 SEQ [2][16][1024][6][64] (r,decay,k,v,a,b)
constexpr size_t OFF_YBUF = OFF_SEQ  + 50331648;   // f32 y   [2][16][1024][64]
constexpr size_t OFF_XGB  = OFF_YBUF + 8388608;    // bf16 xn*g       [2048][1024]

__device__ __forceinline__ u16 f2bf(float f){
  unsigned int u = __builtin_bit_cast(unsigned int, f);
  u = u + 0x7fffu + ((u >> 16) & 1u);
  return (u16)(u >> 16);
}
__device__ __forceinline__ int pk2(float a, float b){
  return (int)((unsigned)f2bf(a) | ((unsigned)f2bf(b) << 16));
}

__device__ __forceinline__ void gload_lds16(const float* g, float* l){
  __builtin_amdgcn_global_load_lds((const __attribute__((address_space(1))) void*)g,
                                   (__attribute__((address_space(3))) void*)l, 16, 0, 0);
}
__device__ __forceinline__ void gload_lds4(const float* g, float* l){
  __builtin_amdgcn_global_load_lds((const __attribute__((address_space(1))) void*)g,
                                   (__attribute__((address_space(3))) void*)l, 4, 0, 0);
}

// ---------------- prep: convert/transpose + v_first passthrough ----------------
constexpr size_t N_XB=2097152, N_WQ=1048576, N_WK=524288, N_WV=524288, N_WO=1048576,
  N_W1T=393216, N_W2T=65536, N_A2T=65536, N_V2T=32768, N_G2T=163840, N_VF=2097152;
constexpr size_t PREP_TOT = N_XB+N_WQ+N_WK+N_WV+N_WO+N_W1T+N_W2T+N_A2T+N_V2T+N_G2T+N_VF;

__global__ __launch_bounds__(256) void prep_kernel(char* ws, const float* x, const float* vfirst,
  const float* w1, const float* w2, const float* a1, const float* a2,
  const float* v1, const float* v2, const float* g1, const float* g2,
  const float* Wq, const float* Wk, const float* Wv, const float* Wo, float* dout)
{
  u16* XB=(u16*)(ws+OFF_XB); u16* WQB=(u16*)(ws+OFF_WQB); u16* WKB=(u16*)(ws+OFF_WKB);
  u16* WVB=(u16*)(ws+OFF_WVB); u16* WOB=(u16*)(ws+OFF_WOB); u16* W1T=(u16*)(ws+OFF_W1T);
  u16* W2T=(u16*)(ws+OFF_W2T); u16* A2T=(u16*)(ws+OFF_A2T); u16* V2T=(u16*)(ws+OFF_V2T);
  u16* G2T=(u16*)(ws+OFF_G2T);
  for (size_t idx=(size_t)blockIdx.x*256+threadIdx.x; idx<PREP_TOT; idx+=(size_t)gridDim.x*256){
    size_t r = idx;
    if (r < N_XB){ XB[r]=f2bf(x[r]); continue; } r-=N_XB;
    if (r < N_WQ){ WQB[r]=f2bf(Wq[r]); continue; } r-=N_WQ;
    if (r < N_WK){ WKB[r]=f2bf(Wk[r]); continue; } r-=N_WK;
    if (r < N_WV){ WVB[r]=f2bf(Wv[r]); continue; } r-=N_WV;
    if (r < N_WO){ WOB[r]=f2bf(Wo[r]); continue; } r-=N_WO;
    if (r < N_W1T){
      int n=(int)(r>>10), k=(int)(r&1023); float v=0.f;
      if (n<64) v=w1[(size_t)k*64+n];
      else if (n<128) v=a1[(size_t)k*64+(n-64)];
      else if (n<160) v=v1[(size_t)k*32+(n-128)];
      else if (n<320) v=g1[(size_t)k*160+(n-160)];
      W1T[r]=f2bf(v); continue; } r-=N_W1T;
    if (r < N_W2T){ int c=(int)(r>>6), d=(int)(r&63); W2T[r]=f2bf(w2[(size_t)d*1024+c]); continue; } r-=N_W2T;
    if (r < N_A2T){ int c=(int)(r>>6), d=(int)(r&63); A2T[r]=f2bf(a2[(size_t)d*1024+c]); continue; } r-=N_A2T;
    if (r < N_V2T){ int c=(int)(r>>5), d=(int)(r&31); V2T[r]=f2bf(v2[(size_t)d*1024+c]); continue; } r-=N_V2T;
    if (r < N_G2T){ int c=(int)(r/160), d=(int)(r%160); G2T[r]=f2bf(g2[(size_t)d*1024+c]); continue; } r-=N_G2T;
    dout[2228224 + r] = vfirst[r];   // v_first passthrough (offset 2097152+131072)
  }
}

// ---------------- activation for stage-1 ----------------
__global__ __launch_bounds__(256) void act_kernel(char* ws){
  const float* URAW=(const float*)(ws+OFF_URAW);
  u16* UB=(u16*)(ws+OFF_UB);
  size_t idx=(size_t)blockIdx.x*256+threadIdx.x;   // grid covers 2048*384 exactly
  int m=(int)(idx/384), n=(int)(idx%384);
  float v=0.f;
  if (n<64)       v = tanhf(URAW[(size_t)m*320+n]);
  else if (n<160) v = URAW[(size_t)m*320+n];
  else if (n<320) v = 1.0f/(1.0f+__expf(-URAW[(size_t)m*320+n]));
  UB[idx]=f2bf(v);
}

// ---------------- unified NT bf16 MFMA GEMM: C[m][n] = sum_k A[m][k]*B[n][k] ----------------
__global__ __launch_bounds__(256) void gemm_kernel(int phase, char* ws,
  const float* w0b, const float* a0b, const float* v0b, float* dout)
{
  const u16* A; const u16* Bw;
  float* outF=nullptr; const float* bias=nullptr;
  float* SEQf=(float*)(ws+OFF_SEQ);
  int lda=0, ldb=0, K=0, ldc=0, Nlim=1024, col0=0, outMode=0;
  int y = blockIdx.y;
  if (phase==0){
    A=(const u16*)(ws+OFF_XB); lda=1024; K=1024;
    if (y<8)      { Bw=(const u16*)(ws+OFF_WQB); ldb=1024; col0=y*128;       outMode=1; }
    else if (y<12){ Bw=(const u16*)(ws+OFF_WKB); ldb=1024; col0=(y-8)*128;   outF=(float*)(ws+OFF_KQF); ldc=512; Nlim=512; }
    else if (y<16){ Bw=(const u16*)(ws+OFF_WVB); ldb=1024; col0=(y-12)*128;  outF=(float*)(ws+OFF_VQF); ldc=512; Nlim=512; }
    else          { Bw=(const u16*)(ws+OFF_W1T); ldb=1024; col0=(y-16)*128;  outF=(float*)(ws+OFF_URAW); ldc=320; Nlim=320; }
  } else if (phase==1){
    int seg=y>>3; col0=(y&7)*128;
    const int Ks[4]={64,64,32,160};
    const int Ao[4]={0,64,128,160};
    K=Ks[seg]; lda=384; ldb=K;
    A=(const u16*)(ws+OFF_UB) + Ao[seg];
    if (seg==0)     { Bw=(const u16*)(ws+OFF_W2T); outMode=2; bias=w0b; }
    else if (seg==1){ Bw=(const u16*)(ws+OFF_A2T); outMode=3; bias=a0b; outF=(float*)(ws+OFF_S2A); ldc=1024; }
    else if (seg==2){ Bw=(const u16*)(ws+OFF_V2T); outMode=3; bias=v0b; outF=(float*)(ws+OFF_S2V); ldc=1024; }
    else            { Bw=(const u16*)(ws+OFF_G2T); outF=(float*)(ws+OFF_GBUF); ldc=1024; }
  } else {
    A=(const u16*)(ws+OFF_XGB); lda=1024; K=1024;
    Bw=(const u16*)(ws+OFF_WOB); ldb=1024; col0=y*128; outF=dout; ldc=1024;
  }
  int m0 = blockIdx.x*128;
  __shared__ __align__(16) u16 As[128][40];
  __shared__ __align__(16) u16 Bs[128][40];
  int tid=threadIdx.x, l=tid&63, wv=tid>>6, wm=wv>>1, wn=wv&1;
  f32x4 acc[4][4];
  #pragma unroll
  for (int i=0;i<4;i++)
    #pragma unroll
    for (int j=0;j<4;j++) acc[i][j]=(f32x4){0.f,0.f,0.f,0.f};

  for (int k0=0;k0<K;k0+=32){
    #pragma unroll
    for (int c=tid;c<512;c+=256){
      int row=c>>2, seg=c&3;
      *(i32x4*)(&As[row][seg*8]) = *(const i32x4*)(A  + (size_t)(m0+row)*lda  + k0 + seg*8);
      *(i32x4*)(&Bs[row][seg*8]) = *(const i32x4*)(Bw + (size_t)(col0+row)*ldb + k0 + seg*8);
    }
    __syncthreads();
    int kseg=(l>>4)*8, rrow=l&15;
    s16x8 af[4], bf[4];
    #pragma unroll
    for (int mt=0;mt<4;mt++) af[mt]=*(const s16x8*)(&As[wm*64+mt*16+rrow][kseg]);
    #pragma unroll
    for (int nt=0;nt<4;nt++) bf[nt]=*(const s16x8*)(&Bs[wn*64+nt*16+rrow][kseg]);
    #pragma unroll
    for (int mt=0;mt<4;mt++)
      #pragma unroll
      for (int nt=0;nt<4;nt++)
        acc[mt][nt]=__builtin_amdgcn_mfma_f32_16x16x32_bf16(af[mt],bf[nt],acc[mt][nt],0,0,0);
    __syncthreads();
  }
  // epilogue
  #pragma unroll
  for (int mt=0;mt<4;mt++){
    #pragma unroll
    for (int nt=0;nt<4;nt++){
      int nglob = col0 + wn*64 + nt*16 + (l&15);
      if (nglob >= Nlim) continue;
      #pragma unroll
      for (int rg=0;rg<4;rg++){
        int mrow = m0 + wm*64 + mt*16 + ((l>>4)<<2) + rg;
        float val = acc[mt][nt][rg];
        if (outMode==0){
          outF[(size_t)mrow*ldc + nglob] = val;
        } else if (outMode==1){          // r -> SEQ slot 0
          int b=mrow>>10, t=mrow&1023, h=nglob>>6, i=nglob&63;
          SEQf[(((size_t)(b*16+h)*1024+t)*384) + i] = val;
        } else if (outMode==2){          // decay -> SEQ slot 1
          float w = bias[nglob] + val;
          float d = expf(-expf(w));
          int b=mrow>>10, t=mrow&1023, h=nglob>>6, i=nglob&63;
          SEQf[(((size_t)(b*16+h)*1024+t)*384) + 64 + i] = d;
        } else {                          // sigmoid(bias+acc)
          float s = 1.0f/(1.0f+__expf(-(bias[nglob]+val)));
          outF[(size_t)mrow*ldc + nglob] = s;
        }
      }
    }
  }
}

// ---------------- prep2: build SEQ slots k,v,a,b ----------------
__global__ __launch_bounds__(256) void prep2_kernel(char* ws, const float* vfirst,
  const float* kk_s, const float* ka_s)
{
  const float* KQF=(const float*)(ws+OFF_KQF);
  const float* VQF=(const float*)(ws+OFF_VQF);
  const float* ICLR=(const float*)(ws+OFF_S2A);
  const float* VMIX=(const float*)(ws+OFF_S2V);
  float* SEQf=(float*)(ws+OFF_SEQ);
  int m=blockIdx.x, b=m>>10, t=m&1023;
  int tid=threadIdx.x, c0=tid*4, h=c0>>6, i0=c0&63, hk=h>>1;
  f32x4 kq=*(const f32x4*)(KQF+(size_t)m*512+hk*64+i0);
  f32x4 vq=*(const f32x4*)(VQF+(size_t)m*512+hk*64+i0);
  f32x4 ic=*(const f32x4*)(ICLR+(size_t)m*1024+c0);
  f32x4 vm=*(const f32x4*)(VMIX+(size_t)m*1024+c0);
  f32x4 vf=*(const f32x4*)(vfirst+(size_t)m*1024+c0);
  f32x4 kkc=*(const f32x4*)(kk_s+c0);
  f32x4 kac=*(const f32x4*)(ka_s+c0);
  f32x4 kk=kq*kkc;
  float ssq=kk[0]*kk[0]+kk[1]*kk[1]+kk[2]*kk[2]+kk[3]*kk[3];
  #pragma unroll
  for (int mk=1;mk<16;mk<<=1) ssq += __shfl_xor(ssq,mk);
  float scale = 1.0f / fmaxf(sqrtf(ssq), 1e-12f);
  f32x4 kf,vv,av,bv;
  #pragma unroll
  for (int j=0;j<4;j++){
    float icc = 1.0f + (ic[j]-1.0f)*kac[j];
    float kkn = kk[j]*scale;
    kf[j]=kq[j]*icc;
    vv[j]=vq[j] + (vf[j]-vq[j])*vm[j];
    av[j]=-kkn;
    bv[j]=kkn*icc;
  }
  size_t sb = (((size_t)(b*16+h)*1024)+t)*384 + i0;
  *(f32x4*)(SEQf+sb+128)=kf;
  *(f32x4*)(SEQf+sb+192)=vv;
  *(f32x4*)(SEQf+sb+256)=av;
  *(f32x4*)(SEQf+sb+320)=bv;
}

// ---------------- chunked WY wkv scan ----------------
// 1 wave per (b,h), 32 blocks. L=16 chunk, 64 chunks serial.
// State kept as S^T[j][i] per lane in D-frag layout: lane (c,g) holds
// Sreg[Mt][J][e] = S[i=16J+c][j=16Mt+4g+e]  (f32, exact decay path),
// plus bf16 copy in LDS Sbf[i][j] for MFMA B-operand use.
#define MFMA32(a,b,c) __builtin_amdgcn_mfma_f32_16x16x32_bf16(a,b,c,0,0,0)

__global__ __launch_bounds__(64) void scan_kernel(char* ws, const float* S0, float* dout){
  const float* SEQ=(const float*)(ws+OFF_SEQ);
  float* YB=(float*)(ws+OFF_YBUF);
  int bh=blockIdx.x;
  int l=threadIdx.x, c16=l&15, g=l>>4;
  const float* seqb = SEQ + (size_t)bh*(1024*384);

  __shared__ __align__(16) float raw[16*396];      // padded raw chunk [t][396]
  __shared__ __align__(16) float pbuf[16*68];      // cumulative decay p_t[c]
  __shared__ __align__(16) u16 AT[16*72];          // a~^T [t][j]
  __shared__ __align__(16) u16 RT[16*72];          // r~^T [t][j]
  __shared__ __align__(16) u16 BT[16*72];          // b~   [s][j]
  __shared__ __align__(16) u16 KT[16*72];          // k~   [s][j]
  __shared__ __align__(16) u16 vbb[64*24+16];      // v    [i][t]
  __shared__ __align__(16) u16 bar[64*24+16];      // bbar [j][s]
  __shared__ __align__(16) u16 kar[64*24+16];      // kbar [j][s]
  __shared__ __align__(16) u16 zbb[64*24+16];      // z    [i][s]
  __shared__ __align__(16) u16 Sbf[64*72];         // bf16 S [i][j]
  __shared__ __align__(16) float WN[16*17];        // N[t][s] (f32, fsub)
  __shared__ __align__(16) u16 WY[16*24+16];       // Yhat^T[t][s] (s<t)
  __shared__ __align__(16) u16 WB[16*24+16];       // Tb[t][s] (s<=t)
  __shared__ __align__(16) u16 WK[16*24+16];       // Tk[t][s] (s<=t)
  __shared__ __align__(16) float rhsb[16*68];      // rhs^T [t][i]

  const s16x8 zero8 = {0,0,0,0,0,0,0,0};

  // ---- prologue: load S0 into Sreg + Sbf, stage chunk 0 ----
  f32x4 Sreg[4][4];
  #pragma unroll
  for (int Mt=0;Mt<4;Mt++)
    #pragma unroll
    for (int J=0;J<4;J++)
      Sreg[Mt][J] = *(const f32x4*)(S0 + (size_t)bh*4096 + (size_t)(16*J+c16)*64 + 16*Mt + 4*g);
  #pragma unroll
  for (int Mt=0;Mt<4;Mt++)
    #pragma unroll
    for (int J=0;J<4;J++){
      i32x2 w2v; w2v[0]=pk2(Sreg[Mt][J][0],Sreg[Mt][J][1]); w2v[1]=pk2(Sreg[Mt][J][2],Sreg[Mt][J][3]);
      *(i32x2*)(&Sbf[(16*J+c16)*72 + 16*Mt + 4*g]) = w2v;
    }
  #pragma unroll
  for (int t=0;t<16;t++){
    const float* src = seqb + (size_t)t*384;
    float* dst = &raw[t*396];
    gload_lds16(src + l*4, dst);
    gload_lds4 (src + 256 + l, dst + 256);
    gload_lds4 (src + 320 + l, dst + 320);
  }
  asm volatile("s_waitcnt vmcnt(0)" ::: "memory");

  #pragma unroll 1
  for (int ch=0; ch<64; ++ch){
    asm volatile("s_waitcnt vmcnt(16)" ::: "memory");
    __builtin_amdgcn_sched_barrier(0);

    // ---- P1a: lane = channel l. cumprod decay; write p, vbb, bar, kar ----
    {
      float ptv[16]; float pp=1.f;
      #pragma unroll
      for (int t=0;t<16;t++){ pp *= raw[t*396+64+l]; ptv[t]=pp; pbuf[t*68+l]=pp; }
      float pL = ptv[15];
      float bs[16], ks[16], vs[16];
      #pragma unroll
      for (int t=0;t<16;t++){
        float sc = pL * __builtin_amdgcn_rcpf(ptv[t]);
        bs[t]=raw[t*396+320+l]*sc;
        ks[t]=raw[t*396+128+l]*sc;
        vs[t]=raw[t*396+192+l];
      }
      i32x4 o;
      o[0]=pk2(vs[0],vs[1]); o[1]=pk2(vs[2],vs[3]); o[2]=pk2(vs[4],vs[5]); o[3]=pk2(vs[6],vs[7]);
      *(i32x4*)(&vbb[l*24]) = o;
      o[0]=pk2(vs[8],vs[9]); o[1]=pk2(vs[10],vs[11]); o[2]=pk2(vs[12],vs[13]); o[3]=pk2(vs[14],vs[15]);
      *(i32x4*)(&vbb[l*24+8]) = o;
      o[0]=pk2(bs[0],bs[1]); o[1]=pk2(bs[2],bs[3]); o[2]=pk2(bs[4],bs[5]); o[3]=pk2(bs[6],bs[7]);
      *(i32x4*)(&bar[l*24]) = o;
      o[0]=pk2(bs[8],bs[9]); o[1]=pk2(bs[10],bs[11]); o[2]=pk2(bs[12],bs[13]); o[3]=pk2(bs[14],bs[15]);
      *(i32x4*)(&bar[l*24+8]) = o;
      o[0]=pk2(ks[0],ks[1]); o[1]=pk2(ks[2],ks[3]); o[2]=pk2(ks[4],ks[5]); o[3]=pk2(ks[6],ks[7]);
      *(i32x4*)(&kar[l*24]) = o;
      o[0]=pk2(ks[8],ks[9]); o[1]=pk2(ks[10],ks[11]); o[2]=pk2(ks[12],ks[13]); o[3]=pk2(ks[14],ks[15]);
      *(i32x4*)(&kar[l*24+8]) = o;
    }

    // ---- P1b: lane = (t=c16, group g -> channels 16g..16g+15). write AT,RT,BT,KT ----
    {
      int tt=c16, gg=g;
      f32x4 pa[4], pp[4];
      int tp = (tt==0)?0:(tt-1);
      #pragma unroll
      for (int q=0;q<4;q++){
        pa[q] = *(const f32x4*)(&pbuf[tt*68 + 16*gg + 4*q]);
        pp[q] = *(const f32x4*)(&pbuf[tp*68 + 16*gg + 4*q]);
      }
      if (tt==0){
        #pragma unroll
        for (int q=0;q<4;q++) pp[q] = (f32x4){1.f,1.f,1.f,1.f};
      }
      f32x4 ra[4], rr[4], rb[4], rk[4];
      #pragma unroll
      for (int q=0;q<4;q++){
        ra[q]=*(const f32x4*)(&raw[tt*396+256+16*gg+4*q]);
        rr[q]=*(const f32x4*)(&raw[tt*396+    16*gg+4*q]);
        rb[q]=*(const f32x4*)(&raw[tt*396+320+16*gg+4*q]);
        rk[q]=*(const f32x4*)(&raw[tt*396+128+16*gg+4*q]);
      }
      float va[16], vr[16], vb2[16], vk2[16];
      #pragma unroll
      for (int q=0;q<4;q++)
        #pragma unroll
        for (int e=0;e<4;e++){
          float rp = __builtin_amdgcn_rcpf(pa[q][e]);
          va[q*4+e] = pp[q][e]*ra[q][e];
          vr[q*4+e] = pa[q][e]*rr[q][e];
          vb2[q*4+e] = rb[q][e]*rp;
          vk2[q*4+e] = rk[q][e]*rp;
        }
      i32x4 o;
      o[0]=pk2(va[0],va[1]); o[1]=pk2(va[2],va[3]); o[2]=pk2(va[4],va[5]); o[3]=pk2(va[6],va[7]);
      *(i32x4*)(&AT[tt*72+16*gg]) = o;
      o[0]=pk2(va[8],va[9]); o[1]=pk2(va[10],va[11]); o[2]=pk2(va[12],va[13]); o[3]=pk2(va[14],va[15]);
      *(i32x4*)(&AT[tt*72+16*gg+8]) = o;
      o[0]=pk2(vr[0],vr[1]); o[1]=pk2(vr[2],vr[3]); o[2]=pk2(vr[4],vr[5]); o[3]=pk2(vr[6],vr[7]);
      *(i32x4*)(&RT[tt*72+16*gg]) = o;
      o[0]=pk2(vr[8],vr[9]); o[1]=pk2(vr[10],vr[11]); o[2]=pk2(vr[12],vr[13]); o[3]=pk2(vr[14],vr[15]);
      *(i32x4*)(&RT[tt*72+16*gg+8]) = o;
      o[0]=pk2(vb2[0],vb2[1]); o[1]=pk2(vb2[2],vb2[3]); o[2]=pk2(vb2[4],vb2[5]); o[3]=pk2(vb2[6],vb2[7]);
      *(i32x4*)(&BT[tt*72+16*gg]) = o;
      o[0]=pk2(vb2[8],vb2[9]); o[1]=pk2(vb2[10],vb2[11]); o[2]=pk2(vb2[12],vb2[13]); o[3]=pk2(vb2[14],vb2[15]);
      *(i32x4*)(&BT[tt*72+16*gg+8]) = o;
      o[0]=pk2(vk2[0],vk2[1]); o[1]=pk2(vk2[2],vk2[3]); o[2]=pk2(vk2[4],vk2[5]); o[3]=pk2(vk2[6],vk2[7]);
      *(i32x4*)(&KT[tt*72+16*gg]) = o;
      o[0]=pk2(vk2[8],vk2[9]); o[1]=pk2(vk2[10],vk2[11]); o[2]=pk2(vk2[12],vk2[13]); o[3]=pk2(vk2[14],vk2[15]);
      *(i32x4*)(&KT[tt*72+16*gg+8]) = o;
    }

    // ---- issue next chunk's staging (raw fully consumed) ----
    asm volatile("s_waitcnt lgkmcnt(0)" ::: "memory");
    {
      int nch = (ch<63)?(ch+1):63;
      const float* nsrc = seqb + (size_t)nch*6144;
      #pragma unroll
      for (int t=0;t<16;t++){
        const float* src = nsrc + (size_t)t*384;
        float* dst = &raw[t*396];
        gload_lds16(src + l*4, dst);
        gload_lds4 (src + 256 + l, dst + 256);
        gload_lds4 (src + 320 + l, dst + 320);
      }
      __builtin_amdgcn_sched_barrier(0);
      asm volatile("" ::: "memory");
    }

    // ---- W-block: fused [A~;R~]^T x [B~,K~]  (all [t][s]) ----
    s16x8 afA[2], afR[2];
    {
      s16x8 bfB[2], bfK[2];
      #pragma unroll
      for (int Kt=0;Kt<2;Kt++){
        afA[Kt]=*(const s16x8*)(&AT[c16*72 + 32*Kt + 8*g]);
        afR[Kt]=*(const s16x8*)(&RT[c16*72 + 32*Kt + 8*g]);
        bfB[Kt]=*(const s16x8*)(&BT[c16*72 + 32*Kt + 8*g]);
        bfK[Kt]=*(const s16x8*)(&KT[c16*72 + 32*Kt + 8*g]);
      }
      f32x4 dNN={0.f,0.f,0.f,0.f}, dNY=dNN, dBB=dNN, dBK=dNN;
      #pragma unroll
      for (int Kt=0;Kt<2;Kt++){
        dNN=MFMA32(afA[Kt],bfB[Kt],dNN);
        dNY=MFMA32(afA[Kt],bfK[Kt],dNY);
        dBB=MFMA32(afR[Kt],bfB[Kt],dBB);
        dBK=MFMA32(afR[Kt],bfK[Kt],dBK);
      }
      #pragma unroll
      for (int e=0;e<4;e++){
        int tR=4*g+e, sC=c16;
        WN[tR*17+sC] = dNN[e];
        WY[tR*24+sC] = (sC<tR)? f2bf(dNY[e]) : (u16)0;
        WB[tR*24+sC] = (sC<=tR)? f2bf(dBB[e]) : (u16)0;
        WK[tR*24+sC] = (sC<=tR)? f2bf(dBK[e]) : (u16)0;
      }
    }

    // ---- job1: RHS^T = A~^T C^T, Y1^T = R~^T C^T  (C = chunk-start state, bf16) ----
    f32x4 dR[4], dY[4];
    #pragma unroll
    for (int J=0;J<4;J++){ dR[J]=(f32x4){0.f,0.f,0.f,0.f}; dY[J]=dR[J]; }
    {
      #pragma unroll
      for (int Kt=0;Kt<2;Kt++){
        #pragma unroll
        for (int J=0;J<4;J++){
          s16x8 sf = *(const s16x8*)(&Sbf[(16*J+c16)*72 + 32*Kt + 8*g]);
          dR[J]=MFMA32(afA[Kt],sf,dR[J]);
          dY[J]=MFMA32(afR[Kt],sf,dY[J]);
        }
      }
    }
    // RHS += Yhat^T V^T
    s16x8 vf[4];
    #pragma unroll
    for (int J=0;J<4;J++){
      vf[J]=zero8;
      if (g<2) vf[J]=*(const s16x8*)(&vbb[(16*J+c16)*24 + 8*g]);
    }
    {
      s16x8 wyf=zero8;
      if (g<2) wyf=*(const s16x8*)(&WY[c16*24 + 8*g]);
      #pragma unroll
      for (int J=0;J<4;J++) dR[J]=MFMA32(wyf,vf[J],dR[J]);
    }
    #pragma unroll
    for (int J=0;J<4;J++)
      #pragma unroll
      for (int e=0;e<4;e++)
        rhsb[(4*g+e)*68 + 16*J + c16] = dR[J][e];

    // ---- forward substitution: z(I - N) = rhs, lane = channel i=l ----
    {
      float zz[16];
      #pragma unroll
      for (int t=0;t<16;t++) zz[t]=rhsb[t*68+l];
      #pragma unroll
      for (int t=1;t<16;t++)
        #pragma unroll
        for (int s=0;s<16;s++){
          if (s<t) zz[t] += WN[t*17+s]*zz[s];
        }
      i32x4 o;
      o[0]=pk2(zz[0],zz[1]); o[1]=pk2(zz[2],zz[3]); o[2]=pk2(zz[4],zz[5]); o[3]=pk2(zz[6],zz[7]);
      *(i32x4*)(&zbb[l*24]) = o;
      o[0]=pk2(zz[8],zz[9]); o[1]=pk2(zz[10],zz[11]); o[2]=pk2(zz[12],zz[13]); o[3]=pk2(zz[14],zz[15]);
      *(i32x4*)(&zbb[l*24+8]) = o;
    }

    // ---- job4: Y^T += Tb Z^T + Tk V^T ; store y ----
    s16x8 zf[4];
    #pragma unroll
    for (int J=0;J<4;J++){
      zf[J]=zero8;
      if (g<2) zf[J]=*(const s16x8*)(&zbb[(16*J+c16)*24 + 8*g]);
    }
    {
      s16x8 wbf=zero8, wkf=zero8;
      if (g<2){
        wbf=*(const s16x8*)(&WB[c16*24 + 8*g]);
        wkf=*(const s16x8*)(&WK[c16*24 + 8*g]);
      }
      #pragma unroll
      for (int J=0;J<4;J++){
        dY[J]=MFMA32(wbf,zf[J],dY[J]);
        dY[J]=MFMA32(wkf,vf[J],dY[J]);
      }
    }
    {
      float* yb = YB + (size_t)bh*65536 + (size_t)(ch*16)*64;
      #pragma unroll
      for (int J=0;J<4;J++)
        #pragma unroll
        for (int e=0;e<4;e++)
          yb[(size_t)(4*g+e)*64 + 16*J + c16] = dY[J][e];
    }

    // ---- S update: S^T = diag(pL) S^T + Bbar Z^T + Kbar V^T ----
    {
      #pragma unroll
      for (int Mt=0;Mt<4;Mt++){
        f32x4 plv = *(const f32x4*)(&pbuf[15*68 + 16*Mt + 4*g]);
        #pragma unroll
        for (int J=0;J<4;J++)
          #pragma unroll
          for (int e=0;e<4;e++) Sreg[Mt][J][e] *= plv[e];
      }
      #pragma unroll
      for (int Mt=0;Mt<4;Mt++){
        s16x8 barf=zero8, karf=zero8;
        if (g<2){
          barf=*(const s16x8*)(&bar[(16*Mt+c16)*24 + 8*g]);
          karf=*(const s16x8*)(&kar[(16*Mt+c16)*24 + 8*g]);
        }
        #pragma unroll
        for (int J=0;J<4;J++){
          Sreg[Mt][J]=MFMA32(barf,zf[J],Sreg[Mt][J]);
          Sreg[Mt][J]=MFMA32(karf,vf[J],Sreg[Mt][J]);
        }
      }
      #pragma unroll
      for (int Mt=0;Mt<4;Mt++)
        #pragma unroll
        for (int J=0;J<4;J++){
          i32x2 w2v; w2v[0]=pk2(Sreg[Mt][J][0],Sreg[Mt][J][1]); w2v[1]=pk2(Sreg[Mt][J][2],Sreg[Mt][J][3]);
          *(i32x2*)(&Sbf[(16*J+c16)*72 + 16*Mt + 4*g]) = w2v;
        }
    }
  }

  // ---- final state out ----
  #pragma unroll
  for (int Mt=0;Mt<4;Mt++)
    #pragma unroll
    for (int J=0;J<4;J++)
      *(f32x4*)(dout + 2097152 + (size_t)bh*4096 + (size_t)(16*J+c16)*64 + 16*Mt + 4*g) = Sreg[Mt][J];
}

// ---------------- epilogue: groupnorm + bonus + gate -> bf16 ----------------
__global__ __launch_bounds__(256) void epi_kernel(char* ws, const float* rk,
  const float* lnw, const float* lnb)
{
  const float* YB=(const float*)(ws+OFF_YBUF);
  const float* SEQf=(const float*)(ws+OFF_SEQ);
  const float* GB=(const float*)(ws+OFF_GBUF);
  u16* XGB=(u16*)(ws+OFF_XGB);
  int m=blockIdx.x, b=m>>10, t=m&1023;
  int tid=threadIdx.x, c0=tid*4, h=c0>>6, i0=c0&63;
  f32x4 y=*(const f32x4*)(YB + ((size_t)(b*16+h)*1024+t)*64 + i0);
  float s = y[0]+y[1]+y[2]+y[3];
  float ss= y[0]*y[0]+y[1]*y[1]+y[2]*y[2]+y[3]*y[3];
  #pragma unroll
  for (int mk=1;mk<16;mk<<=1){ s+=__shfl_xor(s,mk); ss+=__shfl_xor(ss,mk); }
  float mu=s*(1.0f/64.0f), var=ss*(1.0f/64.0f)-mu*mu;
  float inv=rsqrtf(var + 6.4e-4f);
  size_t sb=((size_t)(b*16+h)*1024+t)*384;
  f32x4 r=*(const f32x4*)(SEQf+sb+i0);
  f32x4 k=*(const f32x4*)(SEQf+sb+128+i0);
  f32x4 v=*(const f32x4*)(SEQf+sb+192+i0);
  f32x4 q=*(const f32x4*)(rk + h*64 + i0);
  float dp = r[0]*k[0]*q[0]+r[1]*k[1]*q[1]+r[2]*k[2]*q[2]+r[3]*k[3]*q[3];
  #pragma unroll
  for (int mk=1;mk<16;mk<<=1) dp+=__shfl_xor(dp,mk);
  f32x4 g=*(const f32x4*)(GB+(size_t)m*1024+c0);
  u16x4 outv;
  #pragma unroll
  for (int j=0;j<4;j++){
    float xn = (y[j]-mu)*inv*lnw[c0+j] + lnb[c0+j] + dp*v[j];
    outv[j]=f2bf(xn*g[j]);
  }
  *(u16x4*)(XGB+(size_t)m*1024+c0)=outv;
}

extern "C" void kernel_launch(void* const* d_in, const int* in_sizes, int n_in,
                              void* d_out, int out_size, void* d_ws, size_t ws_size,
                              hipStream_t stream) {
  const float* x      =(const float*)d_in[0];
  const float* S0     =(const float*)d_in[1];
  const float* vfirst =(const float*)d_in[2];
  const float* w0     =(const float*)d_in[3];
  const float* w1     =(const float*)d_in[4];
  const float* w2     =(const float*)d_in[5];
  const float* a0     =(const float*)d_in[6];
  const float* a1     =(const float*)d_in[7];
  const float* a2     =(const float*)d_in[8];
  const float* v0     =(const float*)d_in[9];
  const float* v1     =(const float*)d_in[10];
  const float* v2     =(const float*)d_in[11];
  const float* g1     =(const float*)d_in[12];
  const float* g2     =(const float*)d_in[13];
  const float* k_k    =(const float*)d_in[14];
  const float* k_a    =(const float*)d_in[15];
  const float* r_k    =(const float*)d_in[16];
  const float* Wq     =(const float*)d_in[17];
  const float* Wk     =(const float*)d_in[18];
  const float* Wv     =(const float*)d_in[19];
  const float* Wo     =(const float*)d_in[20];
  const float* ln_w   =(const float*)d_in[21];
  const float* ln_b   =(const float*)d_in[22];
  char* ws=(char*)d_ws;
  float* dout=(float*)d_out;

  prep_kernel<<<2048,256,0,stream>>>(ws,x,vfirst,w1,w2,a1,a2,v1,v2,g1,g2,Wq,Wk,Wv,Wo,dout);
  gemm_kernel<<<dim3(16,19),256,0,stream>>>(0,ws,w0,a0,v0,dout);
  act_kernel<<<3072,256,0,stream>>>(ws);
  gemm_kernel<<<dim3(16,32),256,0,stream>>>(1,ws,w0,a0,v0,dout);
  prep2_kernel<<<2048,256,0,stream>>>(ws,vfirst,k_k,k_a);
  scan_kernel<<<32,64,0,stream>>>(ws,S0,dout);
  epi_kernel<<<2048,256,0,stream>>>(ws,r_k,ln_w,ln_b);
  gemm_kernel<<<dim3(16,8),256,0,stream>>>(2,ws,w0,a0,v0,dout);
}

// Round 5
// 290.154 us; speedup vs baseline: 4.3492x; 1.5500x over previous
//
#include <hip/hip_runtime.h>

typedef unsigned short u16;
typedef __attribute__((ext_vector_type(8))) short s16x8;
typedef __attribute__((ext_vector_type(4))) float f32x4;
typedef __attribute__((ext_vector_type(4))) int   i32x4;
typedef __attribute__((ext_vector_type(2))) int   i32x2;
typedef __attribute__((ext_vector_type(4))) unsigned short u16x4;

// ---------------- workspace layout (bytes) ----------------
constexpr size_t OFF_XB   = 0;                     // bf16 x          [2048][1024]
constexpr size_t OFF_WQB  = OFF_XB   + 4194304;    // bf16 Wq         [1024][1024]
constexpr size_t OFF_WKB  = OFF_WQB  + 2097152;    // bf16 Wk         [512][1024]
constexpr size_t OFF_WVB  = OFF_WKB  + 1048576;    // bf16 Wv         [512][1024]
constexpr size_t OFF_WOB  = OFF_WVB  + 1048576;    // bf16 Wo         [1024][1024]
constexpr size_t OFF_W1T  = OFF_WOB  + 2097152;    // bf16 W1T [384][1024]; reused later as PL array
constexpr size_t OFF_W2T  = OFF_W1T  + 786432;     // bf16 w2T        [1024][64]
constexpr size_t OFF_A2T  = OFF_W2T  + 131072;     // bf16 a2T        [1024][64]
constexpr size_t OFF_V2T  = OFF_A2T  + 131072;     // bf16 v2T        [1024][32]
constexpr size_t OFF_G2T  = OFF_V2T  + 65536;      // bf16 g2T        [1024][160]
constexpr size_t OFF_KQF  = OFF_G2T  + 327680;     // f32 k-proj [2048][512]; reused as chunk records
constexpr size_t OFF_VQF  = OFF_KQF  + 4194304;    // f32 v-proj      [2048][512]
constexpr size_t OFF_URAW = OFF_VQF  + 4194304;    // f32 stage1 raw  [2048][320]
constexpr size_t OFF_UB   = OFF_URAW + 2621440;    // bf16 stage1 act [2048][384]
constexpr size_t OFF_S2A  = OFF_UB   + 1572864;    // f32 iclr        [2048][1024]
constexpr size_t OFF_S2V  = OFF_S2A  + 8388608;    // f32 vmix        [2048][1024]
constexpr size_t OFF_GBUF = OFF_S2V  + 8388608;    // f32 gate        [2048][1024]
constexpr size_t OFF_SEQ  = OFF_GBUF + 8388608;    // f32 SEQ [2][16][1024][6][64] (r,decay,k,v,a,b)
constexpr size_t OFF_YBUF = OFF_SEQ  + 50331648;   // f32 y   [2][16][1024][64]
constexpr size_t OFF_XGB  = OFF_YBUF + 8388608;    // bf16 xn*g       [2048][1024]

// chunk record overlay (dead KQF..S2V window, 2048 records x 14336B = exact fit)
constexpr size_t OFF_REC  = OFF_KQF;   // per record: P_f 0, G_f 2048, zloc_f 4096, Yloc_f 6144,
                                       //             bar_f 8192, kar_f 10240, V_f 12288
constexpr size_t OFF_PL   = OFF_W1T;   // f32 pL [2048][64]

__device__ __forceinline__ u16 f2bf(float f){
  unsigned int u = __builtin_bit_cast(unsigned int, f);
  u = u + 0x7fffu + ((u >> 16) & 1u);
  return (u16)(u >> 16);
}
__device__ __forceinline__ int pk2(float a, float b){
  return (int)((unsigned)f2bf(a) | ((unsigned)f2bf(b) << 16));
}
__device__ __forceinline__ float bf2f(u16 h){
  return __builtin_bit_cast(float, ((unsigned)h) << 16);
}
__device__ __forceinline__ f32x4 cvt4(i32x2 v){
  unsigned a=(unsigned)v[0], b=(unsigned)v[1];
  f32x4 r;
  r[0]=__builtin_bit_cast(float, a<<16);
  r[1]=__builtin_bit_cast(float, a&0xffff0000u);
  r[2]=__builtin_bit_cast(float, b<<16);
  r[3]=__builtin_bit_cast(float, b&0xffff0000u);
  return r;
}

__device__ __forceinline__ void gload_lds16(const float* g, float* l){
  __builtin_amdgcn_global_load_lds((const __attribute__((address_space(1))) void*)g,
                                   (__attribute__((address_space(3))) void*)l, 16, 0, 0);
}
__device__ __forceinline__ void gload_lds4(const float* g, float* l){
  __builtin_amdgcn_global_load_lds((const __attribute__((address_space(1))) void*)g,
                                   (__attribute__((address_space(3))) void*)l, 4, 0, 0);
}

// ---------------- prep: convert/transpose + v_first passthrough ----------------
constexpr size_t N_XB=2097152, N_WQ=1048576, N_WK=524288, N_WV=524288, N_WO=1048576,
  N_W1T=393216, N_W2T=65536, N_A2T=65536, N_V2T=32768, N_G2T=163840, N_VF=2097152;
constexpr size_t PREP_TOT = N_XB+N_WQ+N_WK+N_WV+N_WO+N_W1T+N_W2T+N_A2T+N_V2T+N_G2T+N_VF;

__global__ __launch_bounds__(256) void prep_kernel(char* ws, const float* x, const float* vfirst,
  const float* w1, const float* w2, const float* a1, const float* a2,
  const float* v1, const float* v2, const float* g1, const float* g2,
  const float* Wq, const float* Wk, const float* Wv, const float* Wo, float* dout)
{
  u16* XB=(u16*)(ws+OFF_XB); u16* WQB=(u16*)(ws+OFF_WQB); u16* WKB=(u16*)(ws+OFF_WKB);
  u16* WVB=(u16*)(ws+OFF_WVB); u16* WOB=(u16*)(ws+OFF_WOB); u16* W1T=(u16*)(ws+OFF_W1T);
  u16* W2T=(u16*)(ws+OFF_W2T); u16* A2T=(u16*)(ws+OFF_A2T); u16* V2T=(u16*)(ws+OFF_V2T);
  u16* G2T=(u16*)(ws+OFF_G2T);
  for (size_t idx=(size_t)blockIdx.x*256+threadIdx.x; idx<PREP_TOT; idx+=(size_t)gridDim.x*256){
    size_t r = idx;
    if (r < N_XB){ XB[r]=f2bf(x[r]); continue; } r-=N_XB;
    if (r < N_WQ){ WQB[r]=f2bf(Wq[r]); continue; } r-=N_WQ;
    if (r < N_WK){ WKB[r]=f2bf(Wk[r]); continue; } r-=N_WK;
    if (r < N_WV){ WVB[r]=f2bf(Wv[r]); continue; } r-=N_WV;
    if (r < N_WO){ WOB[r]=f2bf(Wo[r]); continue; } r-=N_WO;
    if (r < N_W1T){
      int n=(int)(r>>10), k=(int)(r&1023); float v=0.f;
      if (n<64) v=w1[(size_t)k*64+n];
      else if (n<128) v=a1[(size_t)k*64+(n-64)];
      else if (n<160) v=v1[(size_t)k*32+(n-128)];
      else if (n<320) v=g1[(size_t)k*160+(n-160)];
      W1T[r]=f2bf(v); continue; } r-=N_W1T;
    if (r < N_W2T){ int c=(int)(r>>6), d=(int)(r&63); W2T[r]=f2bf(w2[(size_t)d*1024+c]); continue; } r-=N_W2T;
    if (r < N_A2T){ int c=(int)(r>>6), d=(int)(r&63); A2T[r]=f2bf(a2[(size_t)d*1024+c]); continue; } r-=N_A2T;
    if (r < N_V2T){ int c=(int)(r>>5), d=(int)(r&31); V2T[r]=f2bf(v2[(size_t)d*1024+c]); continue; } r-=N_V2T;
    if (r < N_G2T){ int c=(int)(r/160), d=(int)(r%160); G2T[r]=f2bf(g2[(size_t)d*1024+c]); continue; } r-=N_G2T;
    dout[2228224 + r] = vfirst[r];   // v_first passthrough (offset 2097152+131072)
  }
}

// ---------------- activation for stage-1 ----------------
__global__ __launch_bounds__(256) void act_kernel(char* ws){
  const float* URAW=(const float*)(ws+OFF_URAW);
  u16* UB=(u16*)(ws+OFF_UB);
  size_t idx=(size_t)blockIdx.x*256+threadIdx.x;   // grid covers 2048*384 exactly
  int m=(int)(idx/384), n=(int)(idx%384);
  float v=0.f;
  if (n<64)       v = tanhf(URAW[(size_t)m*320+n]);
  else if (n<160) v = URAW[(size_t)m*320+n];
  else if (n<320) v = 1.0f/(1.0f+__expf(-URAW[(size_t)m*320+n]));
  UB[idx]=f2bf(v);
}

// ---------------- unified NT bf16 MFMA GEMM: C[m][n] = sum_k A[m][k]*B[n][k] ----------------
__global__ __launch_bounds__(256) void gemm_kernel(int phase, char* ws,
  const float* w0b, const float* a0b, const float* v0b, float* dout)
{
  const u16* A; const u16* Bw;
  float* outF=nullptr; const float* bias=nullptr;
  float* SEQf=(float*)(ws+OFF_SEQ);
  int lda=0, ldb=0, K=0, ldc=0, Nlim=1024, col0=0, outMode=0;
  int y = blockIdx.y;
  if (phase==0){
    A=(const u16*)(ws+OFF_XB); lda=1024; K=1024;
    if (y<8)      { Bw=(const u16*)(ws+OFF_WQB); ldb=1024; col0=y*128;       outMode=1; }
    else if (y<12){ Bw=(const u16*)(ws+OFF_WKB); ldb=1024; col0=(y-8)*128;   outF=(float*)(ws+OFF_KQF); ldc=512; Nlim=512; }
    else if (y<16){ Bw=(const u16*)(ws+OFF_WVB); ldb=1024; col0=(y-12)*128;  outF=(float*)(ws+OFF_VQF); ldc=512; Nlim=512; }
    else          { Bw=(const u16*)(ws+OFF_W1T); ldb=1024; col0=(y-16)*128;  outF=(float*)(ws+OFF_URAW); ldc=320; Nlim=320; }
  } else if (phase==1){
    int seg=y>>3; col0=(y&7)*128;
    const int Ks[4]={64,64,32,160};
    const int Ao[4]={0,64,128,160};
    K=Ks[seg]; lda=384; ldb=K;
    A=(const u16*)(ws+OFF_UB) + Ao[seg];
    if (seg==0)     { Bw=(const u16*)(ws+OFF_W2T); outMode=2; bias=w0b; }
    else if (seg==1){ Bw=(const u16*)(ws+OFF_A2T); outMode=3; bias=a0b; outF=(float*)(ws+OFF_S2A); ldc=1024; }
    else if (seg==2){ Bw=(const u16*)(ws+OFF_V2T); outMode=3; bias=v0b; outF=(float*)(ws+OFF_S2V); ldc=1024; }
    else            { Bw=(const u16*)(ws+OFF_G2T); outF=(float*)(ws+OFF_GBUF); ldc=1024; }
  } else {
    A=(const u16*)(ws+OFF_XGB); lda=1024; K=1024;
    Bw=(const u16*)(ws+OFF_WOB); ldb=1024; col0=y*128; outF=dout; ldc=1024;
  }
  int m0 = blockIdx.x*128;
  __shared__ __align__(16) u16 As[128][40];
  __shared__ __align__(16) u16 Bs[128][40];
  int tid=threadIdx.x, l=tid&63, wv=tid>>6, wm=wv>>1, wn=wv&1;
  f32x4 acc[4][4];
  #pragma unroll
  for (int i=0;i<4;i++)
    #pragma unroll
    for (int j=0;j<4;j++) acc[i][j]=(f32x4){0.f,0.f,0.f,0.f};

  for (int k0=0;k0<K;k0+=32){
    #pragma unroll
    for (int c=tid;c<512;c+=256){
      int row=c>>2, seg=c&3;
      *(i32x4*)(&As[row][seg*8]) = *(const i32x4*)(A  + (size_t)(m0+row)*lda  + k0 + seg*8);
      *(i32x4*)(&Bs[row][seg*8]) = *(const i32x4*)(Bw + (size_t)(col0+row)*ldb + k0 + seg*8);
    }
    __syncthreads();
    int kseg=(l>>4)*8, rrow=l&15;
    s16x8 af[4], bf[4];
    #pragma unroll
    for (int mt=0;mt<4;mt++) af[mt]=*(const s16x8*)(&As[wm*64+mt*16+rrow][kseg]);
    #pragma unroll
    for (int nt=0;nt<4;nt++) bf[nt]=*(const s16x8*)(&Bs[wn*64+nt*16+rrow][kseg]);
    #pragma unroll
    for (int mt=0;mt<4;mt++)
      #pragma unroll
      for (int nt=0;nt<4;nt++)
        acc[mt][nt]=__builtin_amdgcn_mfma_f32_16x16x32_bf16(af[mt],bf[nt],acc[mt][nt],0,0,0);
    __syncthreads();
  }
  // epilogue
  #pragma unroll
  for (int mt=0;mt<4;mt++){
    #pragma unroll
    for (int nt=0;nt<4;nt++){
      int nglob = col0 + wn*64 + nt*16 + (l&15);
      if (nglob >= Nlim) continue;
      #pragma unroll
      for (int rg=0;rg<4;rg++){
        int mrow = m0 + wm*64 + mt*16 + ((l>>4)<<2) + rg;
        float val = acc[mt][nt][rg];
        if (outMode==0){
          outF[(size_t)mrow*ldc + nglob] = val;
        } else if (outMode==1){          // r -> SEQ slot 0
          int b=mrow>>10, t=mrow&1023, h=nglob>>6, i=nglob&63;
          SEQf[(((size_t)(b*16+h)*1024+t)*384) + i] = val;
        } else if (outMode==2){          // decay -> SEQ slot 1
          float w = bias[nglob] + val;
          float d = expf(-expf(w));
          int b=mrow>>10, t=mrow&1023, h=nglob>>6, i=nglob&63;
          SEQf[(((size_t)(b*16+h)*1024+t)*384) + 64 + i] = d;
        } else {                          // sigmoid(bias+acc)
          float s = 1.0f/(1.0f+__expf(-(bias[nglob]+val)));
          outF[(size_t)mrow*ldc + nglob] = s;
        }
      }
    }
  }
}

// ---------------- prep2: build SEQ slots k,v,a,b ----------------
__global__ __launch_bounds__(256) void prep2_kernel(char* ws, const float* vfirst,
  const float* kk_s, const float* ka_s)
{
  const float* KQF=(const float*)(ws+OFF_KQF);
  const float* VQF=(const float*)(ws+OFF_VQF);
  const float* ICLR=(const float*)(ws+OFF_S2A);
  const float* VMIX=(const float*)(ws+OFF_S2V);
  float* SEQf=(float*)(ws+OFF_SEQ);
  int m=blockIdx.x, b=m>>10, t=m&1023;
  int tid=threadIdx.x, c0=tid*4, h=c0>>6, i0=c0&63, hk=h>>1;
  f32x4 kq=*(const f32x4*)(KQF+(size_t)m*512+hk*64+i0);
  f32x4 vq=*(const f32x4*)(VQF+(size_t)m*512+hk*64+i0);
  f32x4 ic=*(const f32x4*)(ICLR+(size_t)m*1024+c0);
  f32x4 vm=*(const f32x4*)(VMIX+(size_t)m*1024+c0);
  f32x4 vf=*(const f32x4*)(vfirst+(size_t)m*1024+c0);
  f32x4 kkc=*(const f32x4*)(kk_s+c0);
  f32x4 kac=*(const f32x4*)(ka_s+c0);
  f32x4 kk=kq*kkc;
  float ssq=kk[0]*kk[0]+kk[1]*kk[1]+kk[2]*kk[2]+kk[3]*kk[3];
  #pragma unroll
  for (int mk=1;mk<16;mk<<=1) ssq += __shfl_xor(ssq,mk);
  float scale = 1.0f / fmaxf(sqrtf(ssq), 1e-12f);
  f32x4 kf,vv,av,bv;
  #pragma unroll
  for (int j=0;j<4;j++){
    float icc = 1.0f + (ic[j]-1.0f)*kac[j];
    float kkn = kk[j]*scale;
    kf[j]=kq[j]*icc;
    vv[j]=vq[j] + (vf[j]-vq[j])*vm[j];
    av[j]=-kkn;
    bv[j]=kkn*icc;
  }
  size_t sb = (((size_t)(b*16+h)*1024)+t)*384 + i0;
  *(f32x4*)(SEQf+sb+128)=kf;
  *(f32x4*)(SEQf+sb+192)=vv;
  *(f32x4*)(SEQf+sb+256)=av;
  *(f32x4*)(SEQf+sb+320)=bv;
}

#define MFMA32(a,b,c) __builtin_amdgcn_mfma_f32_16x16x32_bf16(a,b,c,0,0,0)

// ---------------- precompute: per-chunk S-independent quantities (2048-way parallel) ------
// Record (14336B): P_f[kk][l]x16B, G_f +2048, zloc_f[it][l]x8B +4096, Yloc_f +6144,
//                  bar_f[jt][g2][c]x16B +8192, kar_f +10240, V_f[it][g2][c]x16B +12288.
__global__ __launch_bounds__(64) void pre_kernel(char* ws){
  const float* SEQ=(const float*)(ws+OFF_SEQ);
  int bid=blockIdx.x, bh=bid>>6, ch=bid&63;
  int l=threadIdx.x, c16=l&15, g=l>>4;
  const float* seqb = SEQ + (size_t)bh*(1024*384) + (size_t)ch*6144;
  char* rec = ws + OFF_REC + (size_t)bid*14336;
  float* PLp = (float*)(ws + OFF_PL) + (size_t)bid*64;

  __shared__ __align__(16) float raw[16*396];
  __shared__ __align__(16) float pbuf[16*68];
  __shared__ __align__(16) u16 AT[16*72];
  __shared__ __align__(16) u16 RT[16*72];
  __shared__ __align__(16) u16 BT[16*72];
  __shared__ __align__(16) u16 KT[16*72];
  __shared__ __align__(16) u16 vbb[64*24+16];
  __shared__ __align__(16) u16 zbb[64*24+16];
  __shared__ __align__(16) u16 pbb[64*24+16];
  __shared__ __align__(16) float WN[16*17];
  __shared__ __align__(16) u16 WY[16*24+16];
  __shared__ __align__(16) u16 WB[16*24+16];
  __shared__ __align__(16) u16 WK[16*24+16];
  __shared__ __align__(16) float rhsb[16*68];
  __shared__ __align__(16) float ptmp[16*68];
  __shared__ __align__(16) float gtmp[16*68];
  const s16x8 zero8 = {0,0,0,0,0,0,0,0};

  #pragma unroll
  for (int t=0;t<16;t++){
    const float* src = seqb + (size_t)t*384;
    float* dst = &raw[t*396];
    gload_lds16(src + l*4, dst);
    gload_lds4 (src + 256 + l, dst + 256);
    gload_lds4 (src + 320 + l, dst + 320);
  }
  asm volatile("s_waitcnt vmcnt(0)" ::: "memory");
  __builtin_amdgcn_sched_barrier(0);

  // ---- P1a: lane = channel l. cumprod decay; vbb LDS; bar_f/kar_f/V_f/pL global ----
  {
    float ptv[16]; float pp=1.f;
    #pragma unroll
    for (int t=0;t<16;t++){ pp *= raw[t*396+64+l]; ptv[t]=pp; pbuf[t*68+l]=pp; }
    float pL = ptv[15];
    PLp[l] = pL;
    float bs[16], ks[16], vs[16];
    #pragma unroll
    for (int t=0;t<16;t++){
      float sc = pL * __builtin_amdgcn_rcpf(ptv[t]);
      bs[t]=raw[t*396+320+l]*sc;
      ks[t]=raw[t*396+128+l]*sc;
      vs[t]=raw[t*396+192+l];
    }
    int rlo=(l>>4)*2, rc=l&15;
    i32x4 o;
    o[0]=pk2(vs[0],vs[1]); o[1]=pk2(vs[2],vs[3]); o[2]=pk2(vs[4],vs[5]); o[3]=pk2(vs[6],vs[7]);
    *(i32x4*)(&vbb[l*24]) = o;
    *(i32x4*)(rec + 12288 + (size_t)((rlo+0)*16+rc)*16) = o;
    o[0]=pk2(vs[8],vs[9]); o[1]=pk2(vs[10],vs[11]); o[2]=pk2(vs[12],vs[13]); o[3]=pk2(vs[14],vs[15]);
    *(i32x4*)(&vbb[l*24+8]) = o;
    *(i32x4*)(rec + 12288 + (size_t)((rlo+1)*16+rc)*16) = o;
    o[0]=pk2(bs[0],bs[1]); o[1]=pk2(bs[2],bs[3]); o[2]=pk2(bs[4],bs[5]); o[3]=pk2(bs[6],bs[7]);
    *(i32x4*)(rec + 8192 + (size_t)((rlo+0)*16+rc)*16) = o;
    o[0]=pk2(bs[8],bs[9]); o[1]=pk2(bs[10],bs[11]); o[2]=pk2(bs[12],bs[13]); o[3]=pk2(bs[14],bs[15]);
    *(i32x4*)(rec + 8192 + (size_t)((rlo+1)*16+rc)*16) = o;
    o[0]=pk2(ks[0],ks[1]); o[1]=pk2(ks[2],ks[3]); o[2]=pk2(ks[4],ks[5]); o[3]=pk2(ks[6],ks[7]);
    *(i32x4*)(rec + 10240 + (size_t)((rlo+0)*16+rc)*16) = o;
    o[0]=pk2(ks[8],ks[9]); o[1]=pk2(ks[10],ks[11]); o[2]=pk2(ks[12],ks[13]); o[3]=pk2(ks[14],ks[15]);
    *(i32x4*)(rec + 10240 + (size_t)((rlo+1)*16+rc)*16) = o;
  }

  // ---- P1b: lane (t=c16, group g): write AT,RT,BT,KT ----
  {
    int tt=c16, gg=g;
    f32x4 pa[4], pp[4];
    int tp = (tt==0)?0:(tt-1);
    #pragma unroll
    for (int q=0;q<4;q++){
      pa[q] = *(const f32x4*)(&pbuf[tt*68 + 16*gg + 4*q]);
      pp[q] = *(const f32x4*)(&pbuf[tp*68 + 16*gg + 4*q]);
    }
    if (tt==0){
      #pragma unroll
      for (int q=0;q<4;q++) pp[q] = (f32x4){1.f,1.f,1.f,1.f};
    }
    f32x4 ra[4], rr[4], rb[4], rk[4];
    #pragma unroll
    for (int q=0;q<4;q++){
      ra[q]=*(const f32x4*)(&raw[tt*396+256+16*gg+4*q]);
      rr[q]=*(const f32x4*)(&raw[tt*396+    16*gg+4*q]);
      rb[q]=*(const f32x4*)(&raw[tt*396+320+16*gg+4*q]);
      rk[q]=*(const f32x4*)(&raw[tt*396+128+16*gg+4*q]);
    }
    float va[16], vr[16], vb2[16], vk2[16];
    #pragma unroll
    for (int q=0;q<4;q++)
      #pragma unroll
      for (int e=0;e<4;e++){
        float rp = __builtin_amdgcn_rcpf(pa[q][e]);
        va[q*4+e] = pp[q][e]*ra[q][e];
        vr[q*4+e] = pa[q][e]*rr[q][e];
        vb2[q*4+e] = rb[q][e]*rp;
        vk2[q*4+e] = rk[q][e]*rp;
      }
    i32x4 o;
    o[0]=pk2(va[0],va[1]); o[1]=pk2(va[2],va[3]); o[2]=pk2(va[4],va[5]); o[3]=pk2(va[6],va[7]);
    *(i32x4*)(&AT[tt*72+16*gg]) = o;
    o[0]=pk2(va[8],va[9]); o[1]=pk2(va[10],va[11]); o[2]=pk2(va[12],va[13]); o[3]=pk2(va[14],va[15]);
    *(i32x4*)(&AT[tt*72+16*gg+8]) = o;
    o[0]=pk2(vr[0],vr[1]); o[1]=pk2(vr[2],vr[3]); o[2]=pk2(vr[4],vr[5]); o[3]=pk2(vr[6],vr[7]);
    *(i32x4*)(&RT[tt*72+16*gg]) = o;
    o[0]=pk2(vr[8],vr[9]); o[1]=pk2(vr[10],vr[11]); o[2]=pk2(vr[12],vr[13]); o[3]=pk2(vr[14],vr[15]);
    *(i32x4*)(&RT[tt*72+16*gg+8]) = o;
    o[0]=pk2(vb2[0],vb2[1]); o[1]=pk2(vb2[2],vb2[3]); o[2]=pk2(vb2[4],vb2[5]); o[3]=pk2(vb2[6],vb2[7]);
    *(i32x4*)(&BT[tt*72+16*gg]) = o;
    o[0]=pk2(vb2[8],vb2[9]); o[1]=pk2(vb2[10],vb2[11]); o[2]=pk2(vb2[12],vb2[13]); o[3]=pk2(vb2[14],vb2[15]);
    *(i32x4*)(&BT[tt*72+16*gg+8]) = o;
    o[0]=pk2(vk2[0],vk2[1]); o[1]=pk2(vk2[2],vk2[3]); o[2]=pk2(vk2[4],vk2[5]); o[3]=pk2(vk2[6],vk2[7]);
    *(i32x4*)(&KT[tt*72+16*gg]) = o;
    o[0]=pk2(vk2[8],vk2[9]); o[1]=pk2(vk2[10],vk2[11]); o[2]=pk2(vk2[12],vk2[13]); o[3]=pk2(vk2[14],vk2[15]);
    *(i32x4*)(&KT[tt*72+16*gg+8]) = o;
  }

  // ---- W-block: N, Yhat, Tb, Tk ----
  {
    s16x8 afA[2], afR[2], bfB[2], bfK[2];
    #pragma unroll
    for (int Kt=0;Kt<2;Kt++){
      afA[Kt]=*(const s16x8*)(&AT[c16*72 + 32*Kt + 8*g]);
      afR[Kt]=*(const s16x8*)(&RT[c16*72 + 32*Kt + 8*g]);
      bfB[Kt]=*(const s16x8*)(&BT[c16*72 + 32*Kt + 8*g]);
      bfK[Kt]=*(const s16x8*)(&KT[c16*72 + 32*Kt + 8*g]);
    }
    f32x4 dNN={0.f,0.f,0.f,0.f}, dNY=dNN, dBB=dNN, dBK=dNN;
    #pragma unroll
    for (int Kt=0;Kt<2;Kt++){
      dNN=MFMA32(afA[Kt],bfB[Kt],dNN);
      dNY=MFMA32(afA[Kt],bfK[Kt],dNY);
      dBB=MFMA32(afR[Kt],bfB[Kt],dBB);
      dBK=MFMA32(afR[Kt],bfK[Kt],dBK);
    }
    #pragma unroll
    for (int e=0;e<4;e++){
      int tR=4*g+e, sC=c16;
      WN[tR*17+sC] = dNN[e];
      WY[tR*24+sC] = (sC<tR)? f2bf(dNY[e]) : (u16)0;
      WB[tR*24+sC] = (sC<=tR)? f2bf(dBB[e]) : (u16)0;
      WK[tR*24+sC] = (sC<=tR)? f2bf(dBK[e]) : (u16)0;
    }
  }

  // ---- YhatV -> rhsb ----
  s16x8 vf[4];
  #pragma unroll
  for (int J=0;J<4;J++){
    vf[J]=zero8;
    if (g<2) vf[J]=*(const s16x8*)(&vbb[(16*J+c16)*24 + 8*g]);
  }
  {
    s16x8 wyf=zero8;
    if (g<2) wyf=*(const s16x8*)(&WY[c16*24 + 8*g]);
    f32x4 dR[4];
    #pragma unroll
    for (int J=0;J<4;J++){
      dR[J]=(f32x4){0.f,0.f,0.f,0.f};
      dR[J]=MFMA32(wyf,vf[J],dR[J]);
      #pragma unroll
      for (int e=0;e<4;e++)
        rhsb[(4*g+e)*68 + 16*J + c16] = dR[J][e];
    }
  }

  // ---- P-solve: (I-N)P = Atil, lane = column j=l ----
  {
    float pv[16];
    #pragma unroll
    for (int t=0;t<16;t++) pv[t]=bf2f(AT[t*72+l]);
    #pragma unroll
    for (int t=1;t<16;t++)
      #pragma unroll
      for (int s=0;s<16;s++){
        if (s<t) pv[t] += WN[t*17+s]*pv[s];
      }
    i32x4 o;
    o[0]=pk2(pv[0],pv[1]); o[1]=pk2(pv[2],pv[3]); o[2]=pk2(pv[4],pv[5]); o[3]=pk2(pv[6],pv[7]);
    *(i32x4*)(&pbb[l*24]) = o;
    o[0]=pk2(pv[8],pv[9]); o[1]=pk2(pv[10],pv[11]); o[2]=pk2(pv[12],pv[13]); o[3]=pk2(pv[14],pv[15]);
    *(i32x4*)(&pbb[l*24+8]) = o;
    #pragma unroll
    for (int t=0;t<16;t++) ptmp[t*68+l]=pv[t];
  }

  // ---- z-solve: (I-N)zloc = YhatV, lane = column i=l ----
  {
    float zz[16];
    #pragma unroll
    for (int t=0;t<16;t++) zz[t]=rhsb[t*68+l];
    #pragma unroll
    for (int t=1;t<16;t++)
      #pragma unroll
      for (int s=0;s<16;s++){
        if (s<t) zz[t] += WN[t*17+s]*zz[s];
      }
    i32x4 o;
    o[0]=pk2(zz[0],zz[1]); o[1]=pk2(zz[2],zz[3]); o[2]=pk2(zz[4],zz[5]); o[3]=pk2(zz[6],zz[7]);
    *(i32x4*)(&zbb[l*24]) = o;
    o[0]=pk2(zz[8],zz[9]); o[1]=pk2(zz[10],zz[11]); o[2]=pk2(zz[12],zz[13]); o[3]=pk2(zz[14],zz[15]);
    *(i32x4*)(&zbb[l*24+8]) = o;
  }

  // ---- G = Rtil + Tb*P  -> gtmp ; Yloc = Tb*zloc + Tk*V -> record ----
  {
    s16x8 wbf=zero8, wkf=zero8;
    if (g<2){
      wbf=*(const s16x8*)(&WB[c16*24 + 8*g]);
      wkf=*(const s16x8*)(&WK[c16*24 + 8*g]);
    }
    #pragma unroll
    for (int J=0;J<4;J++){
      s16x8 pfB=zero8, zfB=zero8;
      if (g<2){
        pfB=*(const s16x8*)(&pbb[(16*J+c16)*24 + 8*g]);
        zfB=*(const s16x8*)(&zbb[(16*J+c16)*24 + 8*g]);
      }
      f32x4 dG, dYl=(f32x4){0.f,0.f,0.f,0.f};
      #pragma unroll
      for (int e=0;e<4;e++) dG[e]=bf2f(RT[(4*g+e)*72 + 16*J + c16]);
      dG=MFMA32(wbf,pfB,dG);
      dYl=MFMA32(wbf,zfB,dYl);
      dYl=MFMA32(wkf,vf[J],dYl);
      #pragma unroll
      for (int e=0;e<4;e++) gtmp[(4*g+e)*68 + 16*J + c16]=dG[e];
      i32x2 o2; o2[0]=pk2(dYl[0],dYl[1]); o2[1]=pk2(dYl[2],dYl[3]);
      *(i32x2*)(rec + 6144 + (size_t)(J*64+l)*8) = o2;
    }
  }

  // ---- zloc_f from zbb ----
  #pragma unroll
  for (int it=0;it<4;it++)
    *(i32x2*)(rec + 4096 + (size_t)(it*64+l)*8) =
      *(const i32x2*)(&zbb[(16*it+c16)*24 + 4*g]);

  // ---- P_f / G_f rows from ptmp/gtmp ----
  #pragma unroll
  for (int kk=0;kk<2;kk++){
    f32x4 a0 = *(const f32x4*)(&ptmp[c16*68 + 32*kk + 8*g]);
    f32x4 a1 = *(const f32x4*)(&ptmp[c16*68 + 32*kk + 8*g + 4]);
    i32x4 o;
    o[0]=pk2(a0[0],a0[1]); o[1]=pk2(a0[2],a0[3]); o[2]=pk2(a1[0],a1[1]); o[3]=pk2(a1[2],a1[3]);
    *(i32x4*)(rec + (size_t)(kk*64+l)*16) = o;
    f32x4 b0 = *(const f32x4*)(&gtmp[c16*68 + 32*kk + 8*g]);
    f32x4 b1 = *(const f32x4*)(&gtmp[c16*68 + 32*kk + 8*g + 4]);
    o[0]=pk2(b0[0],b0[1]); o[1]=pk2(b0[2],b0[3]); o[2]=pk2(b1[0],b1[1]); o[3]=pk2(b1[2],b1[3]);
    *(i32x4*)(rec + 2048 + (size_t)(kk*64+l)*16) = o;
  }
}

// ---------------- serial scan: S' = pL.S + Bbar'z + Kbar'V, z = P.S' + zloc, Y = G.S' + Yloc
__global__ __launch_bounds__(64) void scan2_kernel(char* ws, const float* S0, float* dout){
  float* YB=(float*)(ws+OFF_YBUF);
  const char* recb = ws + OFF_REC;
  const float* PLg = (const float*)(ws+OFF_PL);
  int bh=blockIdx.x;
  int l=threadIdx.x, c16=l&15, g=l>>4;

  __shared__ __align__(16) char buf[2][14336];
  __shared__ __align__(16) u16 Sbf[64*72];
  __shared__ __align__(16) u16 zbb[64*24+16];
  __shared__ __align__(16) float PLs[64*64];
  const s16x8 zero8 = {0,0,0,0,0,0,0,0};

  // S0 -> Sreg (Sreg[jt][it][e] = S^T[16jt+4g+e][16it+c16]) + bf16 copy to Sbf
  f32x4 Sreg[4][4];
  #pragma unroll
  for (int jt=0;jt<4;jt++)
    #pragma unroll
    for (int it=0;it<4;it++)
      Sreg[jt][it] = *(const f32x4*)(S0 + (size_t)bh*4096 + (size_t)(16*it+c16)*64 + 16*jt + 4*g);
  #pragma unroll
  for (int jt=0;jt<4;jt++)
    #pragma unroll
    for (int it=0;it<4;it++){
      i32x2 w2v; w2v[0]=pk2(Sreg[jt][it][0],Sreg[jt][it][1]); w2v[1]=pk2(Sreg[jt][it][2],Sreg[jt][it][3]);
      *(i32x2*)(&Sbf[(16*it+c16)*72 + 16*jt + 4*g]) = w2v;
    }

  // stage pL table (64 chunks x 64 f32 = 16KB) and record 0
  {
    const float* plsrc = PLg + (size_t)bh*4096;
    #pragma unroll
    for (int q=0;q<16;q++)
      gload_lds16(plsrc + q*256 + l*4, &PLs[q*256]);
    const float* r0 = (const float*)(recb + (size_t)(bh*64)*14336);
    #pragma unroll
    for (int q=0;q<14;q++)
      gload_lds16(r0 + q*256 + l*4, (float*)(&buf[0][0]) + q*256);
  }
  asm volatile("s_waitcnt vmcnt(0) lgkmcnt(0)" ::: "memory");
  __builtin_amdgcn_sched_barrier(0);

  const char* rb = recb + (size_t)(bh*64)*14336;
  float* yb0 = YB + (size_t)bh*65536;

  #pragma unroll 1
  for (int ch=0; ch<64; ++ch){
    asm volatile("s_waitcnt vmcnt(16)" ::: "memory");
    __builtin_amdgcn_sched_barrier(0);
    const char* bp = buf[ch&1];

    s16x8 pf[2], gf[2];
    #pragma unroll
    for (int kk=0;kk<2;kk++){
      pf[kk]=*(const s16x8*)(bp + (size_t)(kk*64+l)*16);
      gf[kk]=*(const s16x8*)(bp + 2048 + (size_t)(kk*64+l)*16);
    }
    i32x2 zlv[4], ylv[4];
    #pragma unroll
    for (int it=0;it<4;it++){
      zlv[it]=*(const i32x2*)(bp + 4096 + (size_t)(it*64+l)*8);
      ylv[it]=*(const i32x2*)(bp + 6144 + (size_t)(it*64+l)*8);
    }
    s16x8 barf[4], karf[4], vfr[4];
    #pragma unroll
    for (int jt=0;jt<4;jt++){
      barf[jt]=zero8; karf[jt]=zero8;
      if (g<2){
        barf[jt]=*(const s16x8*)(bp + 8192  + (size_t)((jt*2+g)*16+c16)*16);
        karf[jt]=*(const s16x8*)(bp + 10240 + (size_t)((jt*2+g)*16+c16)*16);
      }
    }
    #pragma unroll
    for (int it=0;it<4;it++){
      vfr[it]=zero8;
      if (g<2) vfr[it]=*(const s16x8*)(bp + 12288 + (size_t)((it*2+g)*16+c16)*16);
    }
    s16x8 sB[4][2];
    #pragma unroll
    for (int it=0;it<4;it++)
      #pragma unroll
      for (int kk=0;kk<2;kk++)
        sB[it][kk]=*(const s16x8*)(&Sbf[(16*it+c16)*72 + 32*kk + 8*g]);

    // prefetch next record
    {
      int nc = (ch<63)?(ch+1):63;
      const float* nrb = (const float*)(rb + (size_t)nc*14336);
      float* db = (float*)(&buf[(ch+1)&1][0]);
      #pragma unroll
      for (int q=0;q<14;q++)
        gload_lds16(nrb + q*256 + l*4, db + q*256);
    }
    __builtin_amdgcn_sched_barrier(0);

    // z = P.S^T + zloc ; Y = G.S^T + Yloc
    f32x4 dz[4], dy[4];
    #pragma unroll
    for (int it=0;it<4;it++){
      dz[it]=cvt4(zlv[it]);
      dz[it]=MFMA32(pf[0],sB[it][0],dz[it]);
      dz[it]=MFMA32(pf[1],sB[it][1],dz[it]);
      dy[it]=cvt4(ylv[it]);
      dy[it]=MFMA32(gf[0],sB[it][0],dy[it]);
      dy[it]=MFMA32(gf[1],sB[it][1],dy[it]);
    }
    // z -> zbb (bf16 [i][s])
    #pragma unroll
    for (int it=0;it<4;it++){
      i32x2 o2; o2[0]=pk2(dz[it][0],dz[it][1]); o2[1]=pk2(dz[it][2],dz[it][3]);
      *(i32x2*)(&zbb[(16*it+c16)*24 + 4*g]) = o2;
    }
    asm volatile("s_waitcnt lgkmcnt(0)" ::: "memory");
    __builtin_amdgcn_sched_barrier(0);
    s16x8 zf[4];
    #pragma unroll
    for (int it=0;it<4;it++){
      zf[it]=zero8;
      if (g<2) zf[it]=*(const s16x8*)(&zbb[(16*it+c16)*24 + 8*g]);
    }
    // S' = diag(pL) S + Bbar^T z + Kbar^T V
    #pragma unroll
    for (int jt=0;jt<4;jt++){
      f32x4 pl4 = *(const f32x4*)(&PLs[ch*64 + 16*jt + 4*g]);
      #pragma unroll
      for (int it=0;it<4;it++){
        f32x4 acc = Sreg[jt][it]*pl4;
        acc=MFMA32(barf[jt],zf[it],acc);
        acc=MFMA32(karf[jt],vfr[it],acc);
        Sreg[jt][it]=acc;
      }
    }
    // Sbf update for next chunk
    #pragma unroll
    for (int jt=0;jt<4;jt++)
      #pragma unroll
      for (int it=0;it<4;it++){
        i32x2 w2v; w2v[0]=pk2(Sreg[jt][it][0],Sreg[jt][it][1]); w2v[1]=pk2(Sreg[jt][it][2],Sreg[jt][it][3]);
        *(i32x2*)(&Sbf[(16*it+c16)*72 + 16*jt + 4*g]) = w2v;
      }
    // Y stores (issued after prefetch loads: vmcnt accounting = 14 loads + 16 stores)
    {
      float* yb = yb0 + (size_t)ch*1024;
      #pragma unroll
      for (int it=0;it<4;it++)
        #pragma unroll
        for (int e=0;e<4;e++)
          yb[(size_t)(4*g+e)*64 + 16*it + c16] = dy[it][e];
    }
    asm volatile("s_waitcnt lgkmcnt(0)" ::: "memory");
    __builtin_amdgcn_sched_barrier(0);
  }

  // final state
  #pragma unroll
  for (int jt=0;jt<4;jt++)
    #pragma unroll
    for (int it=0;it<4;it++)
      *(f32x4*)(dout + 2097152 + (size_t)bh*4096 + (size_t)(16*it+c16)*64 + 16*jt + 4*g) = Sreg[jt][it];
}

// ---------------- epilogue: groupnorm + bonus + gate -> bf16 ----------------
__global__ __launch_bounds__(256) void epi_kernel(char* ws, const float* rk,
  const float* lnw, const float* lnb)
{
  const float* YB=(const float*)(ws+OFF_YBUF);
  const float* SEQf=(const float*)(ws+OFF_SEQ);
  const float* GB=(const float*)(ws+OFF_GBUF);
  u16* XGB=(u16*)(ws+OFF_XGB);
  int m=blockIdx.x, b=m>>10, t=m&1023;
  int tid=threadIdx.x, c0=tid*4, h=c0>>6, i0=c0&63;
  f32x4 y=*(const f32x4*)(YB + ((size_t)(b*16+h)*1024+t)*64 + i0);
  float s = y[0]+y[1]+y[2]+y[3];
  float ss= y[0]*y[0]+y[1]*y[1]+y[2]*y[2]+y[3]*y[3];
  #pragma unroll
  for (int mk=1;mk<16;mk<<=1){ s+=__shfl_xor(s,mk); ss+=__shfl_xor(ss,mk); }
  float mu=s*(1.0f/64.0f), var=ss*(1.0f/64.0f)-mu*mu;
  float inv=rsqrtf(var + 6.4e-4f);
  size_t sb=((size_t)(b*16+h)*1024+t)*384;
  f32x4 r=*(const f32x4*)(SEQf+sb+i0);
  f32x4 k=*(const f32x4*)(SEQf+sb+128+i0);
  f32x4 v=*(const f32x4*)(SEQf+sb+192+i0);
  f32x4 q=*(const f32x4*)(rk + h*64 + i0);
  float dp = r[0]*k[0]*q[0]+r[1]*k[1]*q[1]+r[2]*k[2]*q[2]+r[3]*k[3]*q[3];
  #pragma unroll
  for (int mk=1;mk<16;mk<<=1) dp+=__shfl_xor(dp,mk);
  f32x4 gg=*(const f32x4*)(GB+(size_t)m*1024+c0);
  u16x4 outv;
  #pragma unroll
  for (int j=0;j<4;j++){
    float xn = (y[j]-mu)*inv*lnw[c0+j] + lnb[c0+j] + dp*v[j];
    outv[j]=f2bf(xn*gg[j]);
  }
  *(u16x4*)(XGB+(size_t)m*1024+c0)=outv;
}

extern "C" void kernel_launch(void* const* d_in, const int* in_sizes, int n_in,
                              void* d_out, int out_size, void* d_ws, size_t ws_size,
                              hipStream_t stream) {
  const float* x      =(const float*)d_in[0];
  const float* S0     =(const float*)d_in[1];
  const float* vfirst =(const float*)d_in[2];
  const float* w0     =(const float*)d_in[3];
  const float* w1     =(const float*)d_in[4];
  const float* w2     =(const float*)d_in[5];
  const float* a0     =(const float*)d_in[6];
  const float* a1     =(const float*)d_in[7];
  const float* a2     =(const float*)d_in[8];
  const float* v0     =(const float*)d_in[9];
  const float* v1     =(const float*)d_in[10];
  const float* v2     =(const float*)d_in[11];
  const float* g1     =(const float*)d_in[12];
  const float* g2     =(const float*)d_in[13];
  const float* k_k    =(const float*)d_in[14];
  const float* k_a    =(const float*)d_in[15];
  const float* r_k    =(const float*)d_in[16];
  const float* Wq     =(const float*)d_in[17];
  const float* Wk     =(const float*)d_in[18];
  const float* Wv     =(const float*)d_in[19];
  const float* Wo     =(const float*)d_in[20];
  const float* ln_w   =(const float*)d_in[21];
  const float* ln_b   =(const float*)d_in[22];
  char* ws=(char*)d_ws;
  float* dout=(float*)d_out;

  prep_kernel<<<2048,256,0,stream>>>(ws,x,vfirst,w1,w2,a1,a2,v1,v2,g1,g2,Wq,Wk,Wv,Wo,dout);
  gemm_kernel<<<dim3(16,19),256,0,stream>>>(0,ws,w0,a0,v0,dout);
  act_kernel<<<3072,256,0,stream>>>(ws);
  gemm_kernel<<<dim3(16,32),256,0,stream>>>(1,ws,w0,a0,v0,dout);
  prep2_kernel<<<2048,256,0,stream>>>(ws,vfirst,k_k,k_a);
  pre_kernel<<<2048,64,0,stream>>>(ws);
  scan2_kernel<<<32,64,0,stream>>>(ws,S0,dout);
  epi_kernel<<<2048,256,0,stream>>>(ws,r_k,ln_w,ln_b);
  gemm_kernel<<<dim3(16,8),256,0,stream>>>(2,ws,w0,a0,v0,dout);
}

// Round 6
// 252.957 us; speedup vs baseline: 4.9888x; 1.1471x over previous
//
#include <hip/hip_runtime.h>

typedef unsigned short u16;
typedef __attribute__((ext_vector_type(8))) short s16x8;
typedef __attribute__((ext_vector_type(4))) float f32x4;
typedef __attribute__((ext_vector_type(4))) int   i32x4;
typedef __attribute__((ext_vector_type(2))) int   i32x2;
typedef __attribute__((ext_vector_type(4))) unsigned short u16x4;

// ---------------- workspace layout (bytes) ----------------
constexpr size_t OFF_XB   = 0;                     // bf16 x          [2048][1024]
constexpr size_t OFF_WQB  = OFF_XB   + 4194304;    // bf16 Wq         [1024][1024]
constexpr size_t OFF_WKB  = OFF_WQB  + 2097152;    // bf16 Wk         [512][1024]
constexpr size_t OFF_WVB  = OFF_WKB  + 1048576;    // bf16 Wv         [512][1024]
constexpr size_t OFF_WOB  = OFF_WVB  + 1048576;    // bf16 Wo         [1024][1024]
constexpr size_t OFF_W1T  = OFF_WOB  + 2097152;    // bf16 W1T [384][1024]; reused later as PL array
constexpr size_t OFF_W2T  = OFF_W1T  + 786432;     // bf16 w2T        [1024][64]
constexpr size_t OFF_A2T  = OFF_W2T  + 131072;     // bf16 a2T        [1024][64]
constexpr size_t OFF_V2T  = OFF_A2T  + 131072;     // bf16 v2T        [1024][32]
constexpr size_t OFF_G2T  = OFF_V2T  + 65536;      // bf16 g2T        [1024][160]
constexpr size_t OFF_KQF  = OFF_G2T  + 327680;     // f32 k-proj [2048][512]; reused as chunk records
constexpr size_t OFF_VQF  = OFF_KQF  + 4194304;    // f32 v-proj      [2048][512]
constexpr size_t OFF_URAW = OFF_VQF  + 4194304;    // (dead; kept for layout)
constexpr size_t OFF_UB   = OFF_URAW + 2621440;    // bf16 stage1 act [2048][384]
constexpr size_t OFF_S2A  = OFF_UB   + 1572864;    // f32 iclr        [2048][1024]
constexpr size_t OFF_S2V  = OFF_S2A  + 8388608;    // f32 vmix        [2048][1024]
constexpr size_t OFF_GBUF = OFF_S2V  + 8388608;    // f32 gate        [2048][1024]
constexpr size_t OFF_SEQ  = OFF_GBUF + 8388608;    // f32 SEQ [2][16][1024][6][64] (r,decay,k,v,a,b)
constexpr size_t OFF_YBUF = OFF_SEQ  + 50331648;   // f32 y   [2][16][1024][64]
constexpr size_t OFF_XGB  = OFF_YBUF + 8388608;    // bf16 xn*g       [2048][1024]

// chunk record overlay (dead KQF..S2V window, 2048 records x 14336B = exact fit)
constexpr size_t OFF_REC  = OFF_KQF;   // per record: P_f 0, G_f 2048, zloc_f 4096, Yloc_f 6144,
                                       //             bar_f 8192, kar_f 10240, V_f 12288
constexpr size_t OFF_PL   = OFF_W1T;   // f32 pL [2048][64]

__device__ __forceinline__ u16 f2bf(float f){
  unsigned int u = __builtin_bit_cast(unsigned int, f);
  u = u + 0x7fffu + ((u >> 16) & 1u);
  return (u16)(u >> 16);
}
__device__ __forceinline__ int pk2(float a, float b){
  return (int)((unsigned)f2bf(a) | ((unsigned)f2bf(b) << 16));
}
__device__ __forceinline__ float bf2f(u16 h){
  return __builtin_bit_cast(float, ((unsigned)h) << 16);
}
__device__ __forceinline__ f32x4 cvt4(i32x2 v){
  unsigned a=(unsigned)v[0], b=(unsigned)v[1];
  f32x4 r;
  r[0]=__builtin_bit_cast(float, a<<16);
  r[1]=__builtin_bit_cast(float, a&0xffff0000u);
  r[2]=__builtin_bit_cast(float, b<<16);
  r[3]=__builtin_bit_cast(float, b&0xffff0000u);
  return r;
}

__device__ __forceinline__ void gload_lds16(const float* g, float* l){
  __builtin_amdgcn_global_load_lds((const __attribute__((address_space(1))) void*)g,
                                   (__attribute__((address_space(3))) void*)l, 16, 0, 0);
}
__device__ __forceinline__ void gload_lds4(const float* g, float* l){
  __builtin_amdgcn_global_load_lds((const __attribute__((address_space(1))) void*)g,
                                   (__attribute__((address_space(3))) void*)l, 4, 0, 0);
}

// ---------------- prep: convert/transpose + v_first passthrough ----------------
constexpr size_t N_XB=2097152, N_WQ=1048576, N_WK=524288, N_WV=524288, N_WO=1048576,
  N_W1T=393216, N_W2T=65536, N_A2T=65536, N_V2T=32768, N_G2T=163840, N_VF=2097152;
constexpr size_t PREP_TOT = N_XB+N_WQ+N_WK+N_WV+N_WO+N_W1T+N_W2T+N_A2T+N_V2T+N_G2T+N_VF;

__global__ __launch_bounds__(256) void prep_kernel(char* ws, const float* x, const float* vfirst,
  const float* w1, const float* w2, const float* a1, const float* a2,
  const float* v1, const float* v2, const float* g1, const float* g2,
  const float* Wq, const float* Wk, const float* Wv, const float* Wo, float* dout)
{
  u16* XB=(u16*)(ws+OFF_XB); u16* WQB=(u16*)(ws+OFF_WQB); u16* WKB=(u16*)(ws+OFF_WKB);
  u16* WVB=(u16*)(ws+OFF_WVB); u16* WOB=(u16*)(ws+OFF_WOB); u16* W1T=(u16*)(ws+OFF_W1T);
  u16* W2T=(u16*)(ws+OFF_W2T); u16* A2T=(u16*)(ws+OFF_A2T); u16* V2T=(u16*)(ws+OFF_V2T);
  u16* G2T=(u16*)(ws+OFF_G2T);
  for (size_t idx=(size_t)blockIdx.x*256+threadIdx.x; idx<PREP_TOT; idx+=(size_t)gridDim.x*256){
    size_t r = idx;
    if (r < N_XB){ XB[r]=f2bf(x[r]); continue; } r-=N_XB;
    if (r < N_WQ){ WQB[r]=f2bf(Wq[r]); continue; } r-=N_WQ;
    if (r < N_WK){ WKB[r]=f2bf(Wk[r]); continue; } r-=N_WK;
    if (r < N_WV){ WVB[r]=f2bf(Wv[r]); continue; } r-=N_WV;
    if (r < N_WO){ WOB[r]=f2bf(Wo[r]); continue; } r-=N_WO;
    if (r < N_W1T){
      int n=(int)(r>>10), k=(int)(r&1023); float v=0.f;
      if (n<64) v=w1[(size_t)k*64+n];
      else if (n<128) v=a1[(size_t)k*64+(n-64)];
      else if (n<160) v=v1[(size_t)k*32+(n-128)];
      else if (n<320) v=g1[(size_t)k*160+(n-160)];
      W1T[r]=f2bf(v); continue; } r-=N_W1T;
    if (r < N_W2T){ int c=(int)(r>>6), d=(int)(r&63); W2T[r]=f2bf(w2[(size_t)d*1024+c]); continue; } r-=N_W2T;
    if (r < N_A2T){ int c=(int)(r>>6), d=(int)(r&63); A2T[r]=f2bf(a2[(size_t)d*1024+c]); continue; } r-=N_A2T;
    if (r < N_V2T){ int c=(int)(r>>5), d=(int)(r&31); V2T[r]=f2bf(v2[(size_t)d*1024+c]); continue; } r-=N_V2T;
    if (r < N_G2T){ int c=(int)(r/160), d=(int)(r%160); G2T[r]=f2bf(g2[(size_t)d*1024+c]); continue; } r-=N_G2T;
    dout[2228224 + r] = vfirst[r];   // v_first passthrough (offset 2097152+131072)
  }
}

// ---------------- unified NT bf16 MFMA GEMM: C[m][n] = sum_k A[m][k]*B[n][k] ----------------
__global__ __launch_bounds__(256) void gemm_kernel(int phase, char* ws,
  const float* w0b, const float* a0b, const float* v0b, float* dout)
{
  const u16* A; const u16* Bw;
  float* outF=nullptr; const float* bias=nullptr;
  float* SEQf=(float*)(ws+OFF_SEQ);
  u16* UBp=(u16*)(ws+OFF_UB);
  int lda=0, ldb=0, K=0, ldc=0, Nlim=1024, col0=0, outMode=0;
  int y = blockIdx.y;
  if (phase==0){
    A=(const u16*)(ws+OFF_XB); lda=1024; K=1024;
    if (y<8)      { Bw=(const u16*)(ws+OFF_WQB); ldb=1024; col0=y*128;       outMode=1; }
    else if (y<12){ Bw=(const u16*)(ws+OFF_WKB); ldb=1024; col0=(y-8)*128;   outF=(float*)(ws+OFF_KQF); ldc=512; Nlim=512; }
    else if (y<16){ Bw=(const u16*)(ws+OFF_WVB); ldb=1024; col0=(y-12)*128;  outF=(float*)(ws+OFF_VQF); ldc=512; Nlim=512; }
    else          { Bw=(const u16*)(ws+OFF_W1T); ldb=1024; col0=(y-16)*128;  outMode=4; Nlim=320; }
  } else if (phase==1){
    int seg=y>>3; col0=(y&7)*128;
    const int Ks[4]={64,64,32,160};
    const int Ao[4]={0,64,128,160};
    K=Ks[seg]; lda=384; ldb=K;
    A=(const u16*)(ws+OFF_UB) + Ao[seg];
    if (seg==0)     { Bw=(const u16*)(ws+OFF_W2T); outMode=2; bias=w0b; }
    else if (seg==1){ Bw=(const u16*)(ws+OFF_A2T); outMode=3; bias=a0b; outF=(float*)(ws+OFF_S2A); ldc=1024; }
    else if (seg==2){ Bw=(const u16*)(ws+OFF_V2T); outMode=3; bias=v0b; outF=(float*)(ws+OFF_S2V); ldc=1024; }
    else            { Bw=(const u16*)(ws+OFF_G2T); outF=(float*)(ws+OFF_GBUF); ldc=1024; }
  } else {
    A=(const u16*)(ws+OFF_XGB); lda=1024; K=1024;
    Bw=(const u16*)(ws+OFF_WOB); ldb=1024; col0=y*128; outF=dout; ldc=1024;
  }
  int m0 = blockIdx.x*128;
  __shared__ __align__(16) u16 As[128][40];
  __shared__ __align__(16) u16 Bs[128][40];
  int tid=threadIdx.x, l=tid&63, wv=tid>>6, wm=wv>>1, wn=wv&1;
  f32x4 acc[4][4];
  #pragma unroll
  for (int i=0;i<4;i++)
    #pragma unroll
    for (int j=0;j<4;j++) acc[i][j]=(f32x4){0.f,0.f,0.f,0.f};

  for (int k0=0;k0<K;k0+=32){
    #pragma unroll
    for (int c=tid;c<512;c+=256){
      int row=c>>2, seg=c&3;
      *(i32x4*)(&As[row][seg*8]) = *(const i32x4*)(A  + (size_t)(m0+row)*lda  + k0 + seg*8);
      *(i32x4*)(&Bs[row][seg*8]) = *(const i32x4*)(Bw + (size_t)(col0+row)*ldb + k0 + seg*8);
    }
    __syncthreads();
    int kseg=(l>>4)*8, rrow=l&15;
    s16x8 af[4], bf[4];
    #pragma unroll
    for (int mt=0;mt<4;mt++) af[mt]=*(const s16x8*)(&As[wm*64+mt*16+rrow][kseg]);
    #pragma unroll
    for (int nt=0;nt<4;nt++) bf[nt]=*(const s16x8*)(&Bs[wn*64+nt*16+rrow][kseg]);
    #pragma unroll
    for (int mt=0;mt<4;mt++)
      #pragma unroll
      for (int nt=0;nt<4;nt++)
        acc[mt][nt]=__builtin_amdgcn_mfma_f32_16x16x32_bf16(af[mt],bf[nt],acc[mt][nt],0,0,0);
    __syncthreads();
  }
  // epilogue
  #pragma unroll
  for (int mt=0;mt<4;mt++){
    #pragma unroll
    for (int nt=0;nt<4;nt++){
      int nglob = col0 + wn*64 + nt*16 + (l&15);
      if (nglob >= Nlim) continue;
      #pragma unroll
      for (int rg=0;rg<4;rg++){
        int mrow = m0 + wm*64 + mt*16 + ((l>>4)<<2) + rg;
        float val = acc[mt][nt][rg];
        if (outMode==0){
          outF[(size_t)mrow*ldc + nglob] = val;
        } else if (outMode==1){          // r -> SEQ slot 0
          int b=mrow>>10, t=mrow&1023, h=nglob>>6, i=nglob&63;
          SEQf[(((size_t)(b*16+h)*1024+t)*384) + i] = val;
        } else if (outMode==2){          // decay -> SEQ slot 1
          float w = bias[nglob] + val;
          float d = expf(-expf(w));
          int b=mrow>>10, t=mrow&1023, h=nglob>>6, i=nglob&63;
          SEQf[(((size_t)(b*16+h)*1024+t)*384) + 64 + i] = d;
        } else if (outMode==3){          // sigmoid(bias+acc)
          float s = 1.0f/(1.0f+__expf(-(bias[nglob]+val)));
          outF[(size_t)mrow*ldc + nglob] = s;
        } else {                          // fused stage-1 activation -> UB bf16
          float a = (nglob<64) ? tanhf(val)
                  : (nglob<160) ? val
                  : 1.0f/(1.0f+__expf(-val));
          UBp[(size_t)mrow*384 + nglob] = f2bf(a);
        }
      }
    }
  }
}

// ---------------- prep2: build SEQ slots k,v,a,b ----------------
__global__ __launch_bounds__(256) void prep2_kernel(char* ws, const float* vfirst,
  const float* kk_s, const float* ka_s)
{
  const float* KQF=(const float*)(ws+OFF_KQF);
  const float* VQF=(const float*)(ws+OFF_VQF);
  const float* ICLR=(const float*)(ws+OFF_S2A);
  const float* VMIX=(const float*)(ws+OFF_S2V);
  float* SEQf=(float*)(ws+OFF_SEQ);
  int m=blockIdx.x, b=m>>10, t=m&1023;
  int tid=threadIdx.x, c0=tid*4, h=c0>>6, i0=c0&63, hk=h>>1;
  f32x4 kq=*(const f32x4*)(KQF+(size_t)m*512+hk*64+i0);
  f32x4 vq=*(const f32x4*)(VQF+(size_t)m*512+hk*64+i0);
  f32x4 ic=*(const f32x4*)(ICLR+(size_t)m*1024+c0);
  f32x4 vm=*(const f32x4*)(VMIX+(size_t)m*1024+c0);
  f32x4 vf=*(const f32x4*)(vfirst+(size_t)m*1024+c0);
  f32x4 kkc=*(const f32x4*)(kk_s+c0);
  f32x4 kac=*(const f32x4*)(ka_s+c0);
  f32x4 kk=kq*kkc;
  float ssq=kk[0]*kk[0]+kk[1]*kk[1]+kk[2]*kk[2]+kk[3]*kk[3];
  #pragma unroll
  for (int mk=1;mk<16;mk<<=1) ssq += __shfl_xor(ssq,mk);
  float scale = 1.0f / fmaxf(sqrtf(ssq), 1e-12f);
  f32x4 kf,vv,av,bv;
  #pragma unroll
  for (int j=0;j<4;j++){
    float icc = 1.0f + (ic[j]-1.0f)*kac[j];
    float kkn = kk[j]*scale;
    kf[j]=kq[j]*icc;
    vv[j]=vq[j] + (vf[j]-vq[j])*vm[j];
    av[j]=-kkn;
    bv[j]=kkn*icc;
  }
  size_t sb = (((size_t)(b*16+h)*1024)+t)*384 + i0;
  *(f32x4*)(SEQf+sb+128)=kf;
  *(f32x4*)(SEQf+sb+192)=vv;
  *(f32x4*)(SEQf+sb+256)=av;
  *(f32x4*)(SEQf+sb+320)=bv;
}

#define MFMA32(a,b,c) __builtin_amdgcn_mfma_f32_16x16x32_bf16(a,b,c,0,0,0)

// ---------------- precompute: per-chunk S-independent quantities (2048-way parallel) ------
// Record (14336B): P_f[kk][l]x16B, G_f +2048, zloc_f[it][l]x8B +4096, Yloc_f +6144,
//                  bar_f[jt][g2][c]x16B +8192, kar_f +10240, V_f[it][g2][c]x16B +12288.
__global__ __launch_bounds__(64) void pre_kernel(char* ws){
  const float* SEQ=(const float*)(ws+OFF_SEQ);
  int bid=blockIdx.x, bh=bid>>6, ch=bid&63;
  int l=threadIdx.x, c16=l&15, g=l>>4;
  const float* seqb = SEQ + (size_t)bh*(1024*384) + (size_t)ch*6144;
  char* rec = ws + OFF_REC + (size_t)bid*14336;
  float* PLp = (float*)(ws + OFF_PL) + (size_t)bid*64;

  __shared__ __align__(16) float raw[16*396];
  __shared__ __align__(16) float pbuf[16*68];
  __shared__ __align__(16) u16 AT[16*72];
  __shared__ __align__(16) u16 RT[16*72];
  __shared__ __align__(16) u16 BT[16*72];
  __shared__ __align__(16) u16 KT[16*72];
  __shared__ __align__(16) u16 vbb[64*24+16];
  __shared__ __align__(16) u16 zbb[64*24+16];
  __shared__ __align__(16) u16 pbb[64*24+16];
  __shared__ __align__(16) float WN[16*17];
  __shared__ __align__(16) u16 WY[16*24+16];
  __shared__ __align__(16) u16 WB[16*24+16];
  __shared__ __align__(16) u16 WK[16*24+16];
  __shared__ __align__(16) float rhsb[16*68];
  __shared__ __align__(16) float ptmp[16*68];
  __shared__ __align__(16) float gtmp[16*68];
  const s16x8 zero8 = {0,0,0,0,0,0,0,0};

  #pragma unroll
  for (int t=0;t<16;t++){
    const float* src = seqb + (size_t)t*384;
    float* dst = &raw[t*396];
    gload_lds16(src + l*4, dst);
    gload_lds4 (src + 256 + l, dst + 256);
    gload_lds4 (src + 320 + l, dst + 320);
  }
  asm volatile("s_waitcnt vmcnt(0)" ::: "memory");
  __builtin_amdgcn_sched_barrier(0);

  // ---- P1a: lane = channel l. cumprod decay; vbb LDS; bar_f/kar_f/V_f/pL global ----
  {
    float ptv[16]; float pp=1.f;
    #pragma unroll
    for (int t=0;t<16;t++){ pp *= raw[t*396+64+l]; ptv[t]=pp; pbuf[t*68+l]=pp; }
    float pL = ptv[15];
    PLp[l] = pL;
    float bs[16], ks[16], vs[16];
    #pragma unroll
    for (int t=0;t<16;t++){
      float sc = pL * __builtin_amdgcn_rcpf(ptv[t]);
      bs[t]=raw[t*396+320+l]*sc;
      ks[t]=raw[t*396+128+l]*sc;
      vs[t]=raw[t*396+192+l];
    }
    int rlo=(l>>4)*2, rc=l&15;
    i32x4 o;
    o[0]=pk2(vs[0],vs[1]); o[1]=pk2(vs[2],vs[3]); o[2]=pk2(vs[4],vs[5]); o[3]=pk2(vs[6],vs[7]);
    *(i32x4*)(&vbb[l*24]) = o;
    *(i32x4*)(rec + 12288 + (size_t)((rlo+0)*16+rc)*16) = o;
    o[0]=pk2(vs[8],vs[9]); o[1]=pk2(vs[10],vs[11]); o[2]=pk2(vs[12],vs[13]); o[3]=pk2(vs[14],vs[15]);
    *(i32x4*)(&vbb[l*24+8]) = o;
    *(i32x4*)(rec + 12288 + (size_t)((rlo+1)*16+rc)*16) = o;
    o[0]=pk2(bs[0],bs[1]); o[1]=pk2(bs[2],bs[3]); o[2]=pk2(bs[4],bs[5]); o[3]=pk2(bs[6],bs[7]);
    *(i32x4*)(rec + 8192 + (size_t)((rlo+0)*16+rc)*16) = o;
    o[0]=pk2(bs[8],bs[9]); o[1]=pk2(bs[10],bs[11]); o[2]=pk2(bs[12],bs[13]); o[3]=pk2(bs[14],bs[15]);
    *(i32x4*)(rec + 8192 + (size_t)((rlo+1)*16+rc)*16) = o;
    o[0]=pk2(ks[0],ks[1]); o[1]=pk2(ks[2],ks[3]); o[2]=pk2(ks[4],ks[5]); o[3]=pk2(ks[6],ks[7]);
    *(i32x4*)(rec + 10240 + (size_t)((rlo+0)*16+rc)*16) = o;
    o[0]=pk2(ks[8],ks[9]); o[1]=pk2(ks[10],ks[11]); o[2]=pk2(ks[12],ks[13]); o[3]=pk2(ks[14],ks[15]);
    *(i32x4*)(rec + 10240 + (size_t)((rlo+1)*16+rc)*16) = o;
  }

  // ---- P1b: lane (t=c16, group g): write AT,RT,BT,KT ----
  {
    int tt=c16, gg=g;
    f32x4 pa[4], pp[4];
    int tp = (tt==0)?0:(tt-1);
    #pragma unroll
    for (int q=0;q<4;q++){
      pa[q] = *(const f32x4*)(&pbuf[tt*68 + 16*gg + 4*q]);
      pp[q] = *(const f32x4*)(&pbuf[tp*68 + 16*gg + 4*q]);
    }
    if (tt==0){
      #pragma unroll
      for (int q=0;q<4;q++) pp[q] = (f32x4){1.f,1.f,1.f,1.f};
    }
    f32x4 ra[4], rr[4], rb[4], rk[4];
    #pragma unroll
    for (int q=0;q<4;q++){
      ra[q]=*(const f32x4*)(&raw[tt*396+256+16*gg+4*q]);
      rr[q]=*(const f32x4*)(&raw[tt*396+    16*gg+4*q]);
      rb[q]=*(const f32x4*)(&raw[tt*396+320+16*gg+4*q]);
      rk[q]=*(const f32x4*)(&raw[tt*396+128+16*gg+4*q]);
    }
    float va[16], vr[16], vb2[16], vk2[16];
    #pragma unroll
    for (int q=0;q<4;q++)
      #pragma unroll
      for (int e=0;e<4;e++){
        float rp = __builtin_amdgcn_rcpf(pa[q][e]);
        va[q*4+e] = pp[q][e]*ra[q][e];
        vr[q*4+e] = pa[q][e]*rr[q][e];
        vb2[q*4+e] = rb[q][e]*rp;
        vk2[q*4+e] = rk[q][e]*rp;
      }
    i32x4 o;
    o[0]=pk2(va[0],va[1]); o[1]=pk2(va[2],va[3]); o[2]=pk2(va[4],va[5]); o[3]=pk2(va[6],va[7]);
    *(i32x4*)(&AT[tt*72+16*gg]) = o;
    o[0]=pk2(va[8],va[9]); o[1]=pk2(va[10],va[11]); o[2]=pk2(va[12],va[13]); o[3]=pk2(va[14],va[15]);
    *(i32x4*)(&AT[tt*72+16*gg+8]) = o;
    o[0]=pk2(vr[0],vr[1]); o[1]=pk2(vr[2],vr[3]); o[2]=pk2(vr[4],vr[5]); o[3]=pk2(vr[6],vr[7]);
    *(i32x4*)(&RT[tt*72+16*gg]) = o;
    o[0]=pk2(vr[8],vr[9]); o[1]=pk2(vr[10],vr[11]); o[2]=pk2(vr[12],vr[13]); o[3]=pk2(vr[14],vr[15]);
    *(i32x4*)(&RT[tt*72+16*gg+8]) = o;
    o[0]=pk2(vb2[0],vb2[1]); o[1]=pk2(vb2[2],vb2[3]); o[2]=pk2(vb2[4],vb2[5]); o[3]=pk2(vb2[6],vb2[7]);
    *(i32x4*)(&BT[tt*72+16*gg]) = o;
    o[0]=pk2(vb2[8],vb2[9]); o[1]=pk2(vb2[10],vb2[11]); o[2]=pk2(vb2[12],vb2[13]); o[3]=pk2(vb2[14],vb2[15]);
    *(i32x4*)(&BT[tt*72+16*gg+8]) = o;
    o[0]=pk2(vk2[0],vk2[1]); o[1]=pk2(vk2[2],vk2[3]); o[2]=pk2(vk2[4],vk2[5]); o[3]=pk2(vk2[6],vk2[7]);
    *(i32x4*)(&KT[tt*72+16*gg]) = o;
    o[0]=pk2(vk2[8],vk2[9]); o[1]=pk2(vk2[10],vk2[11]); o[2]=pk2(vk2[12],vk2[13]); o[3]=pk2(vk2[14],vk2[15]);
    *(i32x4*)(&KT[tt*72+16*gg+8]) = o;
  }

  // ---- W-block: N, Yhat, Tb, Tk ----
  {
    s16x8 afA[2], afR[2], bfB[2], bfK[2];
    #pragma unroll
    for (int Kt=0;Kt<2;Kt++){
      afA[Kt]=*(const s16x8*)(&AT[c16*72 + 32*Kt + 8*g]);
      afR[Kt]=*(const s16x8*)(&RT[c16*72 + 32*Kt + 8*g]);
      bfB[Kt]=*(const s16x8*)(&BT[c16*72 + 32*Kt + 8*g]);
      bfK[Kt]=*(const s16x8*)(&KT[c16*72 + 32*Kt + 8*g]);
    }
    f32x4 dNN={0.f,0.f,0.f,0.f}, dNY=dNN, dBB=dNN, dBK=dNN;
    #pragma unroll
    for (int Kt=0;Kt<2;Kt++){
      dNN=MFMA32(afA[Kt],bfB[Kt],dNN);
      dNY=MFMA32(afA[Kt],bfK[Kt],dNY);
      dBB=MFMA32(afR[Kt],bfB[Kt],dBB);
      dBK=MFMA32(afR[Kt],bfK[Kt],dBK);
    }
    #pragma unroll
    for (int e=0;e<4;e++){
      int tR=4*g+e, sC=c16;
      WN[tR*17+sC] = dNN[e];
      WY[tR*24+sC] = (sC<tR)? f2bf(dNY[e]) : (u16)0;
      WB[tR*24+sC] = (sC<=tR)? f2bf(dBB[e]) : (u16)0;
      WK[tR*24+sC] = (sC<=tR)? f2bf(dBK[e]) : (u16)0;
    }
  }

  // ---- YhatV -> rhsb ----
  s16x8 vf[4];
  #pragma unroll
  for (int J=0;J<4;J++){
    vf[J]=zero8;
    if (g<2) vf[J]=*(const s16x8*)(&vbb[(16*J+c16)*24 + 8*g]);
  }
  {
    s16x8 wyf=zero8;
    if (g<2) wyf=*(const s16x8*)(&WY[c16*24 + 8*g]);
    f32x4 dR[4];
    #pragma unroll
    for (int J=0;J<4;J++){
      dR[J]=(f32x4){0.f,0.f,0.f,0.f};
      dR[J]=MFMA32(wyf,vf[J],dR[J]);
      #pragma unroll
      for (int e=0;e<4;e++)
        rhsb[(4*g+e)*68 + 16*J + c16] = dR[J][e];
    }
  }

  // ---- P-solve: (I-N)P = Atil, lane = column j=l ----
  {
    float pv[16];
    #pragma unroll
    for (int t=0;t<16;t++) pv[t]=bf2f(AT[t*72+l]);
    #pragma unroll
    for (int t=1;t<16;t++)
      #pragma unroll
      for (int s=0;s<16;s++){
        if (s<t) pv[t] += WN[t*17+s]*pv[s];
      }
    i32x4 o;
    o[0]=pk2(pv[0],pv[1]); o[1]=pk2(pv[2],pv[3]); o[2]=pk2(pv[4],pv[5]); o[3]=pk2(pv[6],pv[7]);
    *(i32x4*)(&pbb[l*24]) = o;
    o[0]=pk2(pv[8],pv[9]); o[1]=pk2(pv[10],pv[11]); o[2]=pk2(pv[12],pv[13]); o[3]=pk2(pv[14],pv[15]);
    *(i32x4*)(&pbb[l*24+8]) = o;
    #pragma unroll
    for (int t=0;t<16;t++) ptmp[t*68+l]=pv[t];
  }

  // ---- z-solve: (I-N)zloc = YhatV, lane = column i=l ----
  {
    float zz[16];
    #pragma unroll
    for (int t=0;t<16;t++) zz[t]=rhsb[t*68+l];
    #pragma unroll
    for (int t=1;t<16;t++)
      #pragma unroll
      for (int s=0;s<16;s++){
        if (s<t) zz[t] += WN[t*17+s]*zz[s];
      }
    i32x4 o;
    o[0]=pk2(zz[0],zz[1]); o[1]=pk2(zz[2],zz[3]); o[2]=pk2(zz[4],zz[5]); o[3]=pk2(zz[6],zz[7]);
    *(i32x4*)(&zbb[l*24]) = o;
    o[0]=pk2(zz[8],zz[9]); o[1]=pk2(zz[10],zz[11]); o[2]=pk2(zz[12],zz[13]); o[3]=pk2(zz[14],zz[15]);
    *(i32x4*)(&zbb[l*24+8]) = o;
  }

  // ---- G = Rtil + Tb*P  -> gtmp ; Yloc = Tb*zloc + Tk*V -> record ----
  {
    s16x8 wbf=zero8, wkf=zero8;
    if (g<2){
      wbf=*(const s16x8*)(&WB[c16*24 + 8*g]);
      wkf=*(const s16x8*)(&WK[c16*24 + 8*g]);
    }
    #pragma unroll
    for (int J=0;J<4;J++){
      s16x8 pfB=zero8, zfB=zero8;
      if (g<2){
        pfB=*(const s16x8*)(&pbb[(16*J+c16)*24 + 8*g]);
        zfB=*(const s16x8*)(&zbb[(16*J+c16)*24 + 8*g]);
      }
      f32x4 dG, dYl=(f32x4){0.f,0.f,0.f,0.f};
      #pragma unroll
      for (int e=0;e<4;e++) dG[e]=bf2f(RT[(4*g+e)*72 + 16*J + c16]);
      dG=MFMA32(wbf,pfB,dG);
      dYl=MFMA32(wbf,zfB,dYl);
      dYl=MFMA32(wkf,vf[J],dYl);
      #pragma unroll
      for (int e=0;e<4;e++) gtmp[(4*g+e)*68 + 16*J + c16]=dG[e];
      i32x2 o2; o2[0]=pk2(dYl[0],dYl[1]); o2[1]=pk2(dYl[2],dYl[3]);
      *(i32x2*)(rec + 6144 + (size_t)(J*64+l)*8) = o2;
    }
  }

  // ---- zloc_f from zbb ----
  #pragma unroll
  for (int it=0;it<4;it++)
    *(i32x2*)(rec + 4096 + (size_t)(it*64+l)*8) =
      *(const i32x2*)(&zbb[(16*it+c16)*24 + 4*g]);

  // ---- P_f / G_f rows from ptmp/gtmp ----
  #pragma unroll
  for (int kk=0;kk<2;kk++){
    f32x4 a0 = *(const f32x4*)(&ptmp[c16*68 + 32*kk + 8*g]);
    f32x4 a1 = *(const f32x4*)(&ptmp[c16*68 + 32*kk + 8*g + 4]);
    i32x4 o;
    o[0]=pk2(a0[0],a0[1]); o[1]=pk2(a0[2],a0[3]); o[2]=pk2(a1[0],a1[1]); o[3]=pk2(a1[2],a1[3]);
    *(i32x4*)(rec + (size_t)(kk*64+l)*16) = o;
    f32x4 b0 = *(const f32x4*)(&gtmp[c16*68 + 32*kk + 8*g]);
    f32x4 b1 = *(const f32x4*)(&gtmp[c16*68 + 32*kk + 8*g + 4]);
    o[0]=pk2(b0[0],b0[1]); o[1]=pk2(b0[2],b0[3]); o[2]=pk2(b1[0],b1[1]); o[3]=pk2(b1[2],b1[3]);
    *(i32x4*)(rec + 2048 + (size_t)(kk*64+l)*16) = o;
  }
}

// ---------------- serial scan v3: 4 waves, i-column strips, barrier-synced staging --------
// wave w owns columns i in [16w,16w+16). Per chunk per wave: 12 MFMA, private z/S transposes.
__global__ __launch_bounds__(256) void scan2_kernel(char* ws, const float* S0, float* dout){
  float* YB=(float*)(ws+OFF_YBUF);
  const char* recb = ws + OFF_REC;
  const float* PLg = (const float*)(ws+OFF_PL);
  int bh=blockIdx.x;
  int tid=threadIdx.x, w=tid>>6, l=tid&63, c16=l&15, g=l>>4;

  __shared__ __align__(16) char buf[2][14336];
  __shared__ __align__(16) float PLs[64*64];
  __shared__ __align__(16) u16 zT[4][16*24];   // per wave: z^T [i16][t16,pad24]
  __shared__ __align__(16) u16 ST[4][16*88];   // per wave: S strip [i16][j64,pad88]
  const s16x8 zero8 = {0,0,0,0,0,0,0,0};

  // Sreg[jt][e] = S^T[16jt+4g+e][i=16w+c16] = S0[i][j]
  f32x4 Sreg[4];
  #pragma unroll
  for (int jt=0;jt<4;jt++)
    Sreg[jt] = *(const f32x4*)(S0 + (size_t)bh*4096 + (size_t)(16*w+c16)*64 + 16*jt + 4*g);
  #pragma unroll
  for (int jt=0;jt<4;jt++){
    i32x2 p; p[0]=pk2(Sreg[jt][0],Sreg[jt][1]); p[1]=pk2(Sreg[jt][2],Sreg[jt][3]);
    *(i32x2*)(&ST[w][c16*88 + 16*jt + 4*g]) = p;
  }

  const char* rb = recb + (size_t)(bh*64)*14336;
  {
    const float* plsrc = PLg + (size_t)bh*4096;
    #pragma unroll
    for (int s=0;s<4;s++){
      int q=w*4+s;
      gload_lds16(plsrc + q*256 + l*4, &PLs[q*256]);
    }
    const float* r0 = (const float*)rb;
    #pragma unroll
    for (int s=0;s<4;s++){
      int q=w*4+s;
      if (q<14) gload_lds16(r0 + q*256 + l*4, (float*)(&buf[0][0]) + q*256);
    }
  }
  asm volatile("s_waitcnt vmcnt(0) lgkmcnt(0)" ::: "memory");
  __builtin_amdgcn_s_barrier();
  __builtin_amdgcn_sched_barrier(0);

  float* yb0 = YB + (size_t)bh*65536;

  #pragma unroll 1
  for (int ch=0; ch<64; ++ch){
    // prefetch loads for this chunk are the oldest 4 (or 2 on wave3) vm ops; y-stores younger
    asm volatile("s_waitcnt vmcnt(4)" ::: "memory");
    __builtin_amdgcn_sched_barrier(0);
    __builtin_amdgcn_s_barrier();
    __builtin_amdgcn_sched_barrier(0);
    const char* bp = buf[ch&1];

    s16x8 pf[2], gf[2], sB[2];
    #pragma unroll
    for (int kk=0;kk<2;kk++){
      pf[kk]=*(const s16x8*)(bp + (size_t)(kk*64+l)*16);
      gf[kk]=*(const s16x8*)(bp + 2048 + (size_t)(kk*64+l)*16);
      sB[kk]=*(const s16x8*)(&ST[w][c16*88 + 32*kk + 8*g]);
    }
    i32x2 zlv=*(const i32x2*)(bp + 4096 + (size_t)(w*64+l)*8);
    i32x2 ylv=*(const i32x2*)(bp + 6144 + (size_t)(w*64+l)*8);
    s16x8 barf[4], karf[4], vfr;
    #pragma unroll
    for (int jt=0;jt<4;jt++){
      barf[jt]= (g<2) ? *(const s16x8*)(bp + 8192  + (size_t)((jt*2+g)*16+c16)*16) : zero8;
      karf[jt]= (g<2) ? *(const s16x8*)(bp + 10240 + (size_t)((jt*2+g)*16+c16)*16) : zero8;
    }
    vfr = (g<2) ? *(const s16x8*)(bp + 12288 + (size_t)((w*2+g)*16+c16)*16) : zero8;

    // prefetch next record (wave-split: 4/4/4/2 loads)
    {
      int nc = (ch<63)?(ch+1):63;
      const float* nrb = (const float*)(rb + (size_t)nc*14336);
      float* db = (float*)(&buf[(ch+1)&1][0]);
      #pragma unroll
      for (int s=0;s<4;s++){
        int q=w*4+s;
        if (q<14) gload_lds16(nrb + q*256 + l*4, db + q*256);
      }
    }

    // z = P.S^T + zloc ; Y = G.S^T + Yloc   (own i-strip only)
    f32x4 dz=cvt4(zlv), dy=cvt4(ylv);
    dz=MFMA32(pf[0],sB[0],dz); dz=MFMA32(pf[1],sB[1],dz);
    dy=MFMA32(gf[0],sB[0],dy); dy=MFMA32(gf[1],sB[1],dy);

    // z transpose to B-frag layout (private)
    {
      i32x2 zp; zp[0]=pk2(dz[0],dz[1]); zp[1]=pk2(dz[2],dz[3]);
      *(i32x2*)(&zT[w][c16*24 + 4*g]) = zp;
    }
    asm volatile("s_waitcnt lgkmcnt(0)" ::: "memory");
    __builtin_amdgcn_sched_barrier(0);
    s16x8 zf = (g<2) ? *(const s16x8*)(&zT[w][c16*24 + 8*g]) : zero8;

    // S' = diag(pL) S + Bbar^T z + Kbar^T V
    #pragma unroll
    for (int jt=0;jt<4;jt++){
      f32x4 pl4 = *(const f32x4*)(&PLs[ch*64 + 16*jt + 4*g]);
      f32x4 acc = Sreg[jt]*pl4;
      acc=MFMA32(barf[jt],zf,acc);
      acc=MFMA32(karf[jt],vfr,acc);
      Sreg[jt]=acc;
    }
    // S strip -> ST for next chunk's B-operand
    #pragma unroll
    for (int jt=0;jt<4;jt++){
      i32x2 p; p[0]=pk2(Sreg[jt][0],Sreg[jt][1]); p[1]=pk2(Sreg[jt][2],Sreg[jt][3]);
      *(i32x2*)(&ST[w][c16*88 + 16*jt + 4*g]) = p;
    }
    // y stores
    {
      float* yb = yb0 + (size_t)ch*1024;
      #pragma unroll
      for (int e=0;e<4;e++)
        yb[(size_t)(4*g+e)*64 + 16*w + c16] = dy[e];
    }
    asm volatile("s_waitcnt lgkmcnt(0)" ::: "memory");
    __builtin_amdgcn_sched_barrier(0);
  }

  // final state
  #pragma unroll
  for (int jt=0;jt<4;jt++)
    *(f32x4*)(dout + 2097152 + (size_t)bh*4096 + (size_t)(16*w+c16)*64 + 16*jt + 4*g) = Sreg[jt];
}

// ---------------- epilogue: groupnorm + bonus + gate -> bf16 ----------------
__global__ __launch_bounds__(256) void epi_kernel(char* ws, const float* rk,
  const float* lnw, const float* lnb)
{
  const float* YB=(const float*)(ws+OFF_YBUF);
  const float* SEQf=(const float*)(ws+OFF_SEQ);
  const float* GB=(const float*)(ws+OFF_GBUF);
  u16* XGB=(u16*)(ws+OFF_XGB);
  int m=blockIdx.x, b=m>>10, t=m&1023;
  int tid=threadIdx.x, c0=tid*4, h=c0>>6, i0=c0&63;
  f32x4 y=*(const f32x4*)(YB + ((size_t)(b*16+h)*1024+t)*64 + i0);
  float s = y[0]+y[1]+y[2]+y[3];
  float ss= y[0]*y[0]+y[1]*y[1]+y[2]*y[2]+y[3]*y[3];
  #pragma unroll
  for (int mk=1;mk<16;mk<<=1){ s+=__shfl_xor(s,mk); ss+=__shfl_xor(ss,mk); }
  float mu=s*(1.0f/64.0f), var=ss*(1.0f/64.0f)-mu*mu;
  float inv=rsqrtf(var + 6.4e-4f);
  size_t sb=((size_t)(b*16+h)*1024+t)*384;
  f32x4 r=*(const f32x4*)(SEQf+sb+i0);
  f32x4 k=*(const f32x4*)(SEQf+sb+128+i0);
  f32x4 v=*(const f32x4*)(SEQf+sb+192+i0);
  f32x4 q=*(const f32x4*)(rk + h*64 + i0);
  float dp = r[0]*k[0]*q[0]+r[1]*k[1]*q[1]+r[2]*k[2]*q[2]+r[3]*k[3]*q[3];
  #pragma unroll
  for (int mk=1;mk<16;mk<<=1) dp+=__shfl_xor(dp,mk);
  f32x4 gg=*(const f32x4*)(GB+(size_t)m*1024+c0);
  u16x4 outv;
  #pragma unroll
  for (int j=0;j<4;j++){
    float xn = (y[j]-mu)*inv*lnw[c0+j] + lnb[c0+j] + dp*v[j];
    outv[j]=f2bf(xn*gg[j]);
  }
  *(u16x4*)(XGB+(size_t)m*1024+c0)=outv;
}

extern "C" void kernel_launch(void* const* d_in, const int* in_sizes, int n_in,
                              void* d_out, int out_size, void* d_ws, size_t ws_size,
                              hipStream_t stream) {
  const float* x      =(const float*)d_in[0];
  const float* S0     =(const float*)d_in[1];
  const float* vfirst =(const float*)d_in[2];
  const float* w0     =(const float*)d_in[3];
  const float* w1     =(const float*)d_in[4];
  const float* w2     =(const float*)d_in[5];
  const float* a0     =(const float*)d_in[6];
  const float* a1     =(const float*)d_in[7];
  const float* a2     =(const float*)d_in[8];
  const float* v0     =(const float*)d_in[9];
  const float* v1     =(const float*)d_in[10];
  const float* v2     =(const float*)d_in[11];
  const float* g1     =(const float*)d_in[12];
  const float* g2     =(const float*)d_in[13];
  const float* k_k    =(const float*)d_in[14];
  const float* k_a    =(const float*)d_in[15];
  const float* r_k    =(const float*)d_in[16];
  const float* Wq     =(const float*)d_in[17];
  const float* Wk     =(const float*)d_in[18];
  const float* Wv     =(const float*)d_in[19];
  const float* Wo     =(const float*)d_in[20];
  const float* ln_w   =(const float*)d_in[21];
  const float* ln_b   =(const float*)d_in[22];
  char* ws=(char*)d_ws;
  float* dout=(float*)d_out;

  prep_kernel<<<2048,256,0,stream>>>(ws,x,vfirst,w1,w2,a1,a2,v1,v2,g1,g2,Wq,Wk,Wv,Wo,dout);
  gemm_kernel<<<dim3(16,19),256,0,stream>>>(0,ws,w0,a0,v0,dout);
  gemm_kernel<<<dim3(16,32),256,0,stream>>>(1,ws,w0,a0,v0,dout);
  prep2_kernel<<<2048,256,0,stream>>>(ws,vfirst,k_k,k_a);
  pre_kernel<<<2048,64,0,stream>>>(ws);
  scan2_kernel<<<32,256,0,stream>>>(ws,S0,dout);
  epi_kernel<<<2048,256,0,stream>>>(ws,r_k,ln_w,ln_b);
  gemm_kernel<<<dim3(16,8),256,0,stream>>>(2,ws,w0,a0,v0,dout);
}

// Round 7
// 237.023 us; speedup vs baseline: 5.3242x; 1.0672x over previous
//
#include <hip/hip_runtime.h>

typedef unsigned short u16;
typedef __attribute__((ext_vector_type(8))) short s16x8;
typedef __attribute__((ext_vector_type(4))) float f32x4;
typedef __attribute__((ext_vector_type(4))) int   i32x4;
typedef __attribute__((ext_vector_type(2))) int   i32x2;
typedef __attribute__((ext_vector_type(4))) unsigned short u16x4;

// ---------------- workspace layout (bytes) ----------------
constexpr size_t OFF_XB   = 0;                     // bf16 x          [2048][1024]
constexpr size_t OFF_WQB  = OFF_XB   + 4194304;    // bf16 Wq         [1024][1024]
constexpr size_t OFF_WKB  = OFF_WQB  + 2097152;    // bf16 Wk         [512][1024]
constexpr size_t OFF_WVB  = OFF_WKB  + 1048576;    // bf16 Wv         [512][1024]
constexpr size_t OFF_WOB  = OFF_WVB  + 1048576;    // bf16 Wo         [1024][1024]
constexpr size_t OFF_W1T  = OFF_WOB  + 2097152;    // bf16 W1T [384][1024]; reused later as PL array
constexpr size_t OFF_W2T  = OFF_W1T  + 786432;     // bf16 w2T        [1024][64]
constexpr size_t OFF_A2T  = OFF_W2T  + 131072;     // bf16 a2T        [1024][64]
constexpr size_t OFF_V2T  = OFF_A2T  + 131072;     // bf16 v2T        [1024][32]
constexpr size_t OFF_G2T  = OFF_V2T  + 65536;      // bf16 g2T        [1024][160]
constexpr size_t OFF_KQF  = OFF_G2T  + 327680;     // f32 k-proj [2048][512]; reused as chunk records
constexpr size_t OFF_VQF  = OFF_KQF  + 4194304;    // f32 v-proj      [2048][512]
constexpr size_t OFF_URAW = OFF_VQF  + 4194304;    // (dead; kept for layout)
constexpr size_t OFF_UB   = OFF_URAW + 2621440;    // bf16 stage1 act [2048][384]
constexpr size_t OFF_S2A  = OFF_UB   + 1572864;    // f32 iclr        [2048][1024]
constexpr size_t OFF_S2V  = OFF_S2A  + 8388608;    // f32 vmix        [2048][1024]
constexpr size_t OFF_GBUF = OFF_S2V  + 8388608;    // f32 gate        [2048][1024]
constexpr size_t OFF_SEQ  = OFF_GBUF + 8388608;    // f32 SEQ [2][16][1024][6][64] (r,decay,k,v,a,b)
constexpr size_t OFF_YBUF = OFF_SEQ  + 50331648;   // f32 y   [2][16][1024][64]
constexpr size_t OFF_XGB  = OFF_YBUF + 8388608;    // bf16 xn*g       [2048][1024]

// chunk record overlay (dead KQF..S2V window, 2048 records x 14336B = exact fit)
// v3 layout: 0 P_f(2048) | 2048 G_f(2048) | 4096 barkar(4096, A-frag, c XOR (slice&3)<<2)
//            | 8192 + w*1536: { zloc_w(512) | Yloc_w(512) | V_w(512) }  (w = i-strip 0..3)
constexpr size_t OFF_REC  = OFF_KQF;
constexpr size_t OFF_PL   = OFF_W1T;   // f32 pL [2048][64]

__device__ __forceinline__ u16 f2bf(float f){
  unsigned int u = __builtin_bit_cast(unsigned int, f);
  u = u + 0x7fffu + ((u >> 16) & 1u);
  return (u16)(u >> 16);
}
__device__ __forceinline__ int pk2(float a, float b){
  return (int)((unsigned)f2bf(a) | ((unsigned)f2bf(b) << 16));
}
__device__ __forceinline__ float bf2f(u16 h){
  return __builtin_bit_cast(float, ((unsigned)h) << 16);
}
__device__ __forceinline__ f32x4 cvt4(i32x2 v){
  unsigned a=(unsigned)v[0], b=(unsigned)v[1];
  f32x4 r;
  r[0]=__builtin_bit_cast(float, a<<16);
  r[1]=__builtin_bit_cast(float, a&0xffff0000u);
  r[2]=__builtin_bit_cast(float, b<<16);
  r[3]=__builtin_bit_cast(float, b&0xffff0000u);
  return r;
}

__device__ __forceinline__ void gload_lds16(const float* g, float* l){
  __builtin_amdgcn_global_load_lds((const __attribute__((address_space(1))) void*)g,
                                   (__attribute__((address_space(3))) void*)l, 16, 0, 0);
}
__device__ __forceinline__ void gload_lds4(const float* g, float* l){
  __builtin_amdgcn_global_load_lds((const __attribute__((address_space(1))) void*)g,
                                   (__attribute__((address_space(3))) void*)l, 4, 0, 0);
}

// ---------------- prep: convert/transpose + v_first passthrough ----------------
constexpr size_t N_XB=2097152, N_WQ=1048576, N_WK=524288, N_WV=524288, N_WO=1048576,
  N_W1T=393216, N_W2T=65536, N_A2T=65536, N_V2T=32768, N_G2T=163840, N_VF=2097152;
constexpr size_t PREP_TOT = N_XB+N_WQ+N_WK+N_WV+N_WO+N_W1T+N_W2T+N_A2T+N_V2T+N_G2T+N_VF;

__global__ __launch_bounds__(256) void prep_kernel(char* ws, const float* x, const float* vfirst,
  const float* w1, const float* w2, const float* a1, const float* a2,
  const float* v1, const float* v2, const float* g1, const float* g2,
  const float* Wq, const float* Wk, const float* Wv, const float* Wo, float* dout)
{
  u16* XB=(u16*)(ws+OFF_XB); u16* WQB=(u16*)(ws+OFF_WQB); u16* WKB=(u16*)(ws+OFF_WKB);
  u16* WVB=(u16*)(ws+OFF_WVB); u16* WOB=(u16*)(ws+OFF_WOB); u16* W1T=(u16*)(ws+OFF_W1T);
  u16* W2T=(u16*)(ws+OFF_W2T); u16* A2T=(u16*)(ws+OFF_A2T); u16* V2T=(u16*)(ws+OFF_V2T);
  u16* G2T=(u16*)(ws+OFF_G2T);
  for (size_t idx=(size_t)blockIdx.x*256+threadIdx.x; idx<PREP_TOT; idx+=(size_t)gridDim.x*256){
    size_t r = idx;
    if (r < N_XB){ XB[r]=f2bf(x[r]); continue; } r-=N_XB;
    if (r < N_WQ){ WQB[r]=f2bf(Wq[r]); continue; } r-=N_WQ;
    if (r < N_WK){ WKB[r]=f2bf(Wk[r]); continue; } r-=N_WK;
    if (r < N_WV){ WVB[r]=f2bf(Wv[r]); continue; } r-=N_WV;
    if (r < N_WO){ WOB[r]=f2bf(Wo[r]); continue; } r-=N_WO;
    if (r < N_W1T){
      int n=(int)(r>>10), k=(int)(r&1023); float v=0.f;
      if (n<64) v=w1[(size_t)k*64+n];
      else if (n<128) v=a1[(size_t)k*64+(n-64)];
      else if (n<160) v=v1[(size_t)k*32+(n-128)];
      else if (n<320) v=g1[(size_t)k*160+(n-160)];
      W1T[r]=f2bf(v); continue; } r-=N_W1T;
    if (r < N_W2T){ int c=(int)(r>>6), d=(int)(r&63); W2T[r]=f2bf(w2[(size_t)d*1024+c]); continue; } r-=N_W2T;
    if (r < N_A2T){ int c=(int)(r>>6), d=(int)(r&63); A2T[r]=f2bf(a2[(size_t)d*1024+c]); continue; } r-=N_A2T;
    if (r < N_V2T){ int c=(int)(r>>5), d=(int)(r&31); V2T[r]=f2bf(v2[(size_t)d*1024+c]); continue; } r-=N_V2T;
    if (r < N_G2T){ int c=(int)(r/160), d=(int)(r%160); G2T[r]=f2bf(g2[(size_t)d*1024+c]); continue; } r-=N_G2T;
    dout[2228224 + r] = vfirst[r];   // v_first passthrough (offset 2097152+131072)
  }
}

// ---------------- unified NT bf16 MFMA GEMM: C[m][n] = sum_k A[m][k]*B[n][k] ----------------
__global__ __launch_bounds__(256) void gemm_kernel(int phase, char* ws,
  const float* w0b, const float* a0b, const float* v0b, float* dout)
{
  const u16* A; const u16* Bw;
  float* outF=nullptr; const float* bias=nullptr;
  float* SEQf=(float*)(ws+OFF_SEQ);
  u16* UBp=(u16*)(ws+OFF_UB);
  int lda=0, ldb=0, K=0, ldc=0, Nlim=1024, col0=0, outMode=0;
  int y = blockIdx.y;
  if (phase==0){
    A=(const u16*)(ws+OFF_XB); lda=1024; K=1024;
    if (y<8)      { Bw=(const u16*)(ws+OFF_WQB); ldb=1024; col0=y*128;       outMode=1; }
    else if (y<12){ Bw=(const u16*)(ws+OFF_WKB); ldb=1024; col0=(y-8)*128;   outF=(float*)(ws+OFF_KQF); ldc=512; Nlim=512; }
    else if (y<16){ Bw=(const u16*)(ws+OFF_WVB); ldb=1024; col0=(y-12)*128;  outF=(float*)(ws+OFF_VQF); ldc=512; Nlim=512; }
    else          { Bw=(const u16*)(ws+OFF_W1T); ldb=1024; col0=(y-16)*128;  outMode=4; Nlim=320; }
  } else if (phase==1){
    int seg=y>>3; col0=(y&7)*128;
    const int Ks[4]={64,64,32,160};
    const int Ao[4]={0,64,128,160};
    K=Ks[seg]; lda=384; ldb=K;
    A=(const u16*)(ws+OFF_UB) + Ao[seg];
    if (seg==0)     { Bw=(const u16*)(ws+OFF_W2T); outMode=2; bias=w0b; }
    else if (seg==1){ Bw=(const u16*)(ws+OFF_A2T); outMode=3; bias=a0b; outF=(float*)(ws+OFF_S2A); ldc=1024; }
    else if (seg==2){ Bw=(const u16*)(ws+OFF_V2T); outMode=3; bias=v0b; outF=(float*)(ws+OFF_S2V); ldc=1024; }
    else            { Bw=(const u16*)(ws+OFF_G2T); outF=(float*)(ws+OFF_GBUF); ldc=1024; }
  } else {
    A=(const u16*)(ws+OFF_XGB); lda=1024; K=1024;
    Bw=(const u16*)(ws+OFF_WOB); ldb=1024; col0=y*128; outF=dout; ldc=1024;
  }
  int m0 = blockIdx.x*128;
  __shared__ __align__(16) u16 As[128][40];
  __shared__ __align__(16) u16 Bs[128][40];
  int tid=threadIdx.x, l=tid&63, wv=tid>>6, wm=wv>>1, wn=wv&1;
  f32x4 acc[4][4];
  #pragma unroll
  for (int i=0;i<4;i++)
    #pragma unroll
    for (int j=0;j<4;j++) acc[i][j]=(f32x4){0.f,0.f,0.f,0.f};

  for (int k0=0;k0<K;k0+=32){
    #pragma unroll
    for (int c=tid;c<512;c+=256){
      int row=c>>2, seg=c&3;
      *(i32x4*)(&As[row][seg*8]) = *(const i32x4*)(A  + (size_t)(m0+row)*lda  + k0 + seg*8);
      *(i32x4*)(&Bs[row][seg*8]) = *(const i32x4*)(Bw + (size_t)(col0+row)*ldb + k0 + seg*8);
    }
    __syncthreads();
    int kseg=(l>>4)*8, rrow=l&15;
    s16x8 af[4], bf[4];
    #pragma unroll
    for (int mt=0;mt<4;mt++) af[mt]=*(const s16x8*)(&As[wm*64+mt*16+rrow][kseg]);
    #pragma unroll
    for (int nt=0;nt<4;nt++) bf[nt]=*(const s16x8*)(&Bs[wn*64+nt*16+rrow][kseg]);
    #pragma unroll
    for (int mt=0;mt<4;mt++)
      #pragma unroll
      for (int nt=0;nt<4;nt++)
        acc[mt][nt]=__builtin_amdgcn_mfma_f32_16x16x32_bf16(af[mt],bf[nt],acc[mt][nt],0,0,0);
    __syncthreads();
  }
  // epilogue
  #pragma unroll
  for (int mt=0;mt<4;mt++){
    #pragma unroll
    for (int nt=0;nt<4;nt++){
      int nglob = col0 + wn*64 + nt*16 + (l&15);
      if (nglob >= Nlim) continue;
      #pragma unroll
      for (int rg=0;rg<4;rg++){
        int mrow = m0 + wm*64 + mt*16 + ((l>>4)<<2) + rg;
        float val = acc[mt][nt][rg];
        if (outMode==0){
          outF[(size_t)mrow*ldc + nglob] = val;
        } else if (outMode==1){          // r -> SEQ slot 0
          int b=mrow>>10, t=mrow&1023, h=nglob>>6, i=nglob&63;
          SEQf[(((size_t)(b*16+h)*1024+t)*384) + i] = val;
        } else if (outMode==2){          // decay -> SEQ slot 1
          float w = bias[nglob] + val;
          float d = expf(-expf(w));
          int b=mrow>>10, t=mrow&1023, h=nglob>>6, i=nglob&63;
          SEQf[(((size_t)(b*16+h)*1024+t)*384) + 64 + i] = d;
        } else if (outMode==3){          // sigmoid(bias+acc)
          float s = 1.0f/(1.0f+__expf(-(bias[nglob]+val)));
          outF[(size_t)mrow*ldc + nglob] = s;
        } else {                          // fused stage-1 activation -> UB bf16
          float a = (nglob<64) ? tanhf(val)
                  : (nglob<160) ? val
                  : 1.0f/(1.0f+__expf(-val));
          UBp[(size_t)mrow*384 + nglob] = f2bf(a);
        }
      }
    }
  }
}

// ---------------- prep2: build SEQ slots k,v,a,b ----------------
__global__ __launch_bounds__(256) void prep2_kernel(char* ws, const float* vfirst,
  const float* kk_s, const float* ka_s)
{
  const float* KQF=(const float*)(ws+OFF_KQF);
  const float* VQF=(const float*)(ws+OFF_VQF);
  const float* ICLR=(const float*)(ws+OFF_S2A);
  const float* VMIX=(const float*)(ws+OFF_S2V);
  float* SEQf=(float*)(ws+OFF_SEQ);
  int m=blockIdx.x, b=m>>10, t=m&1023;
  int tid=threadIdx.x, c0=tid*4, h=c0>>6, i0=c0&63, hk=h>>1;
  f32x4 kq=*(const f32x4*)(KQF+(size_t)m*512+hk*64+i0);
  f32x4 vq=*(const f32x4*)(VQF+(size_t)m*512+hk*64+i0);
  f32x4 ic=*(const f32x4*)(ICLR+(size_t)m*1024+c0);
  f32x4 vm=*(const f32x4*)(VMIX+(size_t)m*1024+c0);
  f32x4 vf=*(const f32x4*)(vfirst+(size_t)m*1024+c0);
  f32x4 kkc=*(const f32x4*)(kk_s+c0);
  f32x4 kac=*(const f32x4*)(ka_s+c0);
  f32x4 kk=kq*kkc;
  float ssq=kk[0]*kk[0]+kk[1]*kk[1]+kk[2]*kk[2]+kk[3]*kk[3];
  #pragma unroll
  for (int mk=1;mk<16;mk<<=1) ssq += __shfl_xor(ssq,mk);
  float scale = 1.0f / fmaxf(sqrtf(ssq), 1e-12f);
  f32x4 kf,vv,av,bv;
  #pragma unroll
  for (int j=0;j<4;j++){
    float icc = 1.0f + (ic[j]-1.0f)*kac[j];
    float kkn = kk[j]*scale;
    kf[j]=kq[j]*icc;
    vv[j]=vq[j] + (vf[j]-vq[j])*vm[j];
    av[j]=-kkn;
    bv[j]=kkn*icc;
  }
  size_t sb = (((size_t)(b*16+h)*1024)+t)*384 + i0;
  *(f32x4*)(SEQf+sb+128)=kf;
  *(f32x4*)(SEQf+sb+192)=vv;
  *(f32x4*)(SEQf+sb+256)=av;
  *(f32x4*)(SEQf+sb+320)=bv;
}

#define MFMA32(a,b,c) __builtin_amdgcn_mfma_f32_16x16x32_bf16(a,b,c,0,0,0)

// ---------------- precompute: per-chunk S-independent quantities (2048-way parallel) ------
__global__ __launch_bounds__(64) void pre_kernel(char* ws){
  const float* SEQ=(const float*)(ws+OFF_SEQ);
  int bid=blockIdx.x, bh=bid>>6, ch=bid&63;
  int l=threadIdx.x, c16=l&15, g=l>>4;
  const float* seqb = SEQ + (size_t)bh*(1024*384) + (size_t)ch*6144;
  char* rec = ws + OFF_REC + (size_t)bid*14336;
  float* PLp = (float*)(ws + OFF_PL) + (size_t)bid*64;

  __shared__ __align__(16) float raw[16*396];
  __shared__ __align__(16) float pbuf[16*68];
  __shared__ __align__(16) u16 AT[16*72];
  __shared__ __align__(16) u16 RT[16*72];
  __shared__ __align__(16) u16 BT[16*72];
  __shared__ __align__(16) u16 KT[16*72];
  __shared__ __align__(16) u16 vbb[64*24+16];
  __shared__ __align__(16) u16 zbb[64*24+16];
  __shared__ __align__(16) u16 pbb[64*24+16];
  __shared__ __align__(16) float WN[16*17];
  __shared__ __align__(16) u16 WY[16*24+16];
  __shared__ __align__(16) u16 WB[16*24+16];
  __shared__ __align__(16) u16 WK[16*24+16];
  __shared__ __align__(16) float rhsb[16*68];
  __shared__ __align__(16) float ptmp[16*68];
  __shared__ __align__(16) float gtmp[16*68];
  const s16x8 zero8 = {0,0,0,0,0,0,0,0};

  #pragma unroll
  for (int t=0;t<16;t++){
    const float* src = seqb + (size_t)t*384;
    float* dst = &raw[t*396];
    gload_lds16(src + l*4, dst);
    gload_lds4 (src + 256 + l, dst + 256);
    gload_lds4 (src + 320 + l, dst + 320);
  }
  asm volatile("s_waitcnt vmcnt(0)" ::: "memory");
  __builtin_amdgcn_sched_barrier(0);

  // ---- P1a: lane = channel l. cumprod decay; vbb LDS; barkar/V/pL writes ----
  {
    float ptv[16]; float pp=1.f;
    #pragma unroll
    for (int t=0;t<16;t++){ pp *= raw[t*396+64+l]; ptv[t]=pp; pbuf[t*68+l]=pp; }
    float pL = ptv[15];
    PLp[l] = pL;
    float bs[16], ks[16], vs[16];
    #pragma unroll
    for (int t=0;t<16;t++){
      float sc = pL * __builtin_amdgcn_rcpf(ptv[t]);
      bs[t]=raw[t*396+320+l]*sc;
      ks[t]=raw[t*396+128+l]*sc;
      vs[t]=raw[t*396+192+l];
    }
    int it=l>>4, rc=l&15;
    size_t slice = 8192 + (size_t)it*1536;
    i32x4 o;
    o[0]=pk2(vs[0],vs[1]); o[1]=pk2(vs[2],vs[3]); o[2]=pk2(vs[4],vs[5]); o[3]=pk2(vs[6],vs[7]);
    *(i32x4*)(&vbb[l*24]) = o;
    *(i32x4*)(rec + slice + 1024 + (size_t)(0*16+rc)*16) = o;
    o[0]=pk2(vs[8],vs[9]); o[1]=pk2(vs[10],vs[11]); o[2]=pk2(vs[12],vs[13]); o[3]=pk2(vs[14],vs[15]);
    *(i32x4*)(&vbb[l*24+8]) = o;
    *(i32x4*)(rec + slice + 1024 + (size_t)(1*16+rc)*16) = o;
    // barkar A-frag section: slice s = it*4 + {0,1: bar halves, 2,3: kar halves}, c XOR (s&3)<<2
    o[0]=pk2(bs[0],bs[1]); o[1]=pk2(bs[2],bs[3]); o[2]=pk2(bs[4],bs[5]); o[3]=pk2(bs[6],bs[7]);
    *(i32x4*)(rec + 4096 + (size_t)((it*4+0)*16 + (rc^0 ))*16) = o;
    o[0]=pk2(bs[8],bs[9]); o[1]=pk2(bs[10],bs[11]); o[2]=pk2(bs[12],bs[13]); o[3]=pk2(bs[14],bs[15]);
    *(i32x4*)(rec + 4096 + (size_t)((it*4+1)*16 + (rc^4 ))*16) = o;
    o[0]=pk2(ks[0],ks[1]); o[1]=pk2(ks[2],ks[3]); o[2]=pk2(ks[4],ks[5]); o[3]=pk2(ks[6],ks[7]);
    *(i32x4*)(rec + 4096 + (size_t)((it*4+2)*16 + (rc^8 ))*16) = o;
    o[0]=pk2(ks[8],ks[9]); o[1]=pk2(ks[10],ks[11]); o[2]=pk2(ks[12],ks[13]); o[3]=pk2(ks[14],ks[15]);
    *(i32x4*)(rec + 4096 + (size_t)((it*4+3)*16 + (rc^12))*16) = o;
  }

  // ---- P1b: lane (t=c16, group g): write AT,RT,BT,KT ----
  {
    int tt=c16, gg=g;
    f32x4 pa[4], pp[4];
    int tp = (tt==0)?0:(tt-1);
    #pragma unroll
    for (int q=0;q<4;q++){
      pa[q] = *(const f32x4*)(&pbuf[tt*68 + 16*gg + 4*q]);
      pp[q] = *(const f32x4*)(&pbuf[tp*68 + 16*gg + 4*q]);
    }
    if (tt==0){
      #pragma unroll
      for (int q=0;q<4;q++) pp[q] = (f32x4){1.f,1.f,1.f,1.f};
    }
    f32x4 ra[4], rr[4], rb[4], rk[4];
    #pragma unroll
    for (int q=0;q<4;q++){
      ra[q]=*(const f32x4*)(&raw[tt*396+256+16*gg+4*q]);
      rr[q]=*(const f32x4*)(&raw[tt*396+    16*gg+4*q]);
      rb[q]=*(const f32x4*)(&raw[tt*396+320+16*gg+4*q]);
      rk[q]=*(const f32x4*)(&raw[tt*396+128+16*gg+4*q]);
    }
    float va[16], vr[16], vb2[16], vk2[16];
    #pragma unroll
    for (int q=0;q<4;q++)
      #pragma unroll
      for (int e=0;e<4;e++){
        float rp = __builtin_amdgcn_rcpf(pa[q][e]);
        va[q*4+e] = pp[q][e]*ra[q][e];
        vr[q*4+e] = pa[q][e]*rr[q][e];
        vb2[q*4+e] = rb[q][e]*rp;
        vk2[q*4+e] = rk[q][e]*rp;
      }
    i32x4 o;
    o[0]=pk2(va[0],va[1]); o[1]=pk2(va[2],va[3]); o[2]=pk2(va[4],va[5]); o[3]=pk2(va[6],va[7]);
    *(i32x4*)(&AT[tt*72+16*gg]) = o;
    o[0]=pk2(va[8],va[9]); o[1]=pk2(va[10],va[11]); o[2]=pk2(va[12],va[13]); o[3]=pk2(va[14],va[15]);
    *(i32x4*)(&AT[tt*72+16*gg+8]) = o;
    o[0]=pk2(vr[0],vr[1]); o[1]=pk2(vr[2],vr[3]); o[2]=pk2(vr[4],vr[5]); o[3]=pk2(vr[6],vr[7]);
    *(i32x4*)(&RT[tt*72+16*gg]) = o;
    o[0]=pk2(vr[8],vr[9]); o[1]=pk2(vr[10],vr[11]); o[2]=pk2(vr[12],vr[13]); o[3]=pk2(vr[14],vr[15]);
    *(i32x4*)(&RT[tt*72+16*gg+8]) = o;
    o[0]=pk2(vb2[0],vb2[1]); o[1]=pk2(vb2[2],vb2[3]); o[2]=pk2(vb2[4],vb2[5]); o[3]=pk2(vb2[6],vb2[7]);
    *(i32x4*)(&BT[tt*72+16*gg]) = o;
    o[0]=pk2(vb2[8],vb2[9]); o[1]=pk2(vb2[10],vb2[11]); o[2]=pk2(vb2[12],vb2[13]); o[3]=pk2(vb2[14],vb2[15]);
    *(i32x4*)(&BT[tt*72+16*gg+8]) = o;
    o[0]=pk2(vk2[0],vk2[1]); o[1]=pk2(vk2[2],vk2[3]); o[2]=pk2(vk2[4],vk2[5]); o[3]=pk2(vk2[6],vk2[7]);
    *(i32x4*)(&KT[tt*72+16*gg]) = o;
    o[0]=pk2(vk2[8],vk2[9]); o[1]=pk2(vk2[10],vk2[11]); o[2]=pk2(vk2[12],vk2[13]); o[3]=pk2(vk2[14],vk2[15]);
    *(i32x4*)(&KT[tt*72+16*gg+8]) = o;
  }

  // ---- W-block: N, Yhat, Tb, Tk ----
  {
    s16x8 afA[2], afR[2], bfB[2], bfK[2];
    #pragma unroll
    for (int Kt=0;Kt<2;Kt++){
      afA[Kt]=*(const s16x8*)(&AT[c16*72 + 32*Kt + 8*g]);
      afR[Kt]=*(const s16x8*)(&RT[c16*72 + 32*Kt + 8*g]);
      bfB[Kt]=*(const s16x8*)(&BT[c16*72 + 32*Kt + 8*g]);
      bfK[Kt]=*(const s16x8*)(&KT[c16*72 + 32*Kt + 8*g]);
    }
    f32x4 dNN={0.f,0.f,0.f,0.f}, dNY=dNN, dBB=dNN, dBK=dNN;
    #pragma unroll
    for (int Kt=0;Kt<2;Kt++){
      dNN=MFMA32(afA[Kt],bfB[Kt],dNN);
      dNY=MFMA32(afA[Kt],bfK[Kt],dNY);
      dBB=MFMA32(afR[Kt],bfB[Kt],dBB);
      dBK=MFMA32(afR[Kt],bfK[Kt],dBK);
    }
    #pragma unroll
    for (int e=0;e<4;e++){
      int tR=4*g+e, sC=c16;
      WN[tR*17+sC] = dNN[e];
      WY[tR*24+sC] = (sC<tR)? f2bf(dNY[e]) : (u16)0;
      WB[tR*24+sC] = (sC<=tR)? f2bf(dBB[e]) : (u16)0;
      WK[tR*24+sC] = (sC<=tR)? f2bf(dBK[e]) : (u16)0;
    }
  }

  // ---- YhatV -> rhsb ----
  s16x8 vf[4];
  #pragma unroll
  for (int J=0;J<4;J++){
    vf[J]=zero8;
    if (g<2) vf[J]=*(const s16x8*)(&vbb[(16*J+c16)*24 + 8*g]);
  }
  {
    s16x8 wyf=zero8;
    if (g<2) wyf=*(const s16x8*)(&WY[c16*24 + 8*g]);
    f32x4 dR[4];
    #pragma unroll
    for (int J=0;J<4;J++){
      dR[J]=(f32x4){0.f,0.f,0.f,0.f};
      dR[J]=MFMA32(wyf,vf[J],dR[J]);
      #pragma unroll
      for (int e=0;e<4;e++)
        rhsb[(4*g+e)*68 + 16*J + c16] = dR[J][e];
    }
  }

  // ---- P-solve: (I-N)P = Atil, lane = column j=l ----
  {
    float pv[16];
    #pragma unroll
    for (int t=0;t<16;t++) pv[t]=bf2f(AT[t*72+l]);
    #pragma unroll
    for (int t=1;t<16;t++)
      #pragma unroll
      for (int s=0;s<16;s++){
        if (s<t) pv[t] += WN[t*17+s]*pv[s];
      }
    i32x4 o;
    o[0]=pk2(pv[0],pv[1]); o[1]=pk2(pv[2],pv[3]); o[2]=pk2(pv[4],pv[5]); o[3]=pk2(pv[6],pv[7]);
    *(i32x4*)(&pbb[l*24]) = o;
    o[0]=pk2(pv[8],pv[9]); o[1]=pk2(pv[10],pv[11]); o[2]=pk2(pv[12],pv[13]); o[3]=pk2(pv[14],pv[15]);
    *(i32x4*)(&pbb[l*24+8]) = o;
    #pragma unroll
    for (int t=0;t<16;t++) ptmp[t*68+l]=pv[t];
  }

  // ---- z-solve: (I-N)zloc = YhatV, lane = column i=l ----
  {
    float zz[16];
    #pragma unroll
    for (int t=0;t<16;t++) zz[t]=rhsb[t*68+l];
    #pragma unroll
    for (int t=1;t<16;t++)
      #pragma unroll
      for (int s=0;s<16;s++){
        if (s<t) zz[t] += WN[t*17+s]*zz[s];
      }
    i32x4 o;
    o[0]=pk2(zz[0],zz[1]); o[1]=pk2(zz[2],zz[3]); o[2]=pk2(zz[4],zz[5]); o[3]=pk2(zz[6],zz[7]);
    *(i32x4*)(&zbb[l*24]) = o;
    o[0]=pk2(zz[8],zz[9]); o[1]=pk2(zz[10],zz[11]); o[2]=pk2(zz[12],zz[13]); o[3]=pk2(zz[14],zz[15]);
    *(i32x4*)(&zbb[l*24+8]) = o;
  }

  // ---- G = Rtil + Tb*P -> gtmp ; Yloc = Tb*zloc + Tk*V -> record slice ----
  {
    s16x8 wbf=zero8, wkf=zero8;
    if (g<2){
      wbf=*(const s16x8*)(&WB[c16*24 + 8*g]);
      wkf=*(const s16x8*)(&WK[c16*24 + 8*g]);
    }
    #pragma unroll
    for (int J=0;J<4;J++){
      s16x8 pfB=zero8, zfB=zero8;
      if (g<2){
        pfB=*(const s16x8*)(&pbb[(16*J+c16)*24 + 8*g]);
        zfB=*(const s16x8*)(&zbb[(16*J+c16)*24 + 8*g]);
      }
      f32x4 dG, dYl=(f32x4){0.f,0.f,0.f,0.f};
      #pragma unroll
      for (int e=0;e<4;e++) dG[e]=bf2f(RT[(4*g+e)*72 + 16*J + c16]);
      dG=MFMA32(wbf,pfB,dG);
      dYl=MFMA32(wbf,zfB,dYl);
      dYl=MFMA32(wkf,vf[J],dYl);
      #pragma unroll
      for (int e=0;e<4;e++) gtmp[(4*g+e)*68 + 16*J + c16]=dG[e];
      i32x2 o2; o2[0]=pk2(dYl[0],dYl[1]); o2[1]=pk2(dYl[2],dYl[3]);
      *(i32x2*)(rec + 8192 + (size_t)J*1536 + 512 + (size_t)l*8) = o2;
    }
  }

  // ---- zloc into record slices ----
  #pragma unroll
  for (int it=0;it<4;it++)
    *(i32x2*)(rec + 8192 + (size_t)it*1536 + (size_t)l*8) =
      *(const i32x2*)(&zbb[(16*it+c16)*24 + 4*g]);

  // ---- P_f / G_f rows from ptmp/gtmp ----
  #pragma unroll
  for (int kk=0;kk<2;kk++){
    f32x4 a0 = *(const f32x4*)(&ptmp[c16*68 + 32*kk + 8*g]);
    f32x4 a1 = *(const f32x4*)(&ptmp[c16*68 + 32*kk + 8*g + 4]);
    i32x4 o;
    o[0]=pk2(a0[0],a0[1]); o[1]=pk2(a0[2],a0[3]); o[2]=pk2(a1[0],a1[1]); o[3]=pk2(a1[2],a1[3]);
    *(i32x4*)(rec + (size_t)(kk*64+l)*16) = o;
    f32x4 b0 = *(const f32x4*)(&gtmp[c16*68 + 32*kk + 8*g]);
    f32x4 b1 = *(const f32x4*)(&gtmp[c16*68 + 32*kk + 8*g + 4]);
    o[0]=pk2(b0[0],b0[1]); o[1]=pk2(b0[2],b0[3]); o[2]=pk2(b1[0],b1[1]); o[3]=pk2(b1[2],b1[3]);
    *(i32x4*)(rec + 2048 + (size_t)(kk*64+l)*16) = o;
  }
}

// ---------------- serial scan v4: 1 wave per (bh, i-strip), barrier-free ----------------
// block bid = bh*4 + w; wave owns columns i in [16w,16w+16). Per chunk: 8 MFMA,
// 11 gload_lds staged record, counted vmcnt(4) (4 y-stores are the only younger vm ops).
__global__ __launch_bounds__(64) void scan2_kernel(char* ws, const float* S0, float* dout){
  float* YB=(float*)(ws+OFF_YBUF);
  const char* recb = ws + OFF_REC;
  const float* PLg = (const float*)(ws+OFF_PL);
  int bid=blockIdx.x, bh=bid>>2, w=bid&3;
  int l=threadIdx.x, c16=l&15, g=l>>4;

  __shared__ __align__(16) char buf[2][10240];
  __shared__ __align__(16) float plring[2][64];
  __shared__ __align__(16) u16 zT[16*24];
  __shared__ __align__(16) u16 ST[16*88];

  // Sreg[jt][e] = S^T[16jt+4g+e][i=16w+c16]
  f32x4 Sreg[4];
  #pragma unroll
  for (int jt=0;jt<4;jt++)
    Sreg[jt] = *(const f32x4*)(S0 + (size_t)bh*4096 + (size_t)(16*w+c16)*64 + 16*jt + 4*g);
  #pragma unroll
  for (int jt=0;jt<4;jt++){
    i32x2 p; p[0]=pk2(Sreg[jt][0],Sreg[jt][1]); p[1]=pk2(Sreg[jt][2],Sreg[jt][3]);
    *(i32x2*)(&ST[c16*88 + 16*jt + 4*g]) = p;
  }

  const char* rb = recb + (size_t)(bh*64)*14336;
  const float* plb = PLg + (size_t)(bh*64)*64;

  // stage chunk 0 -> slot 0 (8 shared + 2 slice + 1 pL = 11 loads)
  {
    const float* r0 = (const float*)rb;
    float* d = (float*)(&buf[0][0]);
    #pragma unroll
    for (int q=0;q<8;q++) gload_lds16(r0 + q*256 + l*4, d + q*256);
    const float* rs = (const float*)(rb + 8192 + (size_t)w*1536);
    gload_lds16(rs + l*4, d + 2048);
    gload_lds16(rs + 256 + l*4, d + 2304);   // 512B valid + 512B overshoot pad
    gload_lds4(plb + l, &plring[0][0]);
  }
  asm volatile("s_waitcnt vmcnt(0)" ::: "memory");
  __builtin_amdgcn_sched_barrier(0);

  float* yb0 = YB + (size_t)bh*65536;

  #pragma unroll 1
  for (int ch=0; ch<64; ++ch){
    // 11 prefetch loads (oldest) must land; up to 4 y-stores may remain outstanding
    asm volatile("s_waitcnt vmcnt(4)" ::: "memory");
    __builtin_amdgcn_sched_barrier(0);
    const char* bp = &buf[ch&1][0];
    const float* plv = &plring[ch&1][0];

    s16x8 pf[2], gf[2], sB[2], barkar[4];
    #pragma unroll
    for (int kk=0;kk<2;kk++){
      pf[kk]=*(const s16x8*)(bp + (size_t)(kk*64+l)*16);
      gf[kk]=*(const s16x8*)(bp + 2048 + (size_t)(kk*64+l)*16);
      sB[kk]=*(const s16x8*)(&ST[c16*88 + 32*kk + 8*g]);
    }
    #pragma unroll
    for (int jt=0;jt<4;jt++)
      barkar[jt]=*(const s16x8*)(bp + 4096 + (size_t)((jt*4+g)*16 + (c16 ^ (g<<2)))*16);
    i32x2 zlv=*(const i32x2*)(bp + 8192 + (size_t)l*8);
    i32x2 ylv=*(const i32x2*)(bp + 8704 + (size_t)l*8);

    // prefetch next record -> other slot
    {
      int nc = (ch<63)?(ch+1):63;
      const float* r = (const float*)(rb + (size_t)nc*14336);
      float* d = (float*)(&buf[(ch+1)&1][0]);
      #pragma unroll
      for (int q=0;q<8;q++) gload_lds16(r + q*256 + l*4, d + q*256);
      const float* rs = (const float*)(rb + (size_t)nc*14336 + 8192 + (size_t)w*1536);
      gload_lds16(rs + l*4, d + 2048);
      gload_lds16(rs + 256 + l*4, d + 2304);
      gload_lds4(plb + nc*64 + l, &plring[(ch+1)&1][0]);
    }

    // z = P.S^T + zloc ; Y = G.S^T + Yloc   (own i-strip)
    f32x4 dz=cvt4(zlv), dy=cvt4(ylv);
    dz=MFMA32(pf[0],sB[0],dz); dz=MFMA32(pf[1],sB[1],dz);
    dy=MFMA32(gf[0],sB[0],dy); dy=MFMA32(gf[1],sB[1],dy);

    // z -> B-frag via private LDS transpose; K-slots 16..31 come from record V
    {
      i32x2 zp; zp[0]=pk2(dz[0],dz[1]); zp[1]=pk2(dz[2],dz[3]);
      *(i32x2*)(&zT[c16*24 + 4*g]) = zp;
    }
    s16x8 zvf = (g<2) ? *(const s16x8*)(&zT[c16*24 + 8*g])
                      : *(const s16x8*)(bp + 9216 + (size_t)((g-2)*16 + c16)*16);

    // S' = diag(pL) S + [Bbar;Kbar]^T [z;V]   (one MFMA per j-tile)
    #pragma unroll
    for (int jt=0;jt<4;jt++){
      f32x4 pl4 = *(const f32x4*)(plv + 16*jt + 4*g);
      f32x4 acc = Sreg[jt]*pl4;
      acc=MFMA32(barkar[jt],zvf,acc);
      Sreg[jt]=acc;
    }
    #pragma unroll
    for (int jt=0;jt<4;jt++){
      i32x2 p; p[0]=pk2(Sreg[jt][0],Sreg[jt][1]); p[1]=pk2(Sreg[jt][2],Sreg[jt][3]);
      *(i32x2*)(&ST[c16*88 + 16*jt + 4*g]) = p;
    }
    // y stores (4 global stores, younger than next chunk's loads in vmcnt queue)
    {
      float* yb = yb0 + (size_t)ch*1024;
      #pragma unroll
      for (int e=0;e<4;e++)
        yb[(size_t)(4*g+e)*64 + 16*w + c16] = dy[e];
    }
  }

  // final state
  #pragma unroll
  for (int jt=0;jt<4;jt++)
    *(f32x4*)(dout + 2097152 + (size_t)bh*4096 + (size_t)(16*w+c16)*64 + 16*jt + 4*g) = Sreg[jt];
}

// ---------------- epilogue: groupnorm + bonus + gate -> bf16 ----------------
__global__ __launch_bounds__(256) void epi_kernel(char* ws, const float* rk,
  const float* lnw, const float* lnb)
{
  const float* YB=(const float*)(ws+OFF_YBUF);
  const float* SEQf=(const float*)(ws+OFF_SEQ);
  const float* GB=(const float*)(ws+OFF_GBUF);
  u16* XGB=(u16*)(ws+OFF_XGB);
  int m=blockIdx.x, b=m>>10, t=m&1023;
  int tid=threadIdx.x, c0=tid*4, h=c0>>6, i0=c0&63;
  f32x4 y=*(const f32x4*)(YB + ((size_t)(b*16+h)*1024+t)*64 + i0);
  float s = y[0]+y[1]+y[2]+y[3];
  float ss= y[0]*y[0]+y[1]*y[1]+y[2]*y[2]+y[3]*y[3];
  #pragma unroll
  for (int mk=1;mk<16;mk<<=1){ s+=__shfl_xor(s,mk); ss+=__shfl_xor(ss,mk); }
  float mu=s*(1.0f/64.0f), var=ss*(1.0f/64.0f)-mu*mu;
  float inv=rsqrtf(var + 6.4e-4f);
  size_t sb=((size_t)(b*16+h)*1024+t)*384;
  f32x4 r=*(const f32x4*)(SEQf+sb+i0);
  f32x4 k=*(const f32x4*)(SEQf+sb+128+i0);
  f32x4 v=*(const f32x4*)(SEQf+sb+192+i0);
  f32x4 q=*(const f32x4*)(rk + h*64 + i0);
  float dp = r[0]*k[0]*q[0]+r[1]*k[1]*q[1]+r[2]*k[2]*q[2]+r[3]*k[3]*q[3];
  #pragma unroll
  for (int mk=1;mk<16;mk<<=1) dp+=__shfl_xor(dp,mk);
  f32x4 gg=*(const f32x4*)(GB+(size_t)m*1024+c0);
  u16x4 outv;
  #pragma unroll
  for (int j=0;j<4;j++){
    float xn = (y[j]-mu)*inv*lnw[c0+j] + lnb[c0+j] + dp*v[j];
    outv[j]=f2bf(xn*gg[j]);
  }
  *(u16x4*)(XGB+(size_t)m*1024+c0)=outv;
}

extern "C" void kernel_launch(void* const* d_in, const int* in_sizes, int n_in,
                              void* d_out, int out_size, void* d_ws, size_t ws_size,
                              hipStream_t stream) {
  const float* x      =(const float*)d_in[0];
  const float* S0     =(const float*)d_in[1];
  const float* vfirst =(const float*)d_in[2];
  const float* w0     =(const float*)d_in[3];
  const float* w1     =(const float*)d_in[4];
  const float* w2     =(const float*)d_in[5];
  const float* a0     =(const float*)d_in[6];
  const float* a1     =(const float*)d_in[7];
  const float* a2     =(const float*)d_in[8];
  const float* v0     =(const float*)d_in[9];
  const float* v1     =(const float*)d_in[10];
  const float* v2     =(const float*)d_in[11];
  const float* g1     =(const float*)d_in[12];
  const float* g2     =(const float*)d_in[13];
  const float* k_k    =(const float*)d_in[14];
  const float* k_a    =(const float*)d_in[15];
  const float* r_k    =(const float*)d_in[16];
  const float* Wq     =(const float*)d_in[17];
  const float* Wk     =(const float*)d_in[18];
  const float* Wv     =(const float*)d_in[19];
  const float* Wo     =(const float*)d_in[20];
  const float* ln_w   =(const float*)d_in[21];
  const float* ln_b   =(const float*)d_in[22];
  char* ws=(char*)d_ws;
  float* dout=(float*)d_out;

  prep_kernel<<<2048,256,0,stream>>>(ws,x,vfirst,w1,w2,a1,a2,v1,v2,g1,g2,Wq,Wk,Wv,Wo,dout);
  gemm_kernel<<<dim3(16,19),256,0,stream>>>(0,ws,w0,a0,v0,dout);
  gemm_kernel<<<dim3(16,32),256,0,stream>>>(1,ws,w0,a0,v0,dout);
  prep2_kernel<<<2048,256,0,stream>>>(ws,vfirst,k_k,k_a);
  pre_kernel<<<2048,64,0,stream>>>(ws);
  scan2_kernel<<<128,64,0,stream>>>(ws,S0,dout);
  epi_kernel<<<2048,256,0,stream>>>(ws,r_k,ln_w,ln_b);
  gemm_kernel<<<dim3(16,8),256,0,stream>>>(2,ws,w0,a0,v0,dout);
}